// Round 4
// baseline (338.990 us; speedup 1.0000x reference)
//
#include <hip/hip_runtime.h>
#include <hip/hip_bf16.h>

typedef unsigned short u16;
typedef __bf16 bf16x8 __attribute__((ext_vector_type(8)));
typedef float f32x4 __attribute__((ext_vector_type(4)));

__device__ __forceinline__ float bf2f(u16 u) {
  union { unsigned int i; float f; } v; v.i = ((unsigned int)u) << 16; return v.f;
}
__device__ __forceinline__ u16 f2bf(float f) {
  union { float f; unsigned int i; } v; v.f = f;
  unsigned int r = v.i + 0x7fffu + ((v.i >> 16) & 1u);
  return (u16)(r >> 16);
}
__device__ __forceinline__ unsigned cvtpk(float lo, float hi) {
  unsigned r;
  asm("v_cvt_pk_bf16_f32 %0, %1, %2" : "=v"(r) : "v"(lo), "v"(hi));
  return r;
}

__device__ __forceinline__ void async_load16(void* lds, const void* g) {
  __builtin_amdgcn_global_load_lds((const __attribute__((address_space(1))) void*)g,
                                   (__attribute__((address_space(3))) void*)lds, 16, 0, 0);
}

// ---------------- fused fp32 -> bf16 convert (x, Wq|Wk -> Wqk, Wv, Wo) ----------------
__global__ void convert_all(const float* __restrict__ x, const float* __restrict__ Wq,
                            const float* __restrict__ Wk, const float* __restrict__ Wv,
                            const float* __restrict__ Wo, u16* __restrict__ xb,
                            u16* __restrict__ Wqkb, u16* __restrict__ Wvb,
                            u16* __restrict__ Wob) {
  int bid = blockIdx.x;
  const float* src;
  u16* dst;
  int off;
  if (bid < 8192)       { src = x;  dst = xb;              off = bid; }
  else if (bid < 12288) { src = Wq; dst = Wqkb;            off = bid - 8192; }
  else if (bid < 16384) { src = Wk; dst = Wqkb + 4194304;  off = bid - 12288; }
  else if (bid < 20480) { src = Wv; dst = Wvb;             off = bid - 16384; }
  else                  { src = Wo; dst = Wob;             off = bid - 20480; }
  int i = off * 1024 + threadIdx.x * 4;
  float4 v = *(const float4*)(src + i);
  ushort4 o;
  o.x = f2bf(v.x); o.y = f2bf(v.y); o.z = f2bf(v.z); o.w = f2bf(v.w);
  *(ushort4*)(dst + i) = o;
}

// ---------------- GEMM tile body: C[M,N] = A[M,K] * B[N,K]^T (m97-style 128x128) ----------------
template <int OUT_F32>
__device__ __forceinline__ void gemm_tile_body(const u16* __restrict__ A,
                                               const u16* __restrict__ Bm,
                                               void* __restrict__ C, int M, int N, int K,
                                               int swz, u16* sA, u16* sB) {
  const int nTn = N >> 7;
  int tm = swz / nTn, tn = swz % nTn;
  const int t = threadIdx.x;
  const int w = t >> 6, l = t & 63;
  const int wr = w >> 1, wc = w & 1;
  const int lr = l & 15, lh = l >> 4;
  const size_t row0 = (size_t)tm * 128, col0 = (size_t)tn * 128;

  f32x4 zero = {0.f, 0.f, 0.f, 0.f};
  f32x4 acc[4][4];
#pragma unroll
  for (int i = 0; i < 4; ++i)
#pragma unroll
    for (int j = 0; j < 4; ++j) acc[i][j] = zero;

  const u16* Ag = A + row0 * K;
  const u16* Bg = Bm + col0 * K;

  for (int k0 = 0; k0 < K; k0 += 32) {
#pragma unroll
    for (int i = 0; i < 2; ++i) {
      int c = i * 256 + t;
      int r = c >> 2, kk = (c & 3) << 3;
      async_load16(sA + (((size_t)i * 256 + w * 64) << 3), Ag + (size_t)r * K + k0 + kk);
      async_load16(sB + (((size_t)i * 256 + w * 64) << 3), Bg + (size_t)r * K + k0 + kk);
    }
    __syncthreads();
    bf16x8 af[4], bfr[4];
#pragma unroll
    for (int mi = 0; mi < 4; ++mi)
      af[mi] = *reinterpret_cast<const bf16x8*>(sA + (wr * 64 + mi * 16 + lr) * 32 + lh * 8);
#pragma unroll
    for (int ni = 0; ni < 4; ++ni)
      bfr[ni] = *reinterpret_cast<const bf16x8*>(sB + (wc * 64 + ni * 16 + lr) * 32 + lh * 8);
#pragma unroll
    for (int mi = 0; mi < 4; ++mi)
#pragma unroll
      for (int ni = 0; ni < 4; ++ni)
        acc[mi][ni] = __builtin_amdgcn_mfma_f32_16x16x32_bf16(af[mi], bfr[ni], acc[mi][ni], 0, 0, 0);
    __syncthreads();
  }

#pragma unroll
  for (int mi = 0; mi < 4; ++mi)
#pragma unroll
    for (int ni = 0; ni < 4; ++ni)
#pragma unroll
      for (int r = 0; r < 4; ++r) {
        size_t row = row0 + wr * 64 + mi * 16 + lh * 4 + r;
        size_t col = col0 + wc * 64 + ni * 16 + lr;
        float v = acc[mi][ni][r];
        if (OUT_F32)
          ((float*)C)[row * N + col] = v;
        else
          ((u16*)C)[row * N + col] = f2bf(v);
      }
}

// QK (1024 blocks) + V^T (512 blocks) in one launch
__global__ __launch_bounds__(256)
void gemm_qkv(const u16* __restrict__ xb, const u16* __restrict__ Wqkb,
              const u16* __restrict__ Wvb, u16* __restrict__ QKb, u16* __restrict__ VTb) {
  __shared__ __align__(16) u16 sA[128 * 32];
  __shared__ __align__(16) u16 sB[128 * 32];
  int bid = blockIdx.x;
  if (bid < 1024) {
    int swz = (bid & 7) * 128 + (bid >> 3);
    gemm_tile_body<0>(xb, Wqkb, QKb, 4096, 4096, 2048, swz, sA, sB);
  } else {
    int b2 = bid - 1024;
    int swz = (b2 & 7) * 64 + (b2 >> 3);
    gemm_tile_body<0>(Wvb, xb, VTb, 2048, 4096, 2048, swz, sA, sB);
  }
}

__global__ __launch_bounds__(256)
void gemm_o(const u16* __restrict__ Ob, const u16* __restrict__ Wob, float* __restrict__ out) {
  __shared__ __align__(16) u16 sA[128 * 32];
  __shared__ __align__(16) u16 sB[128 * 32];
  int bid = blockIdx.x;
  int swz = (bid & 7) * 64 + (bid >> 3);
  gemm_tile_body<1>(Ob, Wob, (void*)out, 4096, 2048, 2048, swz, sA, sB);
}

// ---------------- RoPE over fused QK buffer [4096 rows][4096 cols] in place ----------------
// head slots 0..15 = Q heads (scaled by qscale), 16..31 = K heads (scale 1).
__global__ void rope_all(u16* __restrict__ qk, const float* __restrict__ cosb,
                         const float* __restrict__ sinb, float qscale) {
  int tid = blockIdx.x * blockDim.x + threadIdx.x;  // 2M threads
  int p = tid & 15;
  int hs = (tid >> 4) & 31;
  int row = tid >> 9;
  int s = row & 2047;
  float scale = hs < 16 ? qscale : 1.0f;
  int d0 = p << 2;
  size_t base = (size_t)row * 4096 + hs * 128;
  u16* q0p = qk + base + d0;
  u16* q1p = qk + base + 64 + d0;
  ushort4 a = *(ushort4*)q0p, b = *(ushort4*)q1p;
  float4 c0 = *(const float4*)(cosb + s * 128 + d0);
  float4 c1 = *(const float4*)(cosb + s * 128 + 64 + d0);
  float4 s0 = *(const float4*)(sinb + s * 128 + d0);
  float4 s1 = *(const float4*)(sinb + s * 128 + 64 + d0);
  float a0 = bf2f(a.x), a1 = bf2f(a.y), a2 = bf2f(a.z), a3 = bf2f(a.w);
  float b0 = bf2f(b.x), b1 = bf2f(b.y), b2 = bf2f(b.z), b3 = bf2f(b.w);
  ushort4 o0, o1;
  o0.x = f2bf((a0 * c0.x - b0 * s0.x) * scale);
  o0.y = f2bf((a1 * c0.y - b1 * s0.y) * scale);
  o0.z = f2bf((a2 * c0.z - b2 * s0.z) * scale);
  o0.w = f2bf((a3 * c0.w - b3 * s0.w) * scale);
  o1.x = f2bf((b0 * c1.x + a0 * s1.x) * scale);
  o1.y = f2bf((b1 * c1.y + a1 * s1.y) * scale);
  o1.z = f2bf((b2 * c1.z + a2 * s1.z) * scale);
  o1.w = f2bf((b3 * c1.w + a3 * s1.w) * scale);
  *(ushort4*)q0p = o0;
  *(ushort4*)q1p = o1;
}

// ---------------- Flash attention: K dbuf + V single-buffer, raw barriers + counted vmcnt ----------------
// QK: [B*S][4096] bf16 (Q cols 0-2047 roped*scaled, K cols 2048-4095 roped).
// VT: [2048][4096] bf16. O: [B*S][2048] bf16.
// grid 512 = 32 bh * 16 qtiles(128); block 256 = 4 waves * 32 q-rows.
// LDS 48KB -> 3 blocks/CU (12 waves). Barrier #1 waits V only (vmcnt(4): K(kt+1)
// stays in flight); barrier #2 waits all (vmcnt(0)).
__global__ __launch_bounds__(256, 4)
void attn_kernel(const u16* __restrict__ QKb, const u16* __restrict__ VT,
                 u16* __restrict__ Ob) {
  __shared__ __align__(16) u16 sK[2][64 * 128];   // 32 KB
  __shared__ __align__(16) u16 sV[128 * 64];      // 16 KB
  __shared__ __align__(16) u16 sP[4][32 * 64];    // 16 KB

  int id = blockIdx.x;
  int swz = (id & 7) * 64 + (id >> 3);    // XCD-chunked: 4 heads/XCD -> KV L2-resident
  int bh = swz >> 4;
  int qb = swz & 15;
  int b = bh >> 4, h = bh & 15;
  int t = threadIdx.x, w = t >> 6, l = t & 63;
  int lr = l & 15, lh = l >> 4;
  int lr7 = lr & 7;
  int q0 = qb * 128;

  const u16* Kbase = QKb + (size_t)(b * 2048) * 4096 + 2048 + h * 128;
  const u16* Vbase = VT + (size_t)(h * 128) * 4096 + b * 2048;
  u16* sPw = sP[w];

  // Q fragments (B-operand of swapped QK^T)
  bf16x8 aq[2][4];
#pragma unroll
  for (int qf = 0; qf < 2; ++qf) {
    size_t qrow = (size_t)(b * 2048 + q0 + w * 32 + qf * 16 + lr) * 4096 + h * 128;
#pragma unroll
    for (int c = 0; c < 4; ++c)
      aq[qf][c] = *reinterpret_cast<const bf16x8*>(QKb + qrow + c * 32 + lh * 8);
  }

  f32x4 zero = {0.f, 0.f, 0.f, 0.f};
  f32x4 acc_o[2][8];  // O^T[d][q=lr]
#pragma unroll
  for (int qf = 0; qf < 2; ++qf)
#pragma unroll
    for (int d = 0; d < 8; ++d) acc_o[qf][d] = zero;
  float m_row[2] = {-1e30f, -1e30f};
  float l_row[2] = {0.f, 0.f};

  auto stageK = [&](int buf, int kt2) {
    const u16* Kt = Kbase + (size_t)(kt2 * 64) * 4096;
#pragma unroll
    for (int it = 0; it < 4; ++it) {
      int o = it * 4096 + t * 16;
      int rowK = o >> 8;
      int cbK = (o & 255) ^ ((rowK & 7) << 4);
      async_load16((u16*)sK[buf] + (o >> 1), Kt + (size_t)rowK * 4096 + (cbK >> 1));
    }
  };
  auto stageV = [&](int kt2) {
    const u16* Vt = Vbase + kt2 * 64;
#pragma unroll
    for (int it = 0; it < 4; ++it) {
      int o = it * 4096 + t * 16;
      int rowV = o >> 7;
      int cbV = (o & 127) ^ ((rowV & 7) << 4);
      async_load16((u16*)sV + (o >> 1), Vt + (size_t)rowV * 4096 + (cbV >> 1));
    }
  };

  stageK(0, 0);
  asm volatile("s_waitcnt vmcnt(0)" ::: "memory");
  __builtin_amdgcn_s_barrier();
  int cur = 0;

  for (int kt = 0; kt < 32; ++kt) {
    stageV(kt);                         // 4 loads (oldest)
    __builtin_amdgcn_sched_barrier(0);  // keep V-before-K issue order for vmcnt counting
    if (kt < 31) stageK(cur ^ 1, kt + 1);  // 4 loads

    const u16* sKc = sK[cur];

    // ---- QK^T swapped: sacc[qf][g] = S[k = g*16+lh*4+e][q = lr] ----
    f32x4 sacc[2][4];
#pragma unroll
    for (int qf = 0; qf < 2; ++qf)
#pragma unroll
      for (int g = 0; g < 4; ++g) sacc[qf][g] = zero;
#pragma unroll
    for (int g = 0; g < 4; ++g) {
      int row = g * 16 + lr;
      int xr = lr7 << 4;
#pragma unroll
      for (int c = 0; c < 4; ++c) {
        int cb = (c * 64 + lh * 16) ^ xr;
        bf16x8 bk = *reinterpret_cast<const bf16x8*>(sKc + row * 128 + (cb >> 1));
        sacc[0][g] = __builtin_amdgcn_mfma_f32_16x16x32_bf16(bk, aq[0][c], sacc[0][g], 0, 0, 0);
        sacc[1][g] = __builtin_amdgcn_mfma_f32_16x16x32_bf16(bk, aq[1][c], sacc[1][g], 0, 0, 0);
      }
    }

    // ---- in-lane online softmax (q = lr lane-local) ----
#pragma unroll
    for (int qf = 0; qf < 2; ++qf) {
      f32x4 m4;
#pragma unroll
      for (int e = 0; e < 4; ++e)
        m4[e] = fmaxf(fmaxf(sacc[qf][0][e], sacc[qf][1][e]),
                      fmaxf(sacc[qf][2][e], sacc[qf][3][e]));
      float mx = fmaxf(fmaxf(m4[0], m4[1]), fmaxf(m4[2], m4[3]));
      mx = fmaxf(mx, __shfl_xor(mx, 16));
      mx = fmaxf(mx, __shfl_xor(mx, 32));
      float mo = m_row[qf];
      if (!__all(mx <= mo + 8.f)) {     // T13 defer-max
        float mn = fmaxf(mo, mx);
        float al = __builtin_amdgcn_exp2f(mo - mn);
        m_row[qf] = mn;
        l_row[qf] *= al;
#pragma unroll
        for (int d = 0; d < 8; ++d) acc_o[qf][d] *= al;
      }
      float mn = m_row[qf];
#pragma unroll
      for (int g = 0; g < 4; ++g)
#pragma unroll
        for (int e = 0; e < 4; ++e)
          sacc[qf][g][e] = __builtin_amdgcn_exp2f(sacc[qf][g][e] - mn);
      f32x4 s4;
#pragma unroll
      for (int e = 0; e < 4; ++e)
        s4[e] = (sacc[qf][0][e] + sacc[qf][1][e]) + (sacc[qf][2][e] + sacc[qf][3][e]);
      float rs = (s4[0] + s4[1]) + (s4[2] + s4[3]);
      rs += __shfl_xor(rs, 16);
      rs += __shfl_xor(rs, 32);
      l_row[qf] += rs;

      int rowb = (qf * 16 + lr) * 128;
      int xw = lr7 << 4;
#pragma unroll
      for (int g = 0; g < 4; ++g) {
        uint2 pw;
        pw.x = cvtpk(sacc[qf][g][0], sacc[qf][g][1]);
        pw.y = cvtpk(sacc[qf][g][2], sacc[qf][g][3]);
        int cb = (g * 32 + lh * 8) ^ xw;
        *reinterpret_cast<uint2*>(reinterpret_cast<char*>(sPw) + rowb + cb) = pw;
      }
    }

    // ---- barrier #1: V(kt) landed everywhere; K(kt+1) stays in flight ----
    if (kt < 31) asm volatile("s_waitcnt vmcnt(4)" ::: "memory");
    else         asm volatile("s_waitcnt vmcnt(0)" ::: "memory");
    __builtin_amdgcn_sched_barrier(0);
    __builtin_amdgcn_s_barrier();

    // ---- PV swapped: acc_o += VT_tile * P ----
    bf16x8 bp[2][2];
#pragma unroll
    for (int qf = 0; qf < 2; ++qf) {
      int rowb = (qf * 16 + lr) * 128;
      int xr = lr7 << 4;
#pragma unroll
      for (int c2 = 0; c2 < 2; ++c2) {
        int cb = (c2 * 64 + lh * 16) ^ xr;
        bp[qf][c2] = *reinterpret_cast<const bf16x8*>(
            reinterpret_cast<const char*>(sPw) + rowb + cb);
      }
    }
#pragma unroll
    for (int c2 = 0; c2 < 2; ++c2) {
#pragma unroll
      for (int d = 0; d < 8; ++d) {
        int row = d * 16 + lr;
        int cb = (c2 * 64 + lh * 16) ^ (lr7 << 4);
        bf16x8 bv = *reinterpret_cast<const bf16x8*>(sV + row * 64 + (cb >> 1));
        acc_o[0][d] = __builtin_amdgcn_mfma_f32_16x16x32_bf16(bv, bp[0][c2], acc_o[0][d], 0, 0, 0);
        acc_o[1][d] = __builtin_amdgcn_mfma_f32_16x16x32_bf16(bv, bp[1][c2], acc_o[1][d], 0, 0, 0);
      }
    }

    // ---- barrier #2: K(kt+1) landed; all waves past PV(kt) ----
    asm volatile("s_waitcnt vmcnt(0)" ::: "memory");
    __builtin_amdgcn_sched_barrier(0);
    __builtin_amdgcn_s_barrier();
    cur ^= 1;
  }

  // ---- epilogue: normalize in-lane, vector store ----
#pragma unroll
  for (int qf = 0; qf < 2; ++qf) {
    float inv = 1.f / l_row[qf];
    size_t qrow = (size_t)(b * 2048 + q0 + w * 32 + qf * 16 + lr) * 2048 + h * 128;
#pragma unroll
    for (int d = 0; d < 8; ++d) {
      ushort4 o;
      o.x = f2bf(acc_o[qf][d][0] * inv);
      o.y = f2bf(acc_o[qf][d][1] * inv);
      o.z = f2bf(acc_o[qf][d][2] * inv);
      o.w = f2bf(acc_o[qf][d][3] * inv);
      *reinterpret_cast<ushort4*>(Ob + qrow + d * 16 + lh * 4) = o;
    }
  }
}

extern "C" void kernel_launch(void* const* d_in, const int* in_sizes, int n_in,
                              void* d_out, int out_size, void* d_ws, size_t ws_size,
                              hipStream_t stream) {
  const float* x  = (const float*)d_in[0];
  const float* rc = (const float*)d_in[1];
  const float* rs = (const float*)d_in[2];
  const float* Wq = (const float*)d_in[3];
  const float* Wk = (const float*)d_in[4];
  const float* Wv = (const float*)d_in[5];
  const float* Wo = (const float*)d_in[6];
  float* out = (float*)d_out;
  char* ws = (char*)d_ws;
  const size_t MB = 1024 * 1024;
  // layout (96 MB): Ob aliases Wqkb (dead after QK GEMM)
  u16* xb   = (u16*)(ws);            // 16 MB
  u16* Wqkb = (u16*)(ws + 16 * MB);  // 16 MB  [4096][2048] = [Wq;Wk]
  u16* Wvb  = (u16*)(ws + 32 * MB);  // 8 MB
  u16* Wob  = (u16*)(ws + 40 * MB);  // 8 MB
  u16* QKb  = (u16*)(ws + 48 * MB);  // 32 MB  [4096][4096]
  u16* VTb  = (u16*)(ws + 80 * MB);  // 16 MB  [2048][4096]
  u16* Ob   = (u16*)(ws + 16 * MB);  // 16 MB  (alias Wqkb)

  convert_all<<<24576, 256, 0, stream>>>(x, Wq, Wk, Wv, Wo, xb, Wqkb, Wvb, Wob);

  gemm_qkv<<<1536, 256, 0, stream>>>(xb, Wqkb, Wvb, QKb, VTb);

  const float qscale = 0.08838834764831845f * 1.4426950408889634f;  // 1/sqrt(128)*log2(e)
  rope_all<<<8192, 256, 0, stream>>>(QKb, rc, rs, qscale);

  attn_kernel<<<512, 256, 0, stream>>>(QKb, VTb, Ob);

  gemm_o<<<512, 256, 0, stream>>>(Ob, Wob, out);
}

// Round 5
// 308.465 us; speedup vs baseline: 1.0990x; 1.0990x over previous
//
#include <hip/hip_runtime.h>
#include <hip/hip_bf16.h>

typedef unsigned short u16;
typedef __bf16 bf16x8 __attribute__((ext_vector_type(8)));
typedef float f32x4 __attribute__((ext_vector_type(4)));

__device__ __forceinline__ float bf2f(u16 u) {
  union { unsigned int i; float f; } v; v.i = ((unsigned int)u) << 16; return v.f;
}
__device__ __forceinline__ u16 f2bf(float f) {
  union { float f; unsigned int i; } v; v.f = f;
  unsigned int r = v.i + 0x7fffu + ((v.i >> 16) & 1u);
  return (u16)(r >> 16);
}
__device__ __forceinline__ unsigned cvtpk(float lo, float hi) {
  unsigned r;
  asm("v_cvt_pk_bf16_f32 %0, %1, %2" : "=v"(r) : "v"(lo), "v"(hi));
  return r;
}

__device__ __forceinline__ void async_load16(void* lds, const void* g) {
  __builtin_amdgcn_global_load_lds((const __attribute__((address_space(1))) void*)g,
                                   (__attribute__((address_space(3))) void*)lds, 16, 0, 0);
}

// ---------------- fused fp32 -> bf16 convert (x, Wq|Wk -> Wqk, Wv, Wo) ----------------
__global__ void convert_all(const float* __restrict__ x, const float* __restrict__ Wq,
                            const float* __restrict__ Wk, const float* __restrict__ Wv,
                            const float* __restrict__ Wo, u16* __restrict__ xb,
                            u16* __restrict__ Wqkb, u16* __restrict__ Wvb,
                            u16* __restrict__ Wob) {
  int bid = blockIdx.x;
  const float* src;
  u16* dst;
  int off;
  if (bid < 8192)       { src = x;  dst = xb;              off = bid; }
  else if (bid < 12288) { src = Wq; dst = Wqkb;            off = bid - 8192; }
  else if (bid < 16384) { src = Wk; dst = Wqkb + 4194304;  off = bid - 12288; }
  else if (bid < 20480) { src = Wv; dst = Wvb;             off = bid - 16384; }
  else                  { src = Wo; dst = Wob;             off = bid - 20480; }
  int i = off * 1024 + threadIdx.x * 4;
  float4 v = *(const float4*)(src + i);
  ushort4 o;
  o.x = f2bf(v.x); o.y = f2bf(v.y); o.z = f2bf(v.z); o.w = f2bf(v.w);
  *(ushort4*)(dst + i) = o;
}

// ---------------- GEMM tile body: C[M,N] = A[M,K] * B[N,K]^T (m97-style 128x128) -----
// Wave mapping: wave w owns rows w*32..w*32+31, ALL 128 cols (acc[2][8]) so that
// rope pairs (d, d+64) are acc[mi][ni] / acc[mi][ni+4] in the SAME lane.
// ROPE=1: output tile col0 is head slot tn (<16: Q, scaled; >=16: K); apply rope in epilogue.
template <int OUT_F32, int ROPE>
__device__ __forceinline__ void gemm_tile_body(const u16* __restrict__ A,
                                               const u16* __restrict__ Bm,
                                               void* __restrict__ C, int M, int N, int K,
                                               int swz, u16* sA, u16* sB,
                                               const float* __restrict__ cosb,
                                               const float* __restrict__ sinb,
                                               float qscale) {
  const int nTn = N >> 7;
  int tm = swz / nTn, tn = swz % nTn;
  const int t = threadIdx.x;
  const int w = t >> 6, l = t & 63;
  const int lr = l & 15, lh = l >> 4;
  const size_t row0 = (size_t)tm * 128, col0 = (size_t)tn * 128;

  f32x4 zero = {0.f, 0.f, 0.f, 0.f};
  f32x4 acc[2][8];
#pragma unroll
  for (int i = 0; i < 2; ++i)
#pragma unroll
    for (int j = 0; j < 8; ++j) acc[i][j] = zero;

  const u16* Ag = A + row0 * K;
  const u16* Bg = Bm + col0 * K;

  for (int k0 = 0; k0 < K; k0 += 32) {
#pragma unroll
    for (int i = 0; i < 2; ++i) {
      int c = i * 256 + t;
      int r = c >> 2, kk = (c & 3) << 3;
      async_load16(sA + (((size_t)i * 256 + w * 64) << 3), Ag + (size_t)r * K + k0 + kk);
      async_load16(sB + (((size_t)i * 256 + w * 64) << 3), Bg + (size_t)r * K + k0 + kk);
    }
    __syncthreads();
    bf16x8 af[2], bfr[8];
#pragma unroll
    for (int mi = 0; mi < 2; ++mi)
      af[mi] = *reinterpret_cast<const bf16x8*>(sA + (w * 32 + mi * 16 + lr) * 32 + lh * 8);
#pragma unroll
    for (int ni = 0; ni < 8; ++ni)
      bfr[ni] = *reinterpret_cast<const bf16x8*>(sB + (ni * 16 + lr) * 32 + lh * 8);
#pragma unroll
    for (int mi = 0; mi < 2; ++mi)
#pragma unroll
      for (int ni = 0; ni < 8; ++ni)
        acc[mi][ni] = __builtin_amdgcn_mfma_f32_16x16x32_bf16(af[mi], bfr[ni], acc[mi][ni], 0, 0, 0);
    __syncthreads();
  }

  if (ROPE) {
    float scale = (tn < 16) ? qscale : 1.0f;
#pragma unroll
    for (int mi = 0; mi < 2; ++mi)
#pragma unroll
      for (int r = 0; r < 4; ++r) {
        size_t row = row0 + w * 32 + mi * 16 + lh * 4 + r;
        int s = (int)(row & 2047);
        const float* cr = cosb + s * 128;
        const float* sr = sinb + s * 128;
#pragma unroll
        for (int ni = 0; ni < 4; ++ni) {
          int dlo = ni * 16 + lr;
          float v0 = acc[mi][ni][r];
          float v1 = acc[mi][ni + 4][r];
          float o0 = (v0 * cr[dlo] - v1 * sr[dlo]) * scale;
          float o1 = (v1 * cr[64 + dlo] + v0 * sr[64 + dlo]) * scale;
          ((u16*)C)[row * N + col0 + dlo]      = f2bf(o0);
          ((u16*)C)[row * N + col0 + 64 + dlo] = f2bf(o1);
        }
      }
  } else {
#pragma unroll
    for (int mi = 0; mi < 2; ++mi)
#pragma unroll
      for (int ni = 0; ni < 8; ++ni)
#pragma unroll
        for (int r = 0; r < 4; ++r) {
          size_t row = row0 + w * 32 + mi * 16 + lh * 4 + r;
          size_t col = col0 + ni * 16 + lr;
          float v = acc[mi][ni][r];
          if (OUT_F32)
            ((float*)C)[row * N + col] = v;
          else
            ((u16*)C)[row * N + col] = f2bf(v);
        }
  }
}

// QK (1024 blocks, rope fused) + V^T (512 blocks) in one launch
__global__ __launch_bounds__(256)
void gemm_qkv(const u16* __restrict__ xb, const u16* __restrict__ Wqkb,
              const u16* __restrict__ Wvb, u16* __restrict__ QKb, u16* __restrict__ VTb,
              const float* __restrict__ cosb, const float* __restrict__ sinb, float qscale) {
  __shared__ __align__(16) u16 sA[128 * 32];
  __shared__ __align__(16) u16 sB[128 * 32];
  int bid = blockIdx.x;
  if (bid < 1024) {
    int swz = (bid & 7) * 128 + (bid >> 3);
    gemm_tile_body<0, 1>(xb, Wqkb, QKb, 4096, 4096, 2048, swz, sA, sB, cosb, sinb, qscale);
  } else {
    int b2 = bid - 1024;
    int swz = (b2 & 7) * 64 + (b2 >> 3);
    gemm_tile_body<0, 0>(Wvb, xb, VTb, 2048, 4096, 2048, swz, sA, sB, nullptr, nullptr, 0.f);
  }
}

__global__ __launch_bounds__(256)
void gemm_o(const u16* __restrict__ Ob, const u16* __restrict__ Wob, float* __restrict__ out) {
  __shared__ __align__(16) u16 sA[128 * 32];
  __shared__ __align__(16) u16 sB[128 * 32];
  int bid = blockIdx.x;
  int swz = (bid & 7) * 64 + (bid >> 3);
  gemm_tile_body<1, 0>(Ob, Wob, (void*)out, 4096, 2048, 2048, swz, sA, sB, nullptr, nullptr, 0.f);
}

// ---------------- Flash attention (round-3 proven structure; QKb strides) ----------------
// QK: [B*S][4096] bf16 (cols 0-2047 = roped*scaled Q, 2048-4095 = roped K).
// VT: [2048][4096] bf16. O: [B*S][2048] bf16.
// grid 512 = 32 bh * 16 qtiles(128); block 256 = 4 waves * 32 q-rows (2 qf of 16).
// Swapped QK^T / PV, in-lane softmax, K+V double-buffered, __syncthreads per tile.
__global__ __launch_bounds__(256, 2)
void attn_kernel(const u16* __restrict__ QKb, const u16* __restrict__ VT,
                 u16* __restrict__ Ob) {
  __shared__ __align__(16) u16 sK[2][64 * 128];   // 32 KB
  __shared__ __align__(16) u16 sV[2][128 * 64];   // 32 KB
  __shared__ __align__(16) u16 sP[4][32 * 64];    // 16 KB

  int id = blockIdx.x;
  int swz = (id & 7) * 64 + (id >> 3);    // XCD-chunked: 4 heads/XCD -> KV L2-resident
  int bh = swz >> 4;
  int qb = swz & 15;
  int b = bh >> 4, h = bh & 15;
  int t = threadIdx.x, w = t >> 6, l = t & 63;
  int lr = l & 15, lh = l >> 4;
  int lr7 = lr & 7;
  int q0 = qb * 128;

  const u16* Kbase = QKb + (size_t)(b * 2048) * 4096 + 2048 + h * 128;
  const u16* Vbase = VT + (size_t)(h * 128) * 4096 + b * 2048;
  u16* sPw = sP[w];

  // Q fragments (B-operand of swapped QK^T)
  bf16x8 aq[2][4];
#pragma unroll
  for (int qf = 0; qf < 2; ++qf) {
    size_t qrow = (size_t)(b * 2048 + q0 + w * 32 + qf * 16 + lr) * 4096 + h * 128;
#pragma unroll
    for (int c = 0; c < 4; ++c)
      aq[qf][c] = *reinterpret_cast<const bf16x8*>(QKb + qrow + c * 32 + lh * 8);
  }

  f32x4 zero = {0.f, 0.f, 0.f, 0.f};
  f32x4 acc_o[2][8];  // O^T[d][q=lr]
#pragma unroll
  for (int qf = 0; qf < 2; ++qf)
#pragma unroll
    for (int d = 0; d < 8; ++d) acc_o[qf][d] = zero;
  float m_row[2] = {-1e30f, -1e30f};
  float l_row[2] = {0.f, 0.f};

  auto stage = [&](int buf, int kt2) {
    const u16* Kt = Kbase + (size_t)(kt2 * 64) * 4096;
    const u16* Vt = Vbase + kt2 * 64;
#pragma unroll
    for (int it = 0; it < 4; ++it) {
      int o = it * 4096 + t * 16;            // byte offset in 16KB tile
      int rowK = o >> 8;
      int cbK = (o & 255) ^ ((rowK & 7) << 4);
      async_load16((u16*)sK[buf] + (o >> 1), Kt + (size_t)rowK * 4096 + (cbK >> 1));
      int rowV = o >> 7;
      int cbV = (o & 127) ^ ((rowV & 7) << 4);
      async_load16((u16*)sV[buf] + (o >> 1), Vt + (size_t)rowV * 4096 + (cbV >> 1));
    }
  };

  stage(0, 0);
  __syncthreads();
  int cur = 0;

  for (int kt = 0; kt < 32; ++kt) {
    if (kt < 31) stage(cur ^ 1, kt + 1);

    const u16* sKc = sK[cur];
    const u16* sVc = sV[cur];

    // ---- QK^T swapped: sacc[qf][g] = S[k = g*16+lh*4+e][q = lr] ----
    f32x4 sacc[2][4];
#pragma unroll
    for (int qf = 0; qf < 2; ++qf)
#pragma unroll
      for (int g = 0; g < 4; ++g) sacc[qf][g] = zero;
#pragma unroll
    for (int g = 0; g < 4; ++g) {
      int row = g * 16 + lr;
      int xr = lr7 << 4;
#pragma unroll
      for (int c = 0; c < 4; ++c) {
        int cb = (c * 64 + lh * 16) ^ xr;
        bf16x8 bk = *reinterpret_cast<const bf16x8*>(sKc + row * 128 + (cb >> 1));
        sacc[0][g] = __builtin_amdgcn_mfma_f32_16x16x32_bf16(bk, aq[0][c], sacc[0][g], 0, 0, 0);
        sacc[1][g] = __builtin_amdgcn_mfma_f32_16x16x32_bf16(bk, aq[1][c], sacc[1][g], 0, 0, 0);
      }
    }

    // ---- in-lane online softmax (q = lr lane-local) ----
#pragma unroll
    for (int qf = 0; qf < 2; ++qf) {
      f32x4 m4;
#pragma unroll
      for (int e = 0; e < 4; ++e)
        m4[e] = fmaxf(fmaxf(sacc[qf][0][e], sacc[qf][1][e]),
                      fmaxf(sacc[qf][2][e], sacc[qf][3][e]));
      float mx = fmaxf(fmaxf(m4[0], m4[1]), fmaxf(m4[2], m4[3]));
      mx = fmaxf(mx, __shfl_xor(mx, 16));
      mx = fmaxf(mx, __shfl_xor(mx, 32));
      float mo = m_row[qf];
      if (!__all(mx <= mo + 8.f)) {     // T13 defer-max (exp2 space, P <= 2^8)
        float mn = fmaxf(mo, mx);
        float al = __builtin_amdgcn_exp2f(mo - mn);
        m_row[qf] = mn;
        l_row[qf] *= al;
#pragma unroll
        for (int d = 0; d < 8; ++d) acc_o[qf][d] *= al;
      }
      float mn = m_row[qf];
#pragma unroll
      for (int g = 0; g < 4; ++g)
#pragma unroll
        for (int e = 0; e < 4; ++e)
          sacc[qf][g][e] = __builtin_amdgcn_exp2f(sacc[qf][g][e] - mn);
      f32x4 s4;
#pragma unroll
      for (int e = 0; e < 4; ++e)
        s4[e] = (sacc[qf][0][e] + sacc[qf][1][e]) + (sacc[qf][2][e] + sacc[qf][3][e]);
      float rs = (s4[0] + s4[1]) + (s4[2] + s4[3]);
      rs += __shfl_xor(rs, 16);
      rs += __shfl_xor(rs, 32);
      l_row[qf] += rs;

      // pack P to bf16 pairs, write sP[q=lr][k], swizzled
      int rowb = (qf * 16 + lr) * 128;
      int xw = lr7 << 4;
#pragma unroll
      for (int g = 0; g < 4; ++g) {
        uint2 pw;
        pw.x = cvtpk(sacc[qf][g][0], sacc[qf][g][1]);
        pw.y = cvtpk(sacc[qf][g][2], sacc[qf][g][3]);
        int cb = (g * 32 + lh * 8) ^ xw;
        *reinterpret_cast<uint2*>(reinterpret_cast<char*>(sPw) + rowb + cb) = pw;
      }
    }

    // ---- PV swapped: acc_o += VT_tile * P ----
    bf16x8 bp[2][2];
#pragma unroll
    for (int qf = 0; qf < 2; ++qf) {
      int rowb = (qf * 16 + lr) * 128;
      int xr = lr7 << 4;
#pragma unroll
      for (int c2 = 0; c2 < 2; ++c2) {
        int cb = (c2 * 64 + lh * 16) ^ xr;
        bp[qf][c2] = *reinterpret_cast<const bf16x8*>(
            reinterpret_cast<const char*>(sPw) + rowb + cb);
      }
    }
#pragma unroll
    for (int c2 = 0; c2 < 2; ++c2) {
#pragma unroll
      for (int d = 0; d < 8; ++d) {
        int row = d * 16 + lr;
        int cb = (c2 * 64 + lh * 16) ^ (lr7 << 4);
        bf16x8 bv = *reinterpret_cast<const bf16x8*>(sVc + row * 64 + (cb >> 1));
        acc_o[0][d] = __builtin_amdgcn_mfma_f32_16x16x32_bf16(bv, bp[0][c2], acc_o[0][d], 0, 0, 0);
        acc_o[1][d] = __builtin_amdgcn_mfma_f32_16x16x32_bf16(bv, bp[1][c2], acc_o[1][d], 0, 0, 0);
      }
    }

    __syncthreads();  // next tile staged; cur fully consumed
    cur ^= 1;
  }

  // ---- epilogue: normalize in-lane, vector store ----
#pragma unroll
  for (int qf = 0; qf < 2; ++qf) {
    float inv = 1.f / l_row[qf];
    size_t qrow = (size_t)(b * 2048 + q0 + w * 32 + qf * 16 + lr) * 2048 + h * 128;
#pragma unroll
    for (int d = 0; d < 8; ++d) {
      ushort4 o;
      o.x = f2bf(acc_o[qf][d][0] * inv);
      o.y = f2bf(acc_o[qf][d][1] * inv);
      o.z = f2bf(acc_o[qf][d][2] * inv);
      o.w = f2bf(acc_o[qf][d][3] * inv);
      *reinterpret_cast<ushort4*>(Ob + qrow + d * 16 + lh * 4) = o;
    }
  }
}

extern "C" void kernel_launch(void* const* d_in, const int* in_sizes, int n_in,
                              void* d_out, int out_size, void* d_ws, size_t ws_size,
                              hipStream_t stream) {
  const float* x  = (const float*)d_in[0];
  const float* rc = (const float*)d_in[1];
  const float* rs = (const float*)d_in[2];
  const float* Wq = (const float*)d_in[3];
  const float* Wk = (const float*)d_in[4];
  const float* Wv = (const float*)d_in[5];
  const float* Wo = (const float*)d_in[6];
  float* out = (float*)d_out;
  char* ws = (char*)d_ws;
  const size_t MB = 1024 * 1024;
  // layout (96 MB): Ob aliases Wqkb (dead after QK GEMM)
  u16* xb   = (u16*)(ws);            // 16 MB
  u16* Wqkb = (u16*)(ws + 16 * MB);  // 16 MB  [4096][2048] = [Wq;Wk]
  u16* Wvb  = (u16*)(ws + 32 * MB);  // 8 MB
  u16* Wob  = (u16*)(ws + 40 * MB);  // 8 MB
  u16* QKb  = (u16*)(ws + 48 * MB);  // 32 MB  [4096][4096]
  u16* VTb  = (u16*)(ws + 80 * MB);  // 16 MB  [2048][4096]
  u16* Ob   = (u16*)(ws + 16 * MB);  // 16 MB  (alias Wqkb)

  convert_all<<<24576, 256, 0, stream>>>(x, Wq, Wk, Wv, Wo, xb, Wqkb, Wvb, Wob);

  const float qscale = 0.08838834764831845f * 1.4426950408889634f;  // 1/sqrt(128)*log2(e)
  gemm_qkv<<<1536, 256, 0, stream>>>(xb, Wqkb, Wvb, QKb, VTb, rc, rs, qscale);

  attn_kernel<<<512, 256, 0, stream>>>(QKb, VTb, Ob);

  gemm_o<<<512, 256, 0, stream>>>(Ob, Wob, out);
}

// Round 6
// 283.462 us; speedup vs baseline: 1.1959x; 1.0882x over previous
//
#include <hip/hip_runtime.h>
#include <hip/hip_bf16.h>

typedef unsigned short u16;
typedef __bf16 bf16x8 __attribute__((ext_vector_type(8)));
typedef float f32x4 __attribute__((ext_vector_type(4)));

__device__ __forceinline__ float bf2f(u16 u) {
  union { unsigned int i; float f; } v; v.i = ((unsigned int)u) << 16; return v.f;
}
__device__ __forceinline__ u16 f2bf(float f) {
  union { float f; unsigned int i; } v; v.f = f;
  unsigned int r = v.i + 0x7fffu + ((v.i >> 16) & 1u);
  return (u16)(r >> 16);
}
__device__ __forceinline__ unsigned cvtpk(float lo, float hi) {
  unsigned r;
  asm("v_cvt_pk_bf16_f32 %0, %1, %2" : "=v"(r) : "v"(lo), "v"(hi));
  return r;
}

__device__ __forceinline__ void async_load16(void* lds, const void* g) {
  __builtin_amdgcn_global_load_lds((const __attribute__((address_space(1))) void*)g,
                                   (__attribute__((address_space(3))) void*)lds, 16, 0, 0);
}

// ---------------- fused fp32 -> bf16 convert (x, Wq|Wk -> Wqk, Wv, Wo) ----------------
__global__ void convert_all(const float* __restrict__ x, const float* __restrict__ Wq,
                            const float* __restrict__ Wk, const float* __restrict__ Wv,
                            const float* __restrict__ Wo, u16* __restrict__ xb,
                            u16* __restrict__ Wqkb, u16* __restrict__ Wvb,
                            u16* __restrict__ Wob) {
  int bid = blockIdx.x;
  const float* src;
  u16* dst;
  int off;
  if (bid < 8192)       { src = x;  dst = xb;              off = bid; }
  else if (bid < 12288) { src = Wq; dst = Wqkb;            off = bid - 8192; }
  else if (bid < 16384) { src = Wk; dst = Wqkb + 4194304;  off = bid - 12288; }
  else if (bid < 20480) { src = Wv; dst = Wvb;             off = bid - 16384; }
  else                  { src = Wo; dst = Wob;             off = bid - 20480; }
  int i = off * 1024 + threadIdx.x * 4;
  float4 v = *(const float4*)(src + i);
  ushort4 o;
  o.x = f2bf(v.x); o.y = f2bf(v.y); o.z = f2bf(v.z); o.w = f2bf(v.w);
  *(ushort4*)(dst + i) = o;
}

// ---------------- GEMM tile body: C[M,N] = A[M,K] * B[N,K]^T (m97 128x128, 2x2 waves) ----
// m97 wave mapping (wr,wc), but each wave's 4 col-frags are permuted to
// cols {wc*32+0..31} u {wc*32+64..95}: frag ni -> col wc*32 + (ni&1)*16 + (ni>>1)*64.
// Rope pair (d, d+64) = (acc[mi][ni], acc[mi][ni+2]) in the SAME lane.
// ROPE=1: tile col0 = head slot tn*128 (<16: Q, scaled; >=16: K); rope in epilogue.
template <int OUT_F32, int ROPE>
__device__ __forceinline__ void gemm_tile_body(const u16* __restrict__ A,
                                               const u16* __restrict__ Bm,
                                               void* __restrict__ C, int M, int N, int K,
                                               int swz, u16* sA, u16* sB,
                                               const float* __restrict__ cosb,
                                               const float* __restrict__ sinb,
                                               float qscale) {
  const int nTn = N >> 7;
  int tm = swz / nTn, tn = swz % nTn;
  const int t = threadIdx.x;
  const int w = t >> 6, l = t & 63;
  const int wr = w >> 1, wc = w & 1;
  const int lr = l & 15, lh = l >> 4;
  const size_t row0 = (size_t)tm * 128, col0 = (size_t)tn * 128;

  f32x4 zero = {0.f, 0.f, 0.f, 0.f};
  f32x4 acc[4][4];
#pragma unroll
  for (int i = 0; i < 4; ++i)
#pragma unroll
    for (int j = 0; j < 4; ++j) acc[i][j] = zero;

  const u16* Ag = A + row0 * K;
  const u16* Bg = Bm + col0 * K;

  for (int k0 = 0; k0 < K; k0 += 32) {
#pragma unroll
    for (int i = 0; i < 2; ++i) {
      int c = i * 256 + t;
      int r = c >> 2, kk = (c & 3) << 3;
      async_load16(sA + (((size_t)i * 256 + w * 64) << 3), Ag + (size_t)r * K + k0 + kk);
      async_load16(sB + (((size_t)i * 256 + w * 64) << 3), Bg + (size_t)r * K + k0 + kk);
    }
    __syncthreads();
    bf16x8 af[4], bfr[4];
#pragma unroll
    for (int mi = 0; mi < 4; ++mi)
      af[mi] = *reinterpret_cast<const bf16x8*>(sA + (wr * 64 + mi * 16 + lr) * 32 + lh * 8);
#pragma unroll
    for (int ni = 0; ni < 4; ++ni) {
      int colf = wc * 32 + (ni & 1) * 16 + (ni >> 1) * 64;
      bfr[ni] = *reinterpret_cast<const bf16x8*>(sB + (colf + lr) * 32 + lh * 8);
    }
#pragma unroll
    for (int mi = 0; mi < 4; ++mi)
#pragma unroll
      for (int ni = 0; ni < 4; ++ni)
        acc[mi][ni] = __builtin_amdgcn_mfma_f32_16x16x32_bf16(af[mi], bfr[ni], acc[mi][ni], 0, 0, 0);
    __syncthreads();
  }

  if (ROPE) {
    float scale = (tn < 16) ? qscale : 1.0f;
#pragma unroll
    for (int mi = 0; mi < 4; ++mi)
#pragma unroll
      for (int r = 0; r < 4; ++r) {
        size_t row = row0 + wr * 64 + mi * 16 + lh * 4 + r;
        int s = (int)(row & 2047);
        const float* cr = cosb + s * 128;
        const float* sr = sinb + s * 128;
#pragma unroll
        for (int ni = 0; ni < 2; ++ni) {
          int dlo = wc * 32 + ni * 16 + lr;
          float v0 = acc[mi][ni][r];
          float v1 = acc[mi][ni + 2][r];
          float o0 = (v0 * cr[dlo] - v1 * sr[dlo]) * scale;
          float o1 = (v1 * cr[64 + dlo] + v0 * sr[64 + dlo]) * scale;
          ((u16*)C)[row * N + col0 + dlo]      = f2bf(o0);
          ((u16*)C)[row * N + col0 + 64 + dlo] = f2bf(o1);
        }
      }
  } else {
#pragma unroll
    for (int mi = 0; mi < 4; ++mi)
#pragma unroll
      for (int ni = 0; ni < 4; ++ni)
#pragma unroll
        for (int r = 0; r < 4; ++r) {
          size_t row = row0 + wr * 64 + mi * 16 + lh * 4 + r;
          size_t col = col0 + wc * 32 + (ni & 1) * 16 + (ni >> 1) * 64 + lr;
          float v = acc[mi][ni][r];
          if (OUT_F32)
            ((float*)C)[row * N + col] = v;
          else
            ((u16*)C)[row * N + col] = f2bf(v);
        }
  }
}

// QK (1024 blocks, rope fused) + V^T (512 blocks) in one launch
__global__ __launch_bounds__(256)
void gemm_qkv(const u16* __restrict__ xb, const u16* __restrict__ Wqkb,
              const u16* __restrict__ Wvb, u16* __restrict__ QKb, u16* __restrict__ VTb,
              const float* __restrict__ cosb, const float* __restrict__ sinb, float qscale) {
  __shared__ __align__(16) u16 sA[128 * 32];
  __shared__ __align__(16) u16 sB[128 * 32];
  int bid = blockIdx.x;
  if (bid < 1024) {
    int swz = (bid & 7) * 128 + (bid >> 3);
    gemm_tile_body<0, 1>(xb, Wqkb, QKb, 4096, 4096, 2048, swz, sA, sB, cosb, sinb, qscale);
  } else {
    int b2 = bid - 1024;
    int swz = (b2 & 7) * 64 + (b2 >> 3);
    gemm_tile_body<0, 0>(Wvb, xb, VTb, 2048, 4096, 2048, swz, sA, sB, nullptr, nullptr, 0.f);
  }
}

__global__ __launch_bounds__(256)
void gemm_o(const u16* __restrict__ Ob, const u16* __restrict__ Wob, float* __restrict__ out) {
  __shared__ __align__(16) u16 sA[128 * 32];
  __shared__ __align__(16) u16 sB[128 * 32];
  int bid = blockIdx.x;
  int swz = (bid & 7) * 64 + (bid >> 3);
  gemm_tile_body<1, 0>(Ob, Wob, (void*)out, 4096, 2048, 2048, swz, sA, sB, nullptr, nullptr, 0.f);
}

// ---------------- Flash attention (round-3 proven structure; QKb strides) ----------------
// QK: [B*S][4096] bf16 (cols 0-2047 = roped*scaled Q, 2048-4095 = roped K).
// VT: [2048][4096] bf16. O: [B*S][2048] bf16.
// grid 512 = 32 bh * 16 qtiles(128); block 256 = 4 waves * 32 q-rows (2 qf of 16).
// Swapped QK^T / PV, in-lane softmax, K+V double-buffered, __syncthreads per tile.
__global__ __launch_bounds__(256, 2)
void attn_kernel(const u16* __restrict__ QKb, const u16* __restrict__ VT,
                 u16* __restrict__ Ob) {
  __shared__ __align__(16) u16 sK[2][64 * 128];   // 32 KB
  __shared__ __align__(16) u16 sV[2][128 * 64];   // 32 KB
  __shared__ __align__(16) u16 sP[4][32 * 64];    // 16 KB

  int id = blockIdx.x;
  int swz = (id & 7) * 64 + (id >> 3);    // XCD-chunked: 4 heads/XCD -> KV L2-resident
  int bh = swz >> 4;
  int qb = swz & 15;
  int b = bh >> 4, h = bh & 15;
  int t = threadIdx.x, w = t >> 6, l = t & 63;
  int lr = l & 15, lh = l >> 4;
  int lr7 = lr & 7;
  int q0 = qb * 128;

  const u16* Kbase = QKb + (size_t)(b * 2048) * 4096 + 2048 + h * 128;
  const u16* Vbase = VT + (size_t)(h * 128) * 4096 + b * 2048;
  u16* sPw = sP[w];

  // Q fragments (B-operand of swapped QK^T)
  bf16x8 aq[2][4];
#pragma unroll
  for (int qf = 0; qf < 2; ++qf) {
    size_t qrow = (size_t)(b * 2048 + q0 + w * 32 + qf * 16 + lr) * 4096 + h * 128;
#pragma unroll
    for (int c = 0; c < 4; ++c)
      aq[qf][c] = *reinterpret_cast<const bf16x8*>(QKb + qrow + c * 32 + lh * 8);
  }

  f32x4 zero = {0.f, 0.f, 0.f, 0.f};
  f32x4 acc_o[2][8];  // O^T[d][q=lr]
#pragma unroll
  for (int qf = 0; qf < 2; ++qf)
#pragma unroll
    for (int d = 0; d < 8; ++d) acc_o[qf][d] = zero;
  float m_row[2] = {-1e30f, -1e30f};
  float l_row[2] = {0.f, 0.f};

  auto stage = [&](int buf, int kt2) {
    const u16* Kt = Kbase + (size_t)(kt2 * 64) * 4096;
    const u16* Vt = Vbase + kt2 * 64;
#pragma unroll
    for (int it = 0; it < 4; ++it) {
      int o = it * 4096 + t * 16;            // byte offset in 16KB tile
      int rowK = o >> 8;
      int cbK = (o & 255) ^ ((rowK & 7) << 4);
      async_load16((u16*)sK[buf] + (o >> 1), Kt + (size_t)rowK * 4096 + (cbK >> 1));
      int rowV = o >> 7;
      int cbV = (o & 127) ^ ((rowV & 7) << 4);
      async_load16((u16*)sV[buf] + (o >> 1), Vt + (size_t)rowV * 4096 + (cbV >> 1));
    }
  };

  stage(0, 0);
  __syncthreads();
  int cur = 0;

  for (int kt = 0; kt < 32; ++kt) {
    if (kt < 31) stage(cur ^ 1, kt + 1);

    const u16* sKc = sK[cur];
    const u16* sVc = sV[cur];

    // ---- QK^T swapped: sacc[qf][g] = S[k = g*16+lh*4+e][q = lr] ----
    f32x4 sacc[2][4];
#pragma unroll
    for (int qf = 0; qf < 2; ++qf)
#pragma unroll
      for (int g = 0; g < 4; ++g) sacc[qf][g] = zero;
#pragma unroll
    for (int g = 0; g < 4; ++g) {
      int row = g * 16 + lr;
      int xr = lr7 << 4;
#pragma unroll
      for (int c = 0; c < 4; ++c) {
        int cb = (c * 64 + lh * 16) ^ xr;
        bf16x8 bk = *reinterpret_cast<const bf16x8*>(sKc + row * 128 + (cb >> 1));
        sacc[0][g] = __builtin_amdgcn_mfma_f32_16x16x32_bf16(bk, aq[0][c], sacc[0][g], 0, 0, 0);
        sacc[1][g] = __builtin_amdgcn_mfma_f32_16x16x32_bf16(bk, aq[1][c], sacc[1][g], 0, 0, 0);
      }
    }

    // ---- in-lane online softmax (q = lr lane-local) ----
#pragma unroll
    for (int qf = 0; qf < 2; ++qf) {
      f32x4 m4;
#pragma unroll
      for (int e = 0; e < 4; ++e)
        m4[e] = fmaxf(fmaxf(sacc[qf][0][e], sacc[qf][1][e]),
                      fmaxf(sacc[qf][2][e], sacc[qf][3][e]));
      float mx = fmaxf(fmaxf(m4[0], m4[1]), fmaxf(m4[2], m4[3]));
      mx = fmaxf(mx, __shfl_xor(mx, 16));
      mx = fmaxf(mx, __shfl_xor(mx, 32));
      float mo = m_row[qf];
      if (!__all(mx <= mo + 8.f)) {     // T13 defer-max (exp2 space, P <= 2^8)
        float mn = fmaxf(mo, mx);
        float al = __builtin_amdgcn_exp2f(mo - mn);
        m_row[qf] = mn;
        l_row[qf] *= al;
#pragma unroll
        for (int d = 0; d < 8; ++d) acc_o[qf][d] *= al;
      }
      float mn = m_row[qf];
#pragma unroll
      for (int g = 0; g < 4; ++g)
#pragma unroll
        for (int e = 0; e < 4; ++e)
          sacc[qf][g][e] = __builtin_amdgcn_exp2f(sacc[qf][g][e] - mn);
      f32x4 s4;
#pragma unroll
      for (int e = 0; e < 4; ++e)
        s4[e] = (sacc[qf][0][e] + sacc[qf][1][e]) + (sacc[qf][2][e] + sacc[qf][3][e]);
      float rs = (s4[0] + s4[1]) + (s4[2] + s4[3]);
      rs += __shfl_xor(rs, 16);
      rs += __shfl_xor(rs, 32);
      l_row[qf] += rs;

      // pack P to bf16 pairs, write sP[q=lr][k], swizzled
      int rowb = (qf * 16 + lr) * 128;
      int xw = lr7 << 4;
#pragma unroll
      for (int g = 0; g < 4; ++g) {
        uint2 pw;
        pw.x = cvtpk(sacc[qf][g][0], sacc[qf][g][1]);
        pw.y = cvtpk(sacc[qf][g][2], sacc[qf][g][3]);
        int cb = (g * 32 + lh * 8) ^ xw;
        *reinterpret_cast<uint2*>(reinterpret_cast<char*>(sPw) + rowb + cb) = pw;
      }
    }

    // ---- PV swapped: acc_o += VT_tile * P ----
    bf16x8 bp[2][2];
#pragma unroll
    for (int qf = 0; qf < 2; ++qf) {
      int rowb = (qf * 16 + lr) * 128;
      int xr = lr7 << 4;
#pragma unroll
      for (int c2 = 0; c2 < 2; ++c2) {
        int cb = (c2 * 64 + lh * 16) ^ xr;
        bp[qf][c2] = *reinterpret_cast<const bf16x8*>(
            reinterpret_cast<const char*>(sPw) + rowb + cb);
      }
    }
#pragma unroll
    for (int c2 = 0; c2 < 2; ++c2) {
#pragma unroll
      for (int d = 0; d < 8; ++d) {
        int row = d * 16 + lr;
        int cb = (c2 * 64 + lh * 16) ^ (lr7 << 4);
        bf16x8 bv = *reinterpret_cast<const bf16x8*>(sVc + row * 64 + (cb >> 1));
        acc_o[0][d] = __builtin_amdgcn_mfma_f32_16x16x32_bf16(bv, bp[0][c2], acc_o[0][d], 0, 0, 0);
        acc_o[1][d] = __builtin_amdgcn_mfma_f32_16x16x32_bf16(bv, bp[1][c2], acc_o[1][d], 0, 0, 0);
      }
    }

    __syncthreads();  // next tile staged; cur fully consumed
    cur ^= 1;
  }

  // ---- epilogue: normalize in-lane, vector store ----
#pragma unroll
  for (int qf = 0; qf < 2; ++qf) {
    float inv = 1.f / l_row[qf];
    size_t qrow = (size_t)(b * 2048 + q0 + w * 32 + qf * 16 + lr) * 2048 + h * 128;
#pragma unroll
    for (int d = 0; d < 8; ++d) {
      ushort4 o;
      o.x = f2bf(acc_o[qf][d][0] * inv);
      o.y = f2bf(acc_o[qf][d][1] * inv);
      o.z = f2bf(acc_o[qf][d][2] * inv);
      o.w = f2bf(acc_o[qf][d][3] * inv);
      *reinterpret_cast<ushort4*>(Ob + qrow + d * 16 + lh * 4) = o;
    }
  }
}

extern "C" void kernel_launch(void* const* d_in, const int* in_sizes, int n_in,
                              void* d_out, int out_size, void* d_ws, size_t ws_size,
                              hipStream_t stream) {
  const float* x  = (const float*)d_in[0];
  const float* rc = (const float*)d_in[1];
  const float* rs = (const float*)d_in[2];
  const float* Wq = (const float*)d_in[3];
  const float* Wk = (const float*)d_in[4];
  const float* Wv = (const float*)d_in[5];
  const float* Wo = (const float*)d_in[6];
  float* out = (float*)d_out;
  char* ws = (char*)d_ws;
  const size_t MB = 1024 * 1024;
  // layout (96 MB): Ob aliases Wqkb (dead after QK GEMM)
  u16* xb   = (u16*)(ws);            // 16 MB
  u16* Wqkb = (u16*)(ws + 16 * MB);  // 16 MB  [4096][2048] = [Wq;Wk]
  u16* Wvb  = (u16*)(ws + 32 * MB);  // 8 MB
  u16* Wob  = (u16*)(ws + 40 * MB);  // 8 MB
  u16* QKb  = (u16*)(ws + 48 * MB);  // 32 MB  [4096][4096]
  u16* VTb  = (u16*)(ws + 80 * MB);  // 16 MB  [2048][4096]
  u16* Ob   = (u16*)(ws + 16 * MB);  // 16 MB  (alias Wqkb)

  convert_all<<<24576, 256, 0, stream>>>(x, Wq, Wk, Wv, Wo, xb, Wqkb, Wvb, Wob);

  const float qscale = 0.08838834764831845f * 1.4426950408889634f;  // 1/sqrt(128)*log2(e)
  gemm_qkv<<<1536, 256, 0, stream>>>(xb, Wqkb, Wvb, QKb, VTb, rc, rs, qscale);

  attn_kernel<<<512, 256, 0, stream>>>(QKb, VTb, Ob);

  gemm_o<<<512, 256, 0, stream>>>(Ob, Wob, out);
}

// Round 7
// 281.770 us; speedup vs baseline: 1.2031x; 1.0060x over previous
//
#include <hip/hip_runtime.h>
#include <hip/hip_bf16.h>

typedef unsigned short u16;
typedef __bf16 bf16x8 __attribute__((ext_vector_type(8)));
typedef float f32x4 __attribute__((ext_vector_type(4)));

__device__ __forceinline__ float bf2f(u16 u) {
  union { unsigned int i; float f; } v; v.i = ((unsigned int)u) << 16; return v.f;
}
__device__ __forceinline__ u16 f2bf(float f) {
  union { float f; unsigned int i; } v; v.f = f;
  unsigned int r = v.i + 0x7fffu + ((v.i >> 16) & 1u);
  return (u16)(r >> 16);
}
__device__ __forceinline__ unsigned cvtpk(float lo, float hi) {
  unsigned r;
  asm("v_cvt_pk_bf16_f32 %0, %1, %2" : "=v"(r) : "v"(lo), "v"(hi));
  return r;
}

__device__ __forceinline__ void async_load16(void* lds, const void* g) {
  __builtin_amdgcn_global_load_lds((const __attribute__((address_space(1))) void*)g,
                                   (__attribute__((address_space(3))) void*)lds, 16, 0, 0);
}

// ---------------- fused fp32 -> bf16 convert (x, Wq|Wk -> Wqk, Wv, Wo) ----------------
__global__ void convert_all(const float* __restrict__ x, const float* __restrict__ Wq,
                            const float* __restrict__ Wk, const float* __restrict__ Wv,
                            const float* __restrict__ Wo, u16* __restrict__ xb,
                            u16* __restrict__ Wqkb, u16* __restrict__ Wvb,
                            u16* __restrict__ Wob) {
  int bid = blockIdx.x;
  const float* src;
  u16* dst;
  int off;
  if (bid < 8192)       { src = x;  dst = xb;              off = bid; }
  else if (bid < 12288) { src = Wq; dst = Wqkb;            off = bid - 8192; }
  else if (bid < 16384) { src = Wk; dst = Wqkb + 4194304;  off = bid - 12288; }
  else if (bid < 20480) { src = Wv; dst = Wvb;             off = bid - 16384; }
  else                  { src = Wo; dst = Wob;             off = bid - 20480; }
  int i = off * 1024 + threadIdx.x * 4;
  float4 v = *(const float4*)(src + i);
  ushort4 o;
  o.x = f2bf(v.x); o.y = f2bf(v.y); o.z = f2bf(v.z); o.w = f2bf(v.w);
  *(ushort4*)(dst + i) = o;
}

// ======== 256x256 8-wave GEMM, ring-4 of BK=32 sub-tiles, counted vmcnt ========
// C[M,N] = A[M,K] * B[N,K]^T, A/B row-major bf16. 512 threads = 8 waves (2M x 4N),
// wave (wm,wn) owns rows wm*128+.., cols per frag map. LDS 128KB = 4 ring bufs x
// (A 256x32 + B 256x32). Step s: vmcnt(8) [sub-tile s landed, s+1/s+2 in flight],
// barrier, stage(s+3), 12 ds_read_b128, setprio{32 MFMA}. One barrier per step;
// never drains vmcnt in main loop. ROPE=1: N-frags permuted so (d,d+64) pairs are
// acc[mi][ni] / acc[mi][ni+2] in-lane; rope applied on fp32 acc in epilogue.
template <int ROPE>
__device__ __forceinline__ void gemm256_body(const u16* __restrict__ A,
                                             const u16* __restrict__ Bm,
                                             u16* __restrict__ C, int M, int N, int K,
                                             int tm, int tn, u16* lds,
                                             const float* __restrict__ cosb,
                                             const float* __restrict__ sinb,
                                             float qscale) {
  const int t = threadIdx.x;            // 0..511
  const int w = t >> 6, l = t & 63;
  const int wm = w >> 2, wn = w & 3;
  const int lr = l & 15, lh = l >> 4;
  const size_t row0 = (size_t)tm * 256, col0 = (size_t)tn * 256;
  const u16* Ag = A + row0 * K;
  const u16* Bg = Bm + col0 * K;

  // stage sub-tile s into ring buf s%4 (linear LDS dest: per-wave base + lane*16B)
  const int ra = t >> 2, kc = (t & 3) << 3;
  auto stage = [&](int s) {
    u16* dst = lds + (s & 3) * 16384;
    const size_t koff = (size_t)s * 32 + kc;
    async_load16(dst + t * 8,         Ag + (size_t)ra * K + koff);           // A rows 0-127
    async_load16(dst + 4096 + t * 8,  Ag + (size_t)(ra + 128) * K + koff);   // A rows 128-255
    async_load16(dst + 8192 + t * 8,  Bg + (size_t)ra * K + koff);           // B rows 0-127
    async_load16(dst + 12288 + t * 8, Bg + (size_t)(ra + 128) * K + koff);   // B rows 128-255
  };

  f32x4 acc[8][4];
#pragma unroll
  for (int i = 0; i < 8; ++i)
#pragma unroll
    for (int j = 0; j < 4; ++j) acc[i][j] = (f32x4){0.f, 0.f, 0.f, 0.f};

  const int NK = K >> 5;
  stage(0); stage(1); stage(2);

  for (int s = 0; s < NK; ++s) {
    if (s + 2 < NK)      asm volatile("s_waitcnt vmcnt(8)" ::: "memory");
    else if (s + 1 < NK) asm volatile("s_waitcnt vmcnt(4)" ::: "memory");
    else                 asm volatile("s_waitcnt vmcnt(0)" ::: "memory");
    __builtin_amdgcn_s_barrier();
    asm volatile("" ::: "memory");      // compiler fence: no LDS reads hoist above barrier
    if (s + 3 < NK) stage(s + 3);

    const u16* sub = lds + (s & 3) * 16384;
    bf16x8 af[8], bfv[4];
#pragma unroll
    for (int mi = 0; mi < 8; ++mi)
      af[mi] = *reinterpret_cast<const bf16x8*>(sub + (wm * 128 + mi * 16 + lr) * 32 + lh * 8);
#pragma unroll
    for (int ni = 0; ni < 4; ++ni) {
      int colf = ROPE ? ((wn >> 1) * 128 + (wn & 1) * 32 + (ni >> 1) * 64 + (ni & 1) * 16)
                      : (wn * 64 + ni * 16);
      bfv[ni] = *reinterpret_cast<const bf16x8*>(sub + 8192 + (colf + lr) * 32 + lh * 8);
    }
    __builtin_amdgcn_s_setprio(1);
#pragma unroll
    for (int mi = 0; mi < 8; ++mi)
#pragma unroll
      for (int ni = 0; ni < 4; ++ni)
        acc[mi][ni] = __builtin_amdgcn_mfma_f32_16x16x32_bf16(af[mi], bfv[ni], acc[mi][ni], 0, 0, 0);
    __builtin_amdgcn_s_setprio(0);
  }

  if (ROPE) {
    float scale = (2 * tn + (wn >> 1)) < 16 ? qscale : 1.0f;
    size_t colbase = col0 + (wn >> 1) * 128;
#pragma unroll
    for (int mi = 0; mi < 8; ++mi)
#pragma unroll
      for (int r = 0; r < 4; ++r) {
        size_t row = row0 + wm * 128 + mi * 16 + lh * 4 + r;
        int si = (int)(row & 2047);
        const float* cr = cosb + si * 128;
        const float* sr = sinb + si * 128;
#pragma unroll
        for (int ni = 0; ni < 2; ++ni) {
          int dlo = (wn & 1) * 32 + ni * 16 + lr;
          float v0 = acc[mi][ni][r];
          float v1 = acc[mi][ni + 2][r];
          float o0 = (v0 * cr[dlo] - v1 * sr[dlo]) * scale;
          float o1 = (v1 * cr[64 + dlo] + v0 * sr[64 + dlo]) * scale;
          C[row * N + colbase + dlo]      = f2bf(o0);
          C[row * N + colbase + 64 + dlo] = f2bf(o1);
        }
      }
  } else {
#pragma unroll
    for (int mi = 0; mi < 8; ++mi)
#pragma unroll
      for (int ni = 0; ni < 4; ++ni)
#pragma unroll
        for (int r = 0; r < 4; ++r) {
          size_t row = row0 + wm * 128 + mi * 16 + lh * 4 + r;
          size_t col = col0 + wn * 64 + ni * 16 + lr;
          C[row * N + col] = f2bf(acc[mi][ni][r]);
        }
  }
}

// QK (256 blocks, rope fused) + V^T (128 blocks) in one 512-thread launch
__global__ __launch_bounds__(512, 2)
void gemm_qkv256(const u16* __restrict__ xb, const u16* __restrict__ Wqkb,
                 const u16* __restrict__ Wvb, u16* __restrict__ QKb, u16* __restrict__ VTb,
                 const float* __restrict__ cosb, const float* __restrict__ sinb,
                 float qscale) {
  __shared__ __align__(16) u16 lds[4 * 16384];  // 128 KB
  int bid = blockIdx.x;
  if (bid < 256) {
    int swz = (bid & 7) * 32 + (bid >> 3);      // XCD-chunked, 256%8==0
    gemm256_body<1>(xb, Wqkb, QKb, 4096, 4096, 2048, swz >> 4, swz & 15, lds,
                    cosb, sinb, qscale);
  } else {
    int b2 = bid - 256;
    int swz = (b2 & 7) * 16 + (b2 >> 3);        // 128%8==0
    gemm256_body<0>(Wvb, xb, VTb, 2048, 4096, 2048, swz >> 4, swz & 15, lds,
                    nullptr, nullptr, 0.f);
  }
}

// ---------------- m97 128x128 GEMM body (kept for gemm_o) ----------------
template <int OUT_F32>
__device__ __forceinline__ void gemm_tile_body(const u16* __restrict__ A,
                                               const u16* __restrict__ Bm,
                                               void* __restrict__ C, int M, int N, int K,
                                               int swz, u16* sA, u16* sB) {
  const int nTn = N >> 7;
  int tm = swz / nTn, tn = swz % nTn;
  const int t = threadIdx.x;
  const int w = t >> 6, l = t & 63;
  const int wr = w >> 1, wc = w & 1;
  const int lr = l & 15, lh = l >> 4;
  const size_t row0 = (size_t)tm * 128, col0 = (size_t)tn * 128;

  f32x4 zero = {0.f, 0.f, 0.f, 0.f};
  f32x4 acc[4][4];
#pragma unroll
  for (int i = 0; i < 4; ++i)
#pragma unroll
    for (int j = 0; j < 4; ++j) acc[i][j] = zero;

  const u16* Ag = A + row0 * K;
  const u16* Bg = Bm + col0 * K;

  for (int k0 = 0; k0 < K; k0 += 32) {
#pragma unroll
    for (int i = 0; i < 2; ++i) {
      int c = i * 256 + t;
      int r = c >> 2, kk = (c & 3) << 3;
      async_load16(sA + (((size_t)i * 256 + w * 64) << 3), Ag + (size_t)r * K + k0 + kk);
      async_load16(sB + (((size_t)i * 256 + w * 64) << 3), Bg + (size_t)r * K + k0 + kk);
    }
    __syncthreads();
    bf16x8 af[4], bfr[4];
#pragma unroll
    for (int mi = 0; mi < 4; ++mi)
      af[mi] = *reinterpret_cast<const bf16x8*>(sA + (wr * 64 + mi * 16 + lr) * 32 + lh * 8);
#pragma unroll
    for (int ni = 0; ni < 4; ++ni)
      bfr[ni] = *reinterpret_cast<const bf16x8*>(sB + (wc * 64 + ni * 16 + lr) * 32 + lh * 8);
#pragma unroll
    for (int mi = 0; mi < 4; ++mi)
#pragma unroll
      for (int ni = 0; ni < 4; ++ni)
        acc[mi][ni] = __builtin_amdgcn_mfma_f32_16x16x32_bf16(af[mi], bfr[ni], acc[mi][ni], 0, 0, 0);
    __syncthreads();
  }

#pragma unroll
  for (int mi = 0; mi < 4; ++mi)
#pragma unroll
    for (int ni = 0; ni < 4; ++ni)
#pragma unroll
      for (int r = 0; r < 4; ++r) {
        size_t row = row0 + wr * 64 + mi * 16 + lh * 4 + r;
        size_t col = col0 + wc * 64 + ni * 16 + lr;
        float v = acc[mi][ni][r];
        if (OUT_F32)
          ((float*)C)[row * N + col] = v;
        else
          ((u16*)C)[row * N + col] = f2bf(v);
      }
}

__global__ __launch_bounds__(256)
void gemm_o(const u16* __restrict__ Ob, const u16* __restrict__ Wob, float* __restrict__ out) {
  __shared__ __align__(16) u16 sA[128 * 32];
  __shared__ __align__(16) u16 sB[128 * 32];
  int bid = blockIdx.x;
  int swz = (bid & 7) * 64 + (bid >> 3);
  gemm_tile_body<1>(Ob, Wob, (void*)out, 4096, 2048, 2048, swz, sA, sB);
}

// ---------------- Flash attention (proven structure; QKb strides) ----------------
// QK: [B*S][4096] bf16 (cols 0-2047 = roped*scaled Q, 2048-4095 = roped K).
// VT: [2048][4096] bf16. O: [B*S][2048] bf16.
// grid 512 = 32 bh * 16 qtiles(128); block 256 = 4 waves * 32 q-rows (2 qf of 16).
// Swapped QK^T / PV, in-lane softmax, K+V double-buffered, __syncthreads per tile.
__global__ __launch_bounds__(256, 2)
void attn_kernel(const u16* __restrict__ QKb, const u16* __restrict__ VT,
                 u16* __restrict__ Ob) {
  __shared__ __align__(16) u16 sK[2][64 * 128];   // 32 KB
  __shared__ __align__(16) u16 sV[2][128 * 64];   // 32 KB
  __shared__ __align__(16) u16 sP[4][32 * 64];    // 16 KB

  int id = blockIdx.x;
  int swz = (id & 7) * 64 + (id >> 3);    // XCD-chunked: 4 heads/XCD -> KV L2-resident
  int bh = swz >> 4;
  int qb = swz & 15;
  int b = bh >> 4, h = bh & 15;
  int t = threadIdx.x, w = t >> 6, l = t & 63;
  int lr = l & 15, lh = l >> 4;
  int lr7 = lr & 7;
  int q0 = qb * 128;

  const u16* Kbase = QKb + (size_t)(b * 2048) * 4096 + 2048 + h * 128;
  const u16* Vbase = VT + (size_t)(h * 128) * 4096 + b * 2048;
  u16* sPw = sP[w];

  // Q fragments (B-operand of swapped QK^T)
  bf16x8 aq[2][4];
#pragma unroll
  for (int qf = 0; qf < 2; ++qf) {
    size_t qrow = (size_t)(b * 2048 + q0 + w * 32 + qf * 16 + lr) * 4096 + h * 128;
#pragma unroll
    for (int c = 0; c < 4; ++c)
      aq[qf][c] = *reinterpret_cast<const bf16x8*>(QKb + qrow + c * 32 + lh * 8);
  }

  f32x4 zero = {0.f, 0.f, 0.f, 0.f};
  f32x4 acc_o[2][8];  // O^T[d][q=lr]
#pragma unroll
  for (int qf = 0; qf < 2; ++qf)
#pragma unroll
    for (int d = 0; d < 8; ++d) acc_o[qf][d] = zero;
  float m_row[2] = {-1e30f, -1e30f};
  float l_row[2] = {0.f, 0.f};

  auto stage = [&](int buf, int kt2) {
    const u16* Kt = Kbase + (size_t)(kt2 * 64) * 4096;
    const u16* Vt = Vbase + kt2 * 64;
#pragma unroll
    for (int it = 0; it < 4; ++it) {
      int o = it * 4096 + t * 16;            // byte offset in 16KB tile
      int rowK = o >> 8;
      int cbK = (o & 255) ^ ((rowK & 7) << 4);
      async_load16((u16*)sK[buf] + (o >> 1), Kt + (size_t)rowK * 4096 + (cbK >> 1));
      int rowV = o >> 7;
      int cbV = (o & 127) ^ ((rowV & 7) << 4);
      async_load16((u16*)sV[buf] + (o >> 1), Vt + (size_t)rowV * 4096 + (cbV >> 1));
    }
  };

  stage(0, 0);
  __syncthreads();
  int cur = 0;

  for (int kt = 0; kt < 32; ++kt) {
    if (kt < 31) stage(cur ^ 1, kt + 1);

    const u16* sKc = sK[cur];
    const u16* sVc = sV[cur];

    // ---- QK^T swapped: sacc[qf][g] = S[k = g*16+lh*4+e][q = lr] ----
    f32x4 sacc[2][4];
#pragma unroll
    for (int qf = 0; qf < 2; ++qf)
#pragma unroll
      for (int g = 0; g < 4; ++g) sacc[qf][g] = zero;
#pragma unroll
    for (int g = 0; g < 4; ++g) {
      int row = g * 16 + lr;
      int xr = lr7 << 4;
#pragma unroll
      for (int c = 0; c < 4; ++c) {
        int cb = (c * 64 + lh * 16) ^ xr;
        bf16x8 bk = *reinterpret_cast<const bf16x8*>(sKc + row * 128 + (cb >> 1));
        sacc[0][g] = __builtin_amdgcn_mfma_f32_16x16x32_bf16(bk, aq[0][c], sacc[0][g], 0, 0, 0);
        sacc[1][g] = __builtin_amdgcn_mfma_f32_16x16x32_bf16(bk, aq[1][c], sacc[1][g], 0, 0, 0);
      }
    }

    // ---- in-lane online softmax (q = lr lane-local) ----
#pragma unroll
    for (int qf = 0; qf < 2; ++qf) {
      f32x4 m4;
#pragma unroll
      for (int e = 0; e < 4; ++e)
        m4[e] = fmaxf(fmaxf(sacc[qf][0][e], sacc[qf][1][e]),
                      fmaxf(sacc[qf][2][e], sacc[qf][3][e]));
      float mx = fmaxf(fmaxf(m4[0], m4[1]), fmaxf(m4[2], m4[3]));
      mx = fmaxf(mx, __shfl_xor(mx, 16));
      mx = fmaxf(mx, __shfl_xor(mx, 32));
      float mo = m_row[qf];
      if (!__all(mx <= mo + 8.f)) {     // T13 defer-max (exp2 space, P <= 2^8)
        float mn = fmaxf(mo, mx);
        float al = __builtin_amdgcn_exp2f(mo - mn);
        m_row[qf] = mn;
        l_row[qf] *= al;
#pragma unroll
        for (int d = 0; d < 8; ++d) acc_o[qf][d] *= al;
      }
      float mn = m_row[qf];
#pragma unroll
      for (int g = 0; g < 4; ++g)
#pragma unroll
        for (int e = 0; e < 4; ++e)
          sacc[qf][g][e] = __builtin_amdgcn_exp2f(sacc[qf][g][e] - mn);
      f32x4 s4;
#pragma unroll
      for (int e = 0; e < 4; ++e)
        s4[e] = (sacc[qf][0][e] + sacc[qf][1][e]) + (sacc[qf][2][e] + sacc[qf][3][e]);
      float rs = (s4[0] + s4[1]) + (s4[2] + s4[3]);
      rs += __shfl_xor(rs, 16);
      rs += __shfl_xor(rs, 32);
      l_row[qf] += rs;

      // pack P to bf16 pairs, write sP[q=lr][k], swizzled
      int rowb = (qf * 16 + lr) * 128;
      int xw = lr7 << 4;
#pragma unroll
      for (int g = 0; g < 4; ++g) {
        uint2 pw;
        pw.x = cvtpk(sacc[qf][g][0], sacc[qf][g][1]);
        pw.y = cvtpk(sacc[qf][g][2], sacc[qf][g][3]);
        int cb = (g * 32 + lh * 8) ^ xw;
        *reinterpret_cast<uint2*>(reinterpret_cast<char*>(sPw) + rowb + cb) = pw;
      }
    }

    // ---- PV swapped: acc_o += VT_tile * P ----
    bf16x8 bp[2][2];
#pragma unroll
    for (int qf = 0; qf < 2; ++qf) {
      int rowb = (qf * 16 + lr) * 128;
      int xr = lr7 << 4;
#pragma unroll
      for (int c2 = 0; c2 < 2; ++c2) {
        int cb = (c2 * 64 + lh * 16) ^ xr;
        bp[qf][c2] = *reinterpret_cast<const bf16x8*>(
            reinterpret_cast<const char*>(sPw) + rowb + cb);
      }
    }
#pragma unroll
    for (int c2 = 0; c2 < 2; ++c2) {
#pragma unroll
      for (int d = 0; d < 8; ++d) {
        int row = d * 16 + lr;
        int cb = (c2 * 64 + lh * 16) ^ (lr7 << 4);
        bf16x8 bv = *reinterpret_cast<const bf16x8*>(sVc + row * 64 + (cb >> 1));
        acc_o[0][d] = __builtin_amdgcn_mfma_f32_16x16x32_bf16(bv, bp[0][c2], acc_o[0][d], 0, 0, 0);
        acc_o[1][d] = __builtin_amdgcn_mfma_f32_16x16x32_bf16(bv, bp[1][c2], acc_o[1][d], 0, 0, 0);
      }
    }

    __syncthreads();  // next tile staged; cur fully consumed
    cur ^= 1;
  }

  // ---- epilogue: normalize in-lane, vector store ----
#pragma unroll
  for (int qf = 0; qf < 2; ++qf) {
    float inv = 1.f / l_row[qf];
    size_t qrow = (size_t)(b * 2048 + q0 + w * 32 + qf * 16 + lr) * 2048 + h * 128;
#pragma unroll
    for (int d = 0; d < 8; ++d) {
      ushort4 o;
      o.x = f2bf(acc_o[qf][d][0] * inv);
      o.y = f2bf(acc_o[qf][d][1] * inv);
      o.z = f2bf(acc_o[qf][d][2] * inv);
      o.w = f2bf(acc_o[qf][d][3] * inv);
      *reinterpret_cast<ushort4*>(Ob + qrow + d * 16 + lh * 4) = o;
    }
  }
}

extern "C" void kernel_launch(void* const* d_in, const int* in_sizes, int n_in,
                              void* d_out, int out_size, void* d_ws, size_t ws_size,
                              hipStream_t stream) {
  const float* x  = (const float*)d_in[0];
  const float* rc = (const float*)d_in[1];
  const float* rs = (const float*)d_in[2];
  const float* Wq = (const float*)d_in[3];
  const float* Wk = (const float*)d_in[4];
  const float* Wv = (const float*)d_in[5];
  const float* Wo = (const float*)d_in[6];
  float* out = (float*)d_out;
  char* ws = (char*)d_ws;
  const size_t MB = 1024 * 1024;
  // layout (96 MB): Ob aliases Wqkb (dead after QK GEMM)
  u16* xb   = (u16*)(ws);            // 16 MB
  u16* Wqkb = (u16*)(ws + 16 * MB);  // 16 MB  [4096][2048] = [Wq;Wk]
  u16* Wvb  = (u16*)(ws + 32 * MB);  // 8 MB
  u16* Wob  = (u16*)(ws + 40 * MB);  // 8 MB
  u16* QKb  = (u16*)(ws + 48 * MB);  // 32 MB  [4096][4096]
  u16* VTb  = (u16*)(ws + 80 * MB);  // 16 MB  [2048][4096]
  u16* Ob   = (u16*)(ws + 16 * MB);  // 16 MB  (alias Wqkb)

  convert_all<<<24576, 256, 0, stream>>>(x, Wq, Wk, Wv, Wo, xb, Wqkb, Wvb, Wob);

  const float qscale = 0.08838834764831845f * 1.4426950408889634f;  // 1/sqrt(128)*log2(e)
  gemm_qkv256<<<384, 512, 0, stream>>>(xb, Wqkb, Wvb, QKb, VTb, rc, rs, qscale);

  attn_kernel<<<512, 256, 0, stream>>>(QKb, VTb, Ob);

  gemm_o<<<512, 256, 0, stream>>>(Ob, Wob, out);
}

// Round 8
// 255.031 us; speedup vs baseline: 1.3292x; 1.1048x over previous
//
#include <hip/hip_runtime.h>
#include <hip/hip_bf16.h>

typedef unsigned short u16;
typedef __bf16 bf16x8 __attribute__((ext_vector_type(8)));
typedef float f32x4 __attribute__((ext_vector_type(4)));

__device__ __forceinline__ float bf2f(u16 u) {
  union { unsigned int i; float f; } v; v.i = ((unsigned int)u) << 16; return v.f;
}
__device__ __forceinline__ u16 f2bf(float f) {
  union { float f; unsigned int i; } v; v.f = f;
  unsigned int r = v.i + 0x7fffu + ((v.i >> 16) & 1u);
  return (u16)(r >> 16);
}
__device__ __forceinline__ unsigned cvtpk(float lo, float hi) {
  unsigned r;
  asm("v_cvt_pk_bf16_f32 %0, %1, %2" : "=v"(r) : "v"(lo), "v"(hi));
  return r;
}

__device__ __forceinline__ void async_load16(void* lds, const void* g) {
  __builtin_amdgcn_global_load_lds((const __attribute__((address_space(1))) void*)g,
                                   (__attribute__((address_space(3))) void*)lds, 16, 0, 0);
}

// ---------------- fused fp32 -> bf16 convert (x, Wq|Wk -> Wqk, Wv, Wo) ----------------
__global__ void convert_all(const float* __restrict__ x, const float* __restrict__ Wq,
                            const float* __restrict__ Wk, const float* __restrict__ Wv,
                            const float* __restrict__ Wo, u16* __restrict__ xb,
                            u16* __restrict__ Wqkb, u16* __restrict__ Wvb,
                            u16* __restrict__ Wob) {
  int bid = blockIdx.x;
  const float* src;
  u16* dst;
  int off;
  if (bid < 8192)       { src = x;  dst = xb;              off = bid; }
  else if (bid < 12288) { src = Wq; dst = Wqkb;            off = bid - 8192; }
  else if (bid < 16384) { src = Wk; dst = Wqkb + 4194304;  off = bid - 12288; }
  else if (bid < 20480) { src = Wv; dst = Wvb;             off = bid - 16384; }
  else                  { src = Wo; dst = Wob;             off = bid - 20480; }
  int i = off * 1024 + threadIdx.x * 4;
  float4 v = *(const float4*)(src + i);
  ushort4 o;
  o.x = f2bf(v.x); o.y = f2bf(v.y); o.z = f2bf(v.z); o.w = f2bf(v.w);
  *(ushort4*)(dst + i) = o;
}

// ======== pipelined GEMM body: BM x 256 tile, ring-4 BK=32, reg-dbuf A-frags ========
// C[M,N] = A[M,K]*B[N,K]^T bf16. 512 thr = 8 waves (wm = row half, wn = col quarter).
// BMHALF = 128 (BM=256) or 64 (BM=128). Ring-4 LDS sub-tiles; per step s:
//   vmcnt(L) [buf s+1 landed; s+2,(s+3) in flight] -> barrier -> stage(s+3)
//   -> ds_read bfv(s) JIT -> ds_read af(s+1) into ALTERNATE reg set
//   -> setprio{ MFMA on af(s) read LAST step — no same-step lgkm dependency }.
// 2x-unrolled loop with named afA/afB sets (static indexing). NK must be even.
// ROPE=1: B-frags permuted so (d,d+64) = acc[mi][ni]/acc[mi][ni+2] in-lane.
template <int BMHALF, int ROPE, int OUT_F32>
__device__ __forceinline__ void gemm_pipe_body(const u16* __restrict__ A,
                                               const u16* __restrict__ Bm,
                                               void* __restrict__ C, int M, int N, int K,
                                               int tm, int tn, u16* lds,
                                               const float* __restrict__ cosb,
                                               const float* __restrict__ sinb,
                                               float qscale) {
  constexpr int MIc = BMHALF / 16;
  constexpr int SUBU16 = (BMHALF == 128) ? 16384 : 12288;  // u16 per ring slot
  constexpr int BOFF = (BMHALF == 128) ? 8192 : 4096;      // B region offset (u16)
  const int t = threadIdx.x;
  const int w = t >> 6, l = t & 63;
  const int wm = w >> 2, wn = w & 3;
  const int lr = l & 15, lh = l >> 4;
  const size_t row0 = (size_t)tm * (2 * BMHALF), col0 = (size_t)tn * 256;
  const u16* Ag = A + row0 * K;
  const u16* Bg = Bm + col0 * K;

  const int ra = t >> 2, kc = (t & 3) << 3;
  auto stage = [&](int s) {
    u16* dst = lds + (s & 3) * SUBU16;
    const size_t koff = (size_t)s * 32 + kc;
    if constexpr (BMHALF == 128) {
      async_load16(dst + t * 8,         Ag + (size_t)ra * K + koff);
      async_load16(dst + 4096 + t * 8,  Ag + (size_t)(ra + 128) * K + koff);
      async_load16(dst + 8192 + t * 8,  Bg + (size_t)ra * K + koff);
      async_load16(dst + 12288 + t * 8, Bg + (size_t)(ra + 128) * K + koff);
    } else {
      async_load16(dst + t * 8,         Ag + (size_t)ra * K + koff);
      async_load16(dst + 4096 + t * 8,  Bg + (size_t)ra * K + koff);
      async_load16(dst + 8192 + t * 8,  Bg + (size_t)(ra + 128) * K + koff);
    }
  };
  auto read_af = [&](bf16x8* dst, int s) {
    const u16* sub = lds + (s & 3) * SUBU16;
#pragma unroll
    for (int mi = 0; mi < MIc; ++mi)
      dst[mi] = *reinterpret_cast<const bf16x8*>(sub + (wm * BMHALF + mi * 16 + lr) * 32 + lh * 8);
  };
  auto read_bfv = [&](bf16x8* dst, int s) {
    const u16* sub = lds + (s & 3) * SUBU16 + BOFF;
#pragma unroll
    for (int ni = 0; ni < 4; ++ni) {
      int colf = ROPE ? ((wn >> 1) * 128 + (wn & 1) * 32 + (ni >> 1) * 64 + (ni & 1) * 16)
                      : (wn * 64 + ni * 16);
      dst[ni] = *reinterpret_cast<const bf16x8*>(sub + (colf + lr) * 32 + lh * 8);
    }
  };

  f32x4 acc[MIc][4];
#pragma unroll
  for (int i = 0; i < MIc; ++i)
#pragma unroll
    for (int j = 0; j < 4; ++j) acc[i][j] = (f32x4){0.f, 0.f, 0.f, 0.f};

  const int NK = K >> 5;  // even
  bf16x8 afA[MIc], afB[MIc], bfv[4];

  stage(0); stage(1); stage(2);
  if constexpr (BMHALF == 128) asm volatile("s_waitcnt vmcnt(8)" ::: "memory");
  else                         asm volatile("s_waitcnt vmcnt(6)" ::: "memory");
  __builtin_amdgcn_s_barrier();
  asm volatile("" ::: "memory");
  read_af(afA, 0);

  auto pipestep = [&](int s, bf16x8* cur, bf16x8* nxt) {
    if (s + 2 < NK) {
      if constexpr (BMHALF == 128) asm volatile("s_waitcnt vmcnt(4)" ::: "memory");
      else                         asm volatile("s_waitcnt vmcnt(3)" ::: "memory");
    } else {
      asm volatile("s_waitcnt vmcnt(0)" ::: "memory");
    }
    __builtin_amdgcn_s_barrier();
    asm volatile("" ::: "memory");
    if (s + 3 < NK) stage(s + 3);
    read_bfv(bfv, s);                  // JIT (first in DS queue: MFMA waits only these)
    if (s + 1 < NK) read_af(nxt, s + 1);  // prefetch into alternate set
    __builtin_amdgcn_s_setprio(1);
#pragma unroll
    for (int mi = 0; mi < MIc; ++mi)
#pragma unroll
      for (int ni = 0; ni < 4; ++ni)
        acc[mi][ni] = __builtin_amdgcn_mfma_f32_16x16x32_bf16(cur[mi], bfv[ni], acc[mi][ni], 0, 0, 0);
    __builtin_amdgcn_s_setprio(0);
  };

  for (int s = 0; s < NK; s += 2) {
    pipestep(s, afA, afB);
    pipestep(s + 1, afB, afA);
  }

  if constexpr (ROPE) {
    float scale = (2 * tn + (wn >> 1)) < 16 ? qscale : 1.0f;
    size_t colbase = col0 + (wn >> 1) * 128;
#pragma unroll
    for (int mi = 0; mi < MIc; ++mi)
#pragma unroll
      for (int r = 0; r < 4; ++r) {
        size_t row = row0 + wm * BMHALF + mi * 16 + lh * 4 + r;
        int si = (int)(row & 2047);
        const float* cr = cosb + si * 128;
        const float* sr = sinb + si * 128;
#pragma unroll
        for (int ni = 0; ni < 2; ++ni) {
          int dlo = (wn & 1) * 32 + ni * 16 + lr;
          float v0 = acc[mi][ni][r];
          float v1 = acc[mi][ni + 2][r];
          float o0 = (v0 * cr[dlo] - v1 * sr[dlo]) * scale;
          float o1 = (v1 * cr[64 + dlo] + v0 * sr[64 + dlo]) * scale;
          ((u16*)C)[row * N + colbase + dlo]      = f2bf(o0);
          ((u16*)C)[row * N + colbase + 64 + dlo] = f2bf(o1);
        }
      }
  } else {
#pragma unroll
    for (int mi = 0; mi < MIc; ++mi)
#pragma unroll
      for (int ni = 0; ni < 4; ++ni)
#pragma unroll
        for (int r = 0; r < 4; ++r) {
          size_t row = row0 + wm * BMHALF + mi * 16 + lh * 4 + r;
          size_t col = col0 + wn * 64 + ni * 16 + lr;
          float v = acc[mi][ni][r];
          if (OUT_F32)
            ((float*)C)[row * N + col] = v;
          else
            ((u16*)C)[row * N + col] = f2bf(v);
        }
  }
}

// QK (256 blocks, 256x256, rope fused) + V^T (256 blocks, 128x256): 512 = 2 exact rounds
__global__ __launch_bounds__(512, 2)
void gemm_qkv256(const u16* __restrict__ xb, const u16* __restrict__ Wqkb,
                 const u16* __restrict__ Wvb, u16* __restrict__ QKb, u16* __restrict__ VTb,
                 const float* __restrict__ cosb, const float* __restrict__ sinb,
                 float qscale) {
  __shared__ __align__(16) u16 lds[4 * 16384];  // 128 KB
  int bid = blockIdx.x;
  if (bid < 256) {
    int swz = (bid & 7) * 32 + (bid >> 3);
    gemm_pipe_body<128, 1, 0>(xb, Wqkb, QKb, 4096, 4096, 2048, swz >> 4, swz & 15, lds,
                              cosb, sinb, qscale);
  } else {
    int b2 = bid - 256;
    int swz = (b2 & 7) * 32 + (b2 >> 3);
    gemm_pipe_body<64, 0, 0>(Wvb, xb, VTb, 2048, 4096, 2048, swz >> 4, swz & 15, lds,
                             nullptr, nullptr, 0.f);
  }
}

// out = O @ Wo^T (fp32 out): 32x8 = 256 blocks of 128x256 = 1 exact round
__global__ __launch_bounds__(512, 2)
void gemm_o(const u16* __restrict__ Ob, const u16* __restrict__ Wob, float* __restrict__ out) {
  __shared__ __align__(16) u16 lds[4 * 16384];
  int bid = blockIdx.x;
  int swz = (bid & 7) * 32 + (bid >> 3);
  gemm_pipe_body<64, 0, 1>(Ob, Wob, (void*)out, 4096, 2048, 2048, swz >> 3, swz & 7, lds,
                           nullptr, nullptr, 0.f);
}

// ---------------- Flash attention (proven structure; QKb strides) ----------------
// QK: [B*S][4096] bf16 (cols 0-2047 = roped*scaled Q, 2048-4095 = roped K).
// VT: [2048][4096] bf16. O: [B*S][2048] bf16.
// grid 512 = 32 bh * 16 qtiles(128); block 256 = 4 waves * 32 q-rows (2 qf of 16).
// Swapped QK^T / PV, in-lane softmax, K+V double-buffered, __syncthreads per tile.
__global__ __launch_bounds__(256, 2)
void attn_kernel(const u16* __restrict__ QKb, const u16* __restrict__ VT,
                 u16* __restrict__ Ob) {
  __shared__ __align__(16) u16 sK[2][64 * 128];   // 32 KB
  __shared__ __align__(16) u16 sV[2][128 * 64];   // 32 KB
  __shared__ __align__(16) u16 sP[4][32 * 64];    // 16 KB

  int id = blockIdx.x;
  int swz = (id & 7) * 64 + (id >> 3);    // XCD-chunked: 4 heads/XCD -> KV L2-resident
  int bh = swz >> 4;
  int qb = swz & 15;
  int b = bh >> 4, h = bh & 15;
  int t = threadIdx.x, w = t >> 6, l = t & 63;
  int lr = l & 15, lh = l >> 4;
  int lr7 = lr & 7;
  int q0 = qb * 128;

  const u16* Kbase = QKb + (size_t)(b * 2048) * 4096 + 2048 + h * 128;
  const u16* Vbase = VT + (size_t)(h * 128) * 4096 + b * 2048;
  u16* sPw = sP[w];

  bf16x8 aq[2][4];
#pragma unroll
  for (int qf = 0; qf < 2; ++qf) {
    size_t qrow = (size_t)(b * 2048 + q0 + w * 32 + qf * 16 + lr) * 4096 + h * 128;
#pragma unroll
    for (int c = 0; c < 4; ++c)
      aq[qf][c] = *reinterpret_cast<const bf16x8*>(QKb + qrow + c * 32 + lh * 8);
  }

  f32x4 zero = {0.f, 0.f, 0.f, 0.f};
  f32x4 acc_o[2][8];  // O^T[d][q=lr]
#pragma unroll
  for (int qf = 0; qf < 2; ++qf)
#pragma unroll
    for (int d = 0; d < 8; ++d) acc_o[qf][d] = zero;
  float m_row[2] = {-1e30f, -1e30f};
  float l_row[2] = {0.f, 0.f};

  auto stage = [&](int buf, int kt2) {
    const u16* Kt = Kbase + (size_t)(kt2 * 64) * 4096;
    const u16* Vt = Vbase + kt2 * 64;
#pragma unroll
    for (int it = 0; it < 4; ++it) {
      int o = it * 4096 + t * 16;            // byte offset in 16KB tile
      int rowK = o >> 8;
      int cbK = (o & 255) ^ ((rowK & 7) << 4);
      async_load16((u16*)sK[buf] + (o >> 1), Kt + (size_t)rowK * 4096 + (cbK >> 1));
      int rowV = o >> 7;
      int cbV = (o & 127) ^ ((rowV & 7) << 4);
      async_load16((u16*)sV[buf] + (o >> 1), Vt + (size_t)rowV * 4096 + (cbV >> 1));
    }
  };

  stage(0, 0);
  __syncthreads();
  int cur = 0;

  for (int kt = 0; kt < 32; ++kt) {
    if (kt < 31) stage(cur ^ 1, kt + 1);

    const u16* sKc = sK[cur];
    const u16* sVc = sV[cur];

    f32x4 sacc[2][4];
#pragma unroll
    for (int qf = 0; qf < 2; ++qf)
#pragma unroll
      for (int g = 0; g < 4; ++g) sacc[qf][g] = zero;
#pragma unroll
    for (int g = 0; g < 4; ++g) {
      int row = g * 16 + lr;
      int xr = lr7 << 4;
#pragma unroll
      for (int c = 0; c < 4; ++c) {
        int cb = (c * 64 + lh * 16) ^ xr;
        bf16x8 bk = *reinterpret_cast<const bf16x8*>(sKc + row * 128 + (cb >> 1));
        sacc[0][g] = __builtin_amdgcn_mfma_f32_16x16x32_bf16(bk, aq[0][c], sacc[0][g], 0, 0, 0);
        sacc[1][g] = __builtin_amdgcn_mfma_f32_16x16x32_bf16(bk, aq[1][c], sacc[1][g], 0, 0, 0);
      }
    }

#pragma unroll
    for (int qf = 0; qf < 2; ++qf) {
      f32x4 m4;
#pragma unroll
      for (int e = 0; e < 4; ++e)
        m4[e] = fmaxf(fmaxf(sacc[qf][0][e], sacc[qf][1][e]),
                      fmaxf(sacc[qf][2][e], sacc[qf][3][e]));
      float mx = fmaxf(fmaxf(m4[0], m4[1]), fmaxf(m4[2], m4[3]));
      mx = fmaxf(mx, __shfl_xor(mx, 16));
      mx = fmaxf(mx, __shfl_xor(mx, 32));
      float mo = m_row[qf];
      if (!__all(mx <= mo + 8.f)) {     // T13 defer-max
        float mn = fmaxf(mo, mx);
        float al = __builtin_amdgcn_exp2f(mo - mn);
        m_row[qf] = mn;
        l_row[qf] *= al;
#pragma unroll
        for (int d = 0; d < 8; ++d) acc_o[qf][d] *= al;
      }
      float mn = m_row[qf];
#pragma unroll
      for (int g = 0; g < 4; ++g)
#pragma unroll
        for (int e = 0; e < 4; ++e)
          sacc[qf][g][e] = __builtin_amdgcn_exp2f(sacc[qf][g][e] - mn);
      f32x4 s4;
#pragma unroll
      for (int e = 0; e < 4; ++e)
        s4[e] = (sacc[qf][0][e] + sacc[qf][1][e]) + (sacc[qf][2][e] + sacc[qf][3][e]);
      float rs = (s4[0] + s4[1]) + (s4[2] + s4[3]);
      rs += __shfl_xor(rs, 16);
      rs += __shfl_xor(rs, 32);
      l_row[qf] += rs;

      int rowb = (qf * 16 + lr) * 128;
      int xw = lr7 << 4;
#pragma unroll
      for (int g = 0; g < 4; ++g) {
        uint2 pw;
        pw.x = cvtpk(sacc[qf][g][0], sacc[qf][g][1]);
        pw.y = cvtpk(sacc[qf][g][2], sacc[qf][g][3]);
        int cb = (g * 32 + lh * 8) ^ xw;
        *reinterpret_cast<uint2*>(reinterpret_cast<char*>(sPw) + rowb + cb) = pw;
      }
    }

    bf16x8 bp[2][2];
#pragma unroll
    for (int qf = 0; qf < 2; ++qf) {
      int rowb = (qf * 16 + lr) * 128;
      int xr = lr7 << 4;
#pragma unroll
      for (int c2 = 0; c2 < 2; ++c2) {
        int cb = (c2 * 64 + lh * 16) ^ xr;
        bp[qf][c2] = *reinterpret_cast<const bf16x8*>(
            reinterpret_cast<const char*>(sPw) + rowb + cb);
      }
    }
#pragma unroll
    for (int c2 = 0; c2 < 2; ++c2) {
#pragma unroll
      for (int d = 0; d < 8; ++d) {
        int row = d * 16 + lr;
        int cb = (c2 * 64 + lh * 16) ^ (lr7 << 4);
        bf16x8 bv = *reinterpret_cast<const bf16x8*>(sVc + row * 64 + (cb >> 1));
        acc_o[0][d] = __builtin_amdgcn_mfma_f32_16x16x32_bf16(bv, bp[0][c2], acc_o[0][d], 0, 0, 0);
        acc_o[1][d] = __builtin_amdgcn_mfma_f32_16x16x32_bf16(bv, bp[1][c2], acc_o[1][d], 0, 0, 0);
      }
    }

    __syncthreads();
    cur ^= 1;
  }

#pragma unroll
  for (int qf = 0; qf < 2; ++qf) {
    float inv = 1.f / l_row[qf];
    size_t qrow = (size_t)(b * 2048 + q0 + w * 32 + qf * 16 + lr) * 2048 + h * 128;
#pragma unroll
    for (int d = 0; d < 8; ++d) {
      ushort4 o;
      o.x = f2bf(acc_o[qf][d][0] * inv);
      o.y = f2bf(acc_o[qf][d][1] * inv);
      o.z = f2bf(acc_o[qf][d][2] * inv);
      o.w = f2bf(acc_o[qf][d][3] * inv);
      *reinterpret_cast<ushort4*>(Ob + qrow + d * 16 + lh * 4) = o;
    }
  }
}

extern "C" void kernel_launch(void* const* d_in, const int* in_sizes, int n_in,
                              void* d_out, int out_size, void* d_ws, size_t ws_size,
                              hipStream_t stream) {
  const float* x  = (const float*)d_in[0];
  const float* rc = (const float*)d_in[1];
  const float* rs = (const float*)d_in[2];
  const float* Wq = (const float*)d_in[3];
  const float* Wk = (const float*)d_in[4];
  const float* Wv = (const float*)d_in[5];
  const float* Wo = (const float*)d_in[6];
  float* out = (float*)d_out;
  char* ws = (char*)d_ws;
  const size_t MB = 1024 * 1024;
  u16* xb   = (u16*)(ws);            // 16 MB
  u16* Wqkb = (u16*)(ws + 16 * MB);  // 16 MB  [4096][2048] = [Wq;Wk]
  u16* Wvb  = (u16*)(ws + 32 * MB);  // 8 MB
  u16* Wob  = (u16*)(ws + 40 * MB);  // 8 MB
  u16* QKb  = (u16*)(ws + 48 * MB);  // 32 MB  [4096][4096]
  u16* VTb  = (u16*)(ws + 80 * MB);  // 16 MB  [2048][4096]
  u16* Ob   = (u16*)(ws + 16 * MB);  // 16 MB  (alias Wqkb, dead after QK GEMM)

  convert_all<<<24576, 256, 0, stream>>>(x, Wq, Wk, Wv, Wo, xb, Wqkb, Wvb, Wob);

  const float qscale = 0.08838834764831845f * 1.4426950408889634f;  // 1/sqrt(128)*log2(e)
  gemm_qkv256<<<512, 512, 0, stream>>>(xb, Wqkb, Wvb, QKb, VTb, rc, rs, qscale);

  attn_kernel<<<512, 256, 0, stream>>>(QKb, VTb, Ob);

  gemm_o<<<256, 512, 0, stream>>>(Ob, Wob, out);
}

// Round 9
// 249.348 us; speedup vs baseline: 1.3595x; 1.0228x over previous
//
#include <hip/hip_runtime.h>
#include <hip/hip_bf16.h>

typedef unsigned short u16;
typedef __bf16 bf16x8 __attribute__((ext_vector_type(8)));
typedef float f32x4 __attribute__((ext_vector_type(4)));

__device__ __forceinline__ float bf2f(u16 u) {
  union { unsigned int i; float f; } v; v.i = ((unsigned int)u) << 16; return v.f;
}
__device__ __forceinline__ u16 f2bf(float f) {
  union { float f; unsigned int i; } v; v.f = f;
  unsigned int r = v.i + 0x7fffu + ((v.i >> 16) & 1u);
  return (u16)(r >> 16);
}
__device__ __forceinline__ unsigned cvtpk(float lo, float hi) {
  unsigned r;
  asm("v_cvt_pk_bf16_f32 %0, %1, %2" : "=v"(r) : "v"(lo), "v"(hi));
  return r;
}

__device__ __forceinline__ void async_load16(void* lds, const void* g) {
  __builtin_amdgcn_global_load_lds((const __attribute__((address_space(1))) void*)g,
                                   (__attribute__((address_space(3))) void*)lds, 16, 0, 0);
}

// ---------------- fused fp32 -> bf16 convert (x, Wq|Wk -> Wqk, Wv, Wo) ----------------
__global__ void convert_all(const float* __restrict__ x, const float* __restrict__ Wq,
                            const float* __restrict__ Wk, const float* __restrict__ Wv,
                            const float* __restrict__ Wo, u16* __restrict__ xb,
                            u16* __restrict__ Wqkb, u16* __restrict__ Wvb,
                            u16* __restrict__ Wob) {
  int bid = blockIdx.x;
  const float* src;
  u16* dst;
  int off;
  if (bid < 8192)       { src = x;  dst = xb;              off = bid; }
  else if (bid < 12288) { src = Wq; dst = Wqkb;            off = bid - 8192; }
  else if (bid < 16384) { src = Wk; dst = Wqkb + 4194304;  off = bid - 12288; }
  else if (bid < 20480) { src = Wv; dst = Wvb;             off = bid - 16384; }
  else                  { src = Wo; dst = Wob;             off = bid - 20480; }
  int i = off * 1024 + threadIdx.x * 4;
  float4 v = *(const float4*)(src + i);
  ushort4 o;
  o.x = f2bf(v.x); o.y = f2bf(v.y); o.z = f2bf(v.z); o.w = f2bf(v.w);
  *(ushort4*)(dst + i) = o;
}

// ======== pipelined GEMM body: BM x 256 tile, ring-4 BK=32, reg-dbuf A-frags ========
// C[M,N] = A[M,K]*B[N,K]^T bf16. 512 thr = 8 waves (wm = row half, wn = col quarter).
// LDS rows are 64B; bank swizzle: byte-in-row ^= (row&6)<<4 (u16 col ^= (row&6)<<2).
// Start bank per lane = {row&1, lh^((row>>1)&3)} -> 8 starts / 16-lane group = 2-way
// (free). Swizzle applied as involution pair: inverse-swizzled GLOBAL source in
// stage (rule 21: global_load_lds writes linearly) + swizzled ds_read addrs.
// Per step s: vmcnt(4) [buf s+1 landed; s+2 in flight] -> barrier -> stage(s+3)
//   -> ds_read bfv(s) JIT -> ds_read af(s+1) into ALTERNATE reg set
//   -> setprio{ MFMA on af(s) read LAST step }.
// 2x-unrolled loop, named afA/afB (static indexing). NK even.
// ROPE=1: B-frags permuted so (d,d+64) = acc[mi][ni]/acc[mi][ni+2] in-lane.
template <int BMHALF, int ROPE, int OUT_F32>
__device__ __forceinline__ void gemm_pipe_body(const u16* __restrict__ A,
                                               const u16* __restrict__ Bm,
                                               void* __restrict__ C, int M, int N, int K,
                                               int tm, int tn, u16* lds,
                                               const float* __restrict__ cosb,
                                               const float* __restrict__ sinb,
                                               float qscale) {
  constexpr int MIc = BMHALF / 16;
  constexpr int SUBU16 = (BMHALF == 128) ? 16384 : 12288;  // u16 per ring slot
  constexpr int BOFF = (BMHALF == 128) ? 8192 : 4096;      // B region offset (u16)
  const int t = threadIdx.x;
  const int w = t >> 6, l = t & 63;
  const int wm = w >> 2, wn = w & 3;
  const int lr = l & 15, lh = l >> 4;
  const size_t row0 = (size_t)tm * (2 * BMHALF), col0 = (size_t)tn * 256;
  const u16* Ag = A + row0 * K;
  const u16* Bg = Bm + col0 * K;

  const int ra = t >> 2;
  const int kcs = ((t & 3) << 3) ^ ((ra & 6) << 2);  // inverse-swizzled source col (u16)
  auto stage = [&](int s) {
    u16* dst = lds + (s & 3) * SUBU16;
    const size_t koff = (size_t)s * 32 + kcs;
    if constexpr (BMHALF == 128) {
      async_load16(dst + t * 8,         Ag + (size_t)ra * K + koff);
      async_load16(dst + 4096 + t * 8,  Ag + (size_t)(ra + 128) * K + koff);
      async_load16(dst + 8192 + t * 8,  Bg + (size_t)ra * K + koff);
      async_load16(dst + 12288 + t * 8, Bg + (size_t)(ra + 128) * K + koff);
    } else {
      async_load16(dst + t * 8,         Ag + (size_t)ra * K + koff);
      async_load16(dst + 4096 + t * 8,  Bg + (size_t)ra * K + koff);
      async_load16(dst + 8192 + t * 8,  Bg + (size_t)(ra + 128) * K + koff);
    }
  };
  const int swl = (lh * 8) ^ ((lr & 6) << 2);  // swizzled within-row u16 offset (rows = base16+lr)
  auto read_af = [&](bf16x8* dst, int s) {
    const u16* sub = lds + (s & 3) * SUBU16;
#pragma unroll
    for (int mi = 0; mi < MIc; ++mi)
      dst[mi] = *reinterpret_cast<const bf16x8*>(sub + (wm * BMHALF + mi * 16 + lr) * 32 + swl);
  };
  auto read_bfv = [&](bf16x8* dst, int s) {
    const u16* sub = lds + (s & 3) * SUBU16 + BOFF;
#pragma unroll
    for (int ni = 0; ni < 4; ++ni) {
      int colf = ROPE ? ((wn >> 1) * 128 + (wn & 1) * 32 + (ni >> 1) * 64 + (ni & 1) * 16)
                      : (wn * 64 + ni * 16);
      dst[ni] = *reinterpret_cast<const bf16x8*>(sub + (colf + lr) * 32 + swl);
    }
  };

  f32x4 acc[MIc][4];
#pragma unroll
  for (int i = 0; i < MIc; ++i)
#pragma unroll
    for (int j = 0; j < 4; ++j) acc[i][j] = (f32x4){0.f, 0.f, 0.f, 0.f};

  const int NK = K >> 5;  // even
  bf16x8 afA[MIc], afB[MIc], bfv[4];

  stage(0); stage(1); stage(2);
  if constexpr (BMHALF == 128) asm volatile("s_waitcnt vmcnt(8)" ::: "memory");
  else                         asm volatile("s_waitcnt vmcnt(6)" ::: "memory");
  __builtin_amdgcn_s_barrier();
  asm volatile("" ::: "memory");
  read_af(afA, 0);

  auto pipestep = [&](int s, bf16x8* cur, bf16x8* nxt) {
    if (s + 2 < NK) {
      if constexpr (BMHALF == 128) asm volatile("s_waitcnt vmcnt(4)" ::: "memory");
      else                         asm volatile("s_waitcnt vmcnt(3)" ::: "memory");
    } else {
      asm volatile("s_waitcnt vmcnt(0)" ::: "memory");
    }
    __builtin_amdgcn_s_barrier();
    asm volatile("" ::: "memory");
    if (s + 3 < NK) stage(s + 3);
    read_bfv(bfv, s);                  // JIT (first in DS queue: MFMA waits only these)
    if (s + 1 < NK) read_af(nxt, s + 1);  // prefetch into alternate set
    __builtin_amdgcn_s_setprio(1);
#pragma unroll
    for (int mi = 0; mi < MIc; ++mi)
#pragma unroll
      for (int ni = 0; ni < 4; ++ni)
        acc[mi][ni] = __builtin_amdgcn_mfma_f32_16x16x32_bf16(cur[mi], bfv[ni], acc[mi][ni], 0, 0, 0);
    __builtin_amdgcn_s_setprio(0);
  };

  for (int s = 0; s < NK; s += 2) {
    pipestep(s, afA, afB);
    pipestep(s + 1, afB, afA);
  }

  if constexpr (ROPE) {
    float scale = (2 * tn + (wn >> 1)) < 16 ? qscale : 1.0f;
    size_t colbase = col0 + (wn >> 1) * 128;
#pragma unroll
    for (int mi = 0; mi < MIc; ++mi)
#pragma unroll
      for (int r = 0; r < 4; ++r) {
        size_t row = row0 + wm * BMHALF + mi * 16 + lh * 4 + r;
        int si = (int)(row & 2047);
        const float* cr = cosb + si * 128;
        const float* sr = sinb + si * 128;
#pragma unroll
        for (int ni = 0; ni < 2; ++ni) {
          int dlo = (wn & 1) * 32 + ni * 16 + lr;
          float v0 = acc[mi][ni][r];
          float v1 = acc[mi][ni + 2][r];
          float o0 = (v0 * cr[dlo] - v1 * sr[dlo]) * scale;
          float o1 = (v1 * cr[64 + dlo] + v0 * sr[64 + dlo]) * scale;
          ((u16*)C)[row * N + colbase + dlo]      = f2bf(o0);
          ((u16*)C)[row * N + colbase + 64 + dlo] = f2bf(o1);
        }
      }
  } else {
#pragma unroll
    for (int mi = 0; mi < MIc; ++mi)
#pragma unroll
      for (int ni = 0; ni < 4; ++ni)
#pragma unroll
        for (int r = 0; r < 4; ++r) {
          size_t row = row0 + wm * BMHALF + mi * 16 + lh * 4 + r;
          size_t col = col0 + wn * 64 + ni * 16 + lr;
          float v = acc[mi][ni][r];
          if (OUT_F32)
            ((float*)C)[row * N + col] = v;
          else
            ((u16*)C)[row * N + col] = f2bf(v);
        }
  }
}

// QK (256 blocks, 256x256, rope fused) + V^T (256 blocks, 128x256): 512 = 2 exact rounds
__global__ __launch_bounds__(512, 2)
void gemm_qkv256(const u16* __restrict__ xb, const u16* __restrict__ Wqkb,
                 const u16* __restrict__ Wvb, u16* __restrict__ QKb, u16* __restrict__ VTb,
                 const float* __restrict__ cosb, const float* __restrict__ sinb,
                 float qscale) {
  __shared__ __align__(16) u16 lds[4 * 16384];  // 128 KB
  int bid = blockIdx.x;
  if (bid < 256) {
    int swz = (bid & 7) * 32 + (bid >> 3);
    gemm_pipe_body<128, 1, 0>(xb, Wqkb, QKb, 4096, 4096, 2048, swz >> 4, swz & 15, lds,
                              cosb, sinb, qscale);
  } else {
    int b2 = bid - 256;
    int swz = (b2 & 7) * 32 + (b2 >> 3);
    gemm_pipe_body<64, 0, 0>(Wvb, xb, VTb, 2048, 4096, 2048, swz >> 4, swz & 15, lds,
                             nullptr, nullptr, 0.f);
  }
}

// out = O @ Wo^T (fp32 out): 256 blocks of 128x256 = 1 exact round
__global__ __launch_bounds__(512, 2)
void gemm_o(const u16* __restrict__ Ob, const u16* __restrict__ Wob, float* __restrict__ out) {
  __shared__ __align__(16) u16 lds[4 * 16384];
  int bid = blockIdx.x;
  int swz = (bid & 7) * 32 + (bid >> 3);
  gemm_pipe_body<64, 0, 1>(Ob, Wob, (void*)out, 4096, 2048, 2048, swz >> 3, swz & 7, lds,
                           nullptr, nullptr, 0.f);
}

// ---------------- Flash attention (proven structure; QKb strides) ----------------
// QK: [B*S][4096] bf16 (cols 0-2047 = roped*scaled Q, 2048-4095 = roped K).
// VT: [2048][4096] bf16. O: [B*S][2048] bf16.
// grid 512 = 32 bh * 16 qtiles(128); block 256 = 4 waves * 32 q-rows (2 qf of 16).
// Swapped QK^T / PV, in-lane softmax, K+V double-buffered, __syncthreads per tile.
__global__ __launch_bounds__(256, 2)
void attn_kernel(const u16* __restrict__ QKb, const u16* __restrict__ VT,
                 u16* __restrict__ Ob) {
  __shared__ __align__(16) u16 sK[2][64 * 128];   // 32 KB
  __shared__ __align__(16) u16 sV[2][128 * 64];   // 32 KB
  __shared__ __align__(16) u16 sP[4][32 * 64];    // 16 KB

  int id = blockIdx.x;
  int swz = (id & 7) * 64 + (id >> 3);    // XCD-chunked: 4 heads/XCD -> KV L2-resident
  int bh = swz >> 4;
  int qb = swz & 15;
  int b = bh >> 4, h = bh & 15;
  int t = threadIdx.x, w = t >> 6, l = t & 63;
  int lr = l & 15, lh = l >> 4;
  int lr7 = lr & 7;
  int q0 = qb * 128;

  const u16* Kbase = QKb + (size_t)(b * 2048) * 4096 + 2048 + h * 128;
  const u16* Vbase = VT + (size_t)(h * 128) * 4096 + b * 2048;
  u16* sPw = sP[w];

  bf16x8 aq[2][4];
#pragma unroll
  for (int qf = 0; qf < 2; ++qf) {
    size_t qrow = (size_t)(b * 2048 + q0 + w * 32 + qf * 16 + lr) * 4096 + h * 128;
#pragma unroll
    for (int c = 0; c < 4; ++c)
      aq[qf][c] = *reinterpret_cast<const bf16x8*>(QKb + qrow + c * 32 + lh * 8);
  }

  f32x4 zero = {0.f, 0.f, 0.f, 0.f};
  f32x4 acc_o[2][8];  // O^T[d][q=lr]
#pragma unroll
  for (int qf = 0; qf < 2; ++qf)
#pragma unroll
    for (int d = 0; d < 8; ++d) acc_o[qf][d] = zero;
  float m_row[2] = {-1e30f, -1e30f};
  float l_row[2] = {0.f, 0.f};

  auto stage = [&](int buf, int kt2) {
    const u16* Kt = Kbase + (size_t)(kt2 * 64) * 4096;
    const u16* Vt = Vbase + kt2 * 64;
#pragma unroll
    for (int it = 0; it < 4; ++it) {
      int o = it * 4096 + t * 16;            // byte offset in 16KB tile
      int rowK = o >> 8;
      int cbK = (o & 255) ^ ((rowK & 7) << 4);
      async_load16((u16*)sK[buf] + (o >> 1), Kt + (size_t)rowK * 4096 + (cbK >> 1));
      int rowV = o >> 7;
      int cbV = (o & 127) ^ ((rowV & 7) << 4);
      async_load16((u16*)sV[buf] + (o >> 1), Vt + (size_t)rowV * 4096 + (cbV >> 1));
    }
  };

  stage(0, 0);
  __syncthreads();
  int cur = 0;

  for (int kt = 0; kt < 32; ++kt) {
    if (kt < 31) stage(cur ^ 1, kt + 1);

    const u16* sKc = sK[cur];
    const u16* sVc = sV[cur];

    f32x4 sacc[2][4];
#pragma unroll
    for (int qf = 0; qf < 2; ++qf)
#pragma unroll
      for (int g = 0; g < 4; ++g) sacc[qf][g] = zero;
#pragma unroll
    for (int g = 0; g < 4; ++g) {
      int row = g * 16 + lr;
      int xr = lr7 << 4;
#pragma unroll
      for (int c = 0; c < 4; ++c) {
        int cb = (c * 64 + lh * 16) ^ xr;
        bf16x8 bk = *reinterpret_cast<const bf16x8*>(sKc + row * 128 + (cb >> 1));
        sacc[0][g] = __builtin_amdgcn_mfma_f32_16x16x32_bf16(bk, aq[0][c], sacc[0][g], 0, 0, 0);
        sacc[1][g] = __builtin_amdgcn_mfma_f32_16x16x32_bf16(bk, aq[1][c], sacc[1][g], 0, 0, 0);
      }
    }

#pragma unroll
    for (int qf = 0; qf < 2; ++qf) {
      f32x4 m4;
#pragma unroll
      for (int e = 0; e < 4; ++e)
        m4[e] = fmaxf(fmaxf(sacc[qf][0][e], sacc[qf][1][e]),
                      fmaxf(sacc[qf][2][e], sacc[qf][3][e]));
      float mx = fmaxf(fmaxf(m4[0], m4[1]), fmaxf(m4[2], m4[3]));
      mx = fmaxf(mx, __shfl_xor(mx, 16));
      mx = fmaxf(mx, __shfl_xor(mx, 32));
      float mo = m_row[qf];
      if (!__all(mx <= mo + 8.f)) {     // T13 defer-max
        float mn = fmaxf(mo, mx);
        float al = __builtin_amdgcn_exp2f(mo - mn);
        m_row[qf] = mn;
        l_row[qf] *= al;
#pragma unroll
        for (int d = 0; d < 8; ++d) acc_o[qf][d] *= al;
      }
      float mn = m_row[qf];
#pragma unroll
      for (int g = 0; g < 4; ++g)
#pragma unroll
        for (int e = 0; e < 4; ++e)
          sacc[qf][g][e] = __builtin_amdgcn_exp2f(sacc[qf][g][e] - mn);
      f32x4 s4;
#pragma unroll
      for (int e = 0; e < 4; ++e)
        s4[e] = (sacc[qf][0][e] + sacc[qf][1][e]) + (sacc[qf][2][e] + sacc[qf][3][e]);
      float rs = (s4[0] + s4[1]) + (s4[2] + s4[3]);
      rs += __shfl_xor(rs, 16);
      rs += __shfl_xor(rs, 32);
      l_row[qf] += rs;

      int rowb = (qf * 16 + lr) * 128;
      int xw = lr7 << 4;
#pragma unroll
      for (int g = 0; g < 4; ++g) {
        uint2 pw;
        pw.x = cvtpk(sacc[qf][g][0], sacc[qf][g][1]);
        pw.y = cvtpk(sacc[qf][g][2], sacc[qf][g][3]);
        int cb = (g * 32 + lh * 8) ^ xw;
        *reinterpret_cast<uint2*>(reinterpret_cast<char*>(sPw) + rowb + cb) = pw;
      }
    }

    bf16x8 bp[2][2];
#pragma unroll
    for (int qf = 0; qf < 2; ++qf) {
      int rowb = (qf * 16 + lr) * 128;
      int xr = lr7 << 4;
#pragma unroll
      for (int c2 = 0; c2 < 2; ++c2) {
        int cb = (c2 * 64 + lh * 16) ^ xr;
        bp[qf][c2] = *reinterpret_cast<const bf16x8*>(
            reinterpret_cast<const char*>(sPw) + rowb + cb);
      }
    }
#pragma unroll
    for (int c2 = 0; c2 < 2; ++c2) {
#pragma unroll
      for (int d = 0; d < 8; ++d) {
        int row = d * 16 + lr;
        int cb = (c2 * 64 + lh * 16) ^ (lr7 << 4);
        bf16x8 bv = *reinterpret_cast<const bf16x8*>(sVc + row * 64 + (cb >> 1));
        acc_o[0][d] = __builtin_amdgcn_mfma_f32_16x16x32_bf16(bv, bp[0][c2], acc_o[0][d], 0, 0, 0);
        acc_o[1][d] = __builtin_amdgcn_mfma_f32_16x16x32_bf16(bv, bp[1][c2], acc_o[1][d], 0, 0, 0);
      }
    }

    __syncthreads();
    cur ^= 1;
  }

#pragma unroll
  for (int qf = 0; qf < 2; ++qf) {
    float inv = 1.f / l_row[qf];
    size_t qrow = (size_t)(b * 2048 + q0 + w * 32 + qf * 16 + lr) * 2048 + h * 128;
#pragma unroll
    for (int d = 0; d < 8; ++d) {
      ushort4 o;
      o.x = f2bf(acc_o[qf][d][0] * inv);
      o.y = f2bf(acc_o[qf][d][1] * inv);
      o.z = f2bf(acc_o[qf][d][2] * inv);
      o.w = f2bf(acc_o[qf][d][3] * inv);
      *reinterpret_cast<ushort4*>(Ob + qrow + d * 16 + lh * 4) = o;
    }
  }
}

extern "C" void kernel_launch(void* const* d_in, const int* in_sizes, int n_in,
                              void* d_out, int out_size, void* d_ws, size_t ws_size,
                              hipStream_t stream) {
  const float* x  = (const float*)d_in[0];
  const float* rc = (const float*)d_in[1];
  const float* rs = (const float*)d_in[2];
  const float* Wq = (const float*)d_in[3];
  const float* Wk = (const float*)d_in[4];
  const float* Wv = (const float*)d_in[5];
  const float* Wo = (const float*)d_in[6];
  float* out = (float*)d_out;
  char* ws = (char*)d_ws;
  const size_t MB = 1024 * 1024;
  u16* xb   = (u16*)(ws);            // 16 MB
  u16* Wqkb = (u16*)(ws + 16 * MB);  // 16 MB  [4096][2048] = [Wq;Wk]
  u16* Wvb  = (u16*)(ws + 32 * MB);  // 8 MB
  u16* Wob  = (u16*)(ws + 40 * MB);  // 8 MB
  u16* QKb  = (u16*)(ws + 48 * MB);  // 32 MB  [4096][4096]
  u16* VTb  = (u16*)(ws + 80 * MB);  // 16 MB  [2048][4096]
  u16* Ob   = (u16*)(ws + 16 * MB);  // 16 MB  (alias Wqkb, dead after QK GEMM)

  convert_all<<<24576, 256, 0, stream>>>(x, Wq, Wk, Wv, Wo, xb, Wqkb, Wvb, Wob);

  const float qscale = 0.08838834764831845f * 1.4426950408889634f;  // 1/sqrt(128)*log2(e)
  gemm_qkv256<<<512, 512, 0, stream>>>(xb, Wqkb, Wvb, QKb, VTb, rc, rs, qscale);

  attn_kernel<<<512, 256, 0, stream>>>(QKb, VTb, Ob);

  gemm_o<<<256, 512, 0, stream>>>(Ob, Wob, out);
}

// Round 10
// 249.302 us; speedup vs baseline: 1.3598x; 1.0002x over previous
//
#include <hip/hip_runtime.h>
#include <hip/hip_bf16.h>

typedef unsigned short u16;
typedef __bf16 bf16x8 __attribute__((ext_vector_type(8)));
typedef float f32x4 __attribute__((ext_vector_type(4)));

__device__ __forceinline__ float bf2f(u16 u) {
  union { unsigned int i; float f; } v; v.i = ((unsigned int)u) << 16; return v.f;
}
__device__ __forceinline__ u16 f2bf(float f) {
  union { float f; unsigned int i; } v; v.f = f;
  unsigned int r = v.i + 0x7fffu + ((v.i >> 16) & 1u);
  return (u16)(r >> 16);
}
__device__ __forceinline__ unsigned cvtpk(float lo, float hi) {
  unsigned r;
  asm("v_cvt_pk_bf16_f32 %0, %1, %2" : "=v"(r) : "v"(lo), "v"(hi));
  return r;
}

__device__ __forceinline__ void async_load16(void* lds, const void* g) {
  __builtin_amdgcn_global_load_lds((const __attribute__((address_space(1))) void*)g,
                                   (__attribute__((address_space(3))) void*)lds, 16, 0, 0);
}

// ---------------- fused fp32 -> bf16 convert (x, Wq|Wk -> Wqk, Wv, Wo) ----------------
__global__ void convert_all(const float* __restrict__ x, const float* __restrict__ Wq,
                            const float* __restrict__ Wk, const float* __restrict__ Wv,
                            const float* __restrict__ Wo, u16* __restrict__ xb,
                            u16* __restrict__ Wqkb, u16* __restrict__ Wvb,
                            u16* __restrict__ Wob) {
  int bid = blockIdx.x;
  const float* src;
  u16* dst;
  int off;
  if (bid < 8192)       { src = x;  dst = xb;              off = bid; }
  else if (bid < 12288) { src = Wq; dst = Wqkb;            off = bid - 8192; }
  else if (bid < 16384) { src = Wk; dst = Wqkb + 4194304;  off = bid - 12288; }
  else if (bid < 20480) { src = Wv; dst = Wvb;             off = bid - 16384; }
  else                  { src = Wo; dst = Wob;             off = bid - 20480; }
  int i = off * 1024 + threadIdx.x * 4;
  float4 v = *(const float4*)(src + i);
  ushort4 o;
  o.x = f2bf(v.x); o.y = f2bf(v.y); o.z = f2bf(v.z); o.w = f2bf(v.w);
  *(ushort4*)(dst + i) = o;
}

// ======== pipelined GEMM body: BM x 256 tile, ring-4 BK=32, FULL reg-dbuf frags ========
// C[M,N] = A[M,K]*B[N,K]^T bf16. 512 thr = 8 waves (wm = row half, wn = col quarter).
// LDS rows are 64B; bank swizzle: u16 col ^= (row&6)<<2 (start bank spread -> 2-way
// free floor; SQ_LDS_BANK_CONFLICT measured 0). Involution pair: inverse-swizzled
// GLOBAL source in stage (rule 21) + swizzled ds_read addrs.
// Per step s: vmcnt(4) [buf s+1 landed; s+2/s+3 in flight] -> barrier -> stage(s+3)
//   -> ds_read af(s+1)+bfv(s+1) into ALTERNATE reg sets (12 reads, NOT consumed
//      this step) -> setprio{ 32 MFMA on regs read LAST step — zero lgkm wait }.
// MFMA pipe and LDS pipe run concurrently; 2x-unrolled loop, named A/B sets. NK even.
// ROPE=1: B-frags permuted so (d,d+64) = acc[mi][ni]/acc[mi][ni+2] in-lane.
template <int BMHALF, int ROPE, int OUT_F32>
__device__ __forceinline__ void gemm_pipe_body(const u16* __restrict__ A,
                                               const u16* __restrict__ Bm,
                                               void* __restrict__ C, int M, int N, int K,
                                               int tm, int tn, u16* lds,
                                               const float* __restrict__ cosb,
                                               const float* __restrict__ sinb,
                                               float qscale) {
  constexpr int MIc = BMHALF / 16;
  constexpr int SUBU16 = (BMHALF == 128) ? 16384 : 12288;  // u16 per ring slot
  constexpr int BOFF = (BMHALF == 128) ? 8192 : 4096;      // B region offset (u16)
  const int t = threadIdx.x;
  const int w = t >> 6, l = t & 63;
  const int wm = w >> 2, wn = w & 3;
  const int lr = l & 15, lh = l >> 4;
  const size_t row0 = (size_t)tm * (2 * BMHALF), col0 = (size_t)tn * 256;
  const u16* Ag = A + row0 * K;
  const u16* Bg = Bm + col0 * K;

  const int ra = t >> 2;
  const int kcs = ((t & 3) << 3) ^ ((ra & 6) << 2);  // inverse-swizzled source col (u16)
  auto stage = [&](int s) {
    u16* dst = lds + (s & 3) * SUBU16;
    const size_t koff = (size_t)s * 32 + kcs;
    if constexpr (BMHALF == 128) {
      async_load16(dst + t * 8,         Ag + (size_t)ra * K + koff);
      async_load16(dst + 4096 + t * 8,  Ag + (size_t)(ra + 128) * K + koff);
      async_load16(dst + 8192 + t * 8,  Bg + (size_t)ra * K + koff);
      async_load16(dst + 12288 + t * 8, Bg + (size_t)(ra + 128) * K + koff);
    } else {
      async_load16(dst + t * 8,         Ag + (size_t)ra * K + koff);
      async_load16(dst + 4096 + t * 8,  Bg + (size_t)ra * K + koff);
      async_load16(dst + 8192 + t * 8,  Bg + (size_t)(ra + 128) * K + koff);
    }
  };
  const int swl = (lh * 8) ^ ((lr & 6) << 2);  // swizzled within-row u16 offset
  auto read_af = [&](bf16x8* dst, int s) {
    const u16* sub = lds + (s & 3) * SUBU16;
#pragma unroll
    for (int mi = 0; mi < MIc; ++mi)
      dst[mi] = *reinterpret_cast<const bf16x8*>(sub + (wm * BMHALF + mi * 16 + lr) * 32 + swl);
  };
  auto read_bfv = [&](bf16x8* dst, int s) {
    const u16* sub = lds + (s & 3) * SUBU16 + BOFF;
#pragma unroll
    for (int ni = 0; ni < 4; ++ni) {
      int colf = ROPE ? ((wn >> 1) * 128 + (wn & 1) * 32 + (ni >> 1) * 64 + (ni & 1) * 16)
                      : (wn * 64 + ni * 16);
      dst[ni] = *reinterpret_cast<const bf16x8*>(sub + (colf + lr) * 32 + swl);
    }
  };

  f32x4 acc[MIc][4];
#pragma unroll
  for (int i = 0; i < MIc; ++i)
#pragma unroll
    for (int j = 0; j < 4; ++j) acc[i][j] = (f32x4){0.f, 0.f, 0.f, 0.f};

  const int NK = K >> 5;  // even
  bf16x8 afA[MIc], afB[MIc], bfvA[4], bfvB[4];

  stage(0); stage(1); stage(2);
  if constexpr (BMHALF == 128) asm volatile("s_waitcnt vmcnt(8)" ::: "memory");
  else                         asm volatile("s_waitcnt vmcnt(6)" ::: "memory");
  __builtin_amdgcn_s_barrier();
  asm volatile("" ::: "memory");
  read_af(afA, 0);
  read_bfv(bfvA, 0);

  auto pipestep = [&](int s, bf16x8* curA, bf16x8* curB, bf16x8* nxtA, bf16x8* nxtB) {
    if (s + 2 < NK) {
      if constexpr (BMHALF == 128) asm volatile("s_waitcnt vmcnt(4)" ::: "memory");
      else                         asm volatile("s_waitcnt vmcnt(3)" ::: "memory");
    } else {
      asm volatile("s_waitcnt vmcnt(0)" ::: "memory");
    }
    __builtin_amdgcn_s_barrier();
    asm volatile("" ::: "memory");
    if (s + 3 < NK) stage(s + 3);
    if (s + 1 < NK) {                 // prefetch s+1 frags: NOT consumed this step —
      read_af(nxtA, s + 1);           // LDS pipe overlaps the MFMA cluster below
      read_bfv(nxtB, s + 1);
    }
    __builtin_amdgcn_s_setprio(1);
#pragma unroll
    for (int mi = 0; mi < MIc; ++mi)
#pragma unroll
      for (int ni = 0; ni < 4; ++ni)
        acc[mi][ni] = __builtin_amdgcn_mfma_f32_16x16x32_bf16(curA[mi], curB[ni], acc[mi][ni], 0, 0, 0);
    __builtin_amdgcn_s_setprio(0);
  };

  for (int s = 0; s < NK; s += 2) {
    pipestep(s,     afA, bfvA, afB, bfvB);
    pipestep(s + 1, afB, bfvB, afA, bfvA);
  }

  if constexpr (ROPE) {
    float scale = (2 * tn + (wn >> 1)) < 16 ? qscale : 1.0f;
    size_t colbase = col0 + (wn >> 1) * 128;
#pragma unroll
    for (int mi = 0; mi < MIc; ++mi)
#pragma unroll
      for (int r = 0; r < 4; ++r) {
        size_t row = row0 + wm * BMHALF + mi * 16 + lh * 4 + r;
        int si = (int)(row & 2047);
        const float* cr = cosb + si * 128;
        const float* sr = sinb + si * 128;
#pragma unroll
        for (int ni = 0; ni < 2; ++ni) {
          int dlo = (wn & 1) * 32 + ni * 16 + lr;
          float v0 = acc[mi][ni][r];
          float v1 = acc[mi][ni + 2][r];
          float o0 = (v0 * cr[dlo] - v1 * sr[dlo]) * scale;
          float o1 = (v1 * cr[64 + dlo] + v0 * sr[64 + dlo]) * scale;
          ((u16*)C)[row * N + colbase + dlo]      = f2bf(o0);
          ((u16*)C)[row * N + colbase + 64 + dlo] = f2bf(o1);
        }
      }
  } else {
#pragma unroll
    for (int mi = 0; mi < MIc; ++mi)
#pragma unroll
      for (int ni = 0; ni < 4; ++ni)
#pragma unroll
        for (int r = 0; r < 4; ++r) {
          size_t row = row0 + wm * BMHALF + mi * 16 + lh * 4 + r;
          size_t col = col0 + wn * 64 + ni * 16 + lr;
          float v = acc[mi][ni][r];
          if (OUT_F32)
            ((float*)C)[row * N + col] = v;
          else
            ((u16*)C)[row * N + col] = f2bf(v);
        }
  }
}

// QK (256 blocks, 256x256, rope fused) + V^T (256 blocks, 128x256): 512 = 2 exact rounds
__global__ __launch_bounds__(512, 2)
void gemm_qkv256(const u16* __restrict__ xb, const u16* __restrict__ Wqkb,
                 const u16* __restrict__ Wvb, u16* __restrict__ QKb, u16* __restrict__ VTb,
                 const float* __restrict__ cosb, const float* __restrict__ sinb,
                 float qscale) {
  __shared__ __align__(16) u16 lds[4 * 16384];  // 128 KB
  int bid = blockIdx.x;
  if (bid < 256) {
    int swz = (bid & 7) * 32 + (bid >> 3);
    gemm_pipe_body<128, 1, 0>(xb, Wqkb, QKb, 4096, 4096, 2048, swz >> 4, swz & 15, lds,
                              cosb, sinb, qscale);
  } else {
    int b2 = bid - 256;
    int swz = (b2 & 7) * 32 + (b2 >> 3);
    gemm_pipe_body<64, 0, 0>(Wvb, xb, VTb, 2048, 4096, 2048, swz >> 4, swz & 15, lds,
                             nullptr, nullptr, 0.f);
  }
}

// out = O @ Wo^T (fp32 out): 256 blocks of 128x256 = 1 exact round
__global__ __launch_bounds__(512, 2)
void gemm_o(const u16* __restrict__ Ob, const u16* __restrict__ Wob, float* __restrict__ out) {
  __shared__ __align__(16) u16 lds[4 * 16384];
  int bid = blockIdx.x;
  int swz = (bid & 7) * 32 + (bid >> 3);
  gemm_pipe_body<64, 0, 1>(Ob, Wob, (void*)out, 4096, 2048, 2048, swz >> 3, swz & 7, lds,
                           nullptr, nullptr, 0.f);
}

// ---------------- Flash attention (proven structure; QKb strides) ----------------
// QK: [B*S][4096] bf16 (cols 0-2047 = roped*scaled Q, 2048-4095 = roped K).
// VT: [2048][4096] bf16. O: [B*S][2048] bf16.
// grid 512 = 32 bh * 16 qtiles(128); block 256 = 4 waves * 32 q-rows (2 qf of 16).
// Swapped QK^T / PV, in-lane softmax, K+V double-buffered, __syncthreads per tile.
__global__ __launch_bounds__(256, 2)
void attn_kernel(const u16* __restrict__ QKb, const u16* __restrict__ VT,
                 u16* __restrict__ Ob) {
  __shared__ __align__(16) u16 sK[2][64 * 128];   // 32 KB
  __shared__ __align__(16) u16 sV[2][128 * 64];   // 32 KB
  __shared__ __align__(16) u16 sP[4][32 * 64];    // 16 KB

  int id = blockIdx.x;
  int swz = (id & 7) * 64 + (id >> 3);    // XCD-chunked: 4 heads/XCD -> KV L2-resident
  int bh = swz >> 4;
  int qb = swz & 15;
  int b = bh >> 4, h = bh & 15;
  int t = threadIdx.x, w = t >> 6, l = t & 63;
  int lr = l & 15, lh = l >> 4;
  int lr7 = lr & 7;
  int q0 = qb * 128;

  const u16* Kbase = QKb + (size_t)(b * 2048) * 4096 + 2048 + h * 128;
  const u16* Vbase = VT + (size_t)(h * 128) * 4096 + b * 2048;
  u16* sPw = sP[w];

  bf16x8 aq[2][4];
#pragma unroll
  for (int qf = 0; qf < 2; ++qf) {
    size_t qrow = (size_t)(b * 2048 + q0 + w * 32 + qf * 16 + lr) * 4096 + h * 128;
#pragma unroll
    for (int c = 0; c < 4; ++c)
      aq[qf][c] = *reinterpret_cast<const bf16x8*>(QKb + qrow + c * 32 + lh * 8);
  }

  f32x4 zero = {0.f, 0.f, 0.f, 0.f};
  f32x4 acc_o[2][8];  // O^T[d][q=lr]
#pragma unroll
  for (int qf = 0; qf < 2; ++qf)
#pragma unroll
    for (int d = 0; d < 8; ++d) acc_o[qf][d] = zero;
  float m_row[2] = {-1e30f, -1e30f};
  float l_row[2] = {0.f, 0.f};

  auto stage = [&](int buf, int kt2) {
    const u16* Kt = Kbase + (size_t)(kt2 * 64) * 4096;
    const u16* Vt = Vbase + kt2 * 64;
#pragma unroll
    for (int it = 0; it < 4; ++it) {
      int o = it * 4096 + t * 16;            // byte offset in 16KB tile
      int rowK = o >> 8;
      int cbK = (o & 255) ^ ((rowK & 7) << 4);
      async_load16((u16*)sK[buf] + (o >> 1), Kt + (size_t)rowK * 4096 + (cbK >> 1));
      int rowV = o >> 7;
      int cbV = (o & 127) ^ ((rowV & 7) << 4);
      async_load16((u16*)sV[buf] + (o >> 1), Vt + (size_t)rowV * 4096 + (cbV >> 1));
    }
  };

  stage(0, 0);
  __syncthreads();
  int cur = 0;

  for (int kt = 0; kt < 32; ++kt) {
    if (kt < 31) stage(cur ^ 1, kt + 1);

    const u16* sKc = sK[cur];
    const u16* sVc = sV[cur];

    f32x4 sacc[2][4];
#pragma unroll
    for (int qf = 0; qf < 2; ++qf)
#pragma unroll
      for (int g = 0; g < 4; ++g) sacc[qf][g] = zero;
#pragma unroll
    for (int g = 0; g < 4; ++g) {
      int row = g * 16 + lr;
      int xr = lr7 << 4;
#pragma unroll
      for (int c = 0; c < 4; ++c) {
        int cb = (c * 64 + lh * 16) ^ xr;
        bf16x8 bk = *reinterpret_cast<const bf16x8*>(sKc + row * 128 + (cb >> 1));
        sacc[0][g] = __builtin_amdgcn_mfma_f32_16x16x32_bf16(bk, aq[0][c], sacc[0][g], 0, 0, 0);
        sacc[1][g] = __builtin_amdgcn_mfma_f32_16x16x32_bf16(bk, aq[1][c], sacc[1][g], 0, 0, 0);
      }
    }

#pragma unroll
    for (int qf = 0; qf < 2; ++qf) {
      f32x4 m4;
#pragma unroll
      for (int e = 0; e < 4; ++e)
        m4[e] = fmaxf(fmaxf(sacc[qf][0][e], sacc[qf][1][e]),
                      fmaxf(sacc[qf][2][e], sacc[qf][3][e]));
      float mx = fmaxf(fmaxf(m4[0], m4[1]), fmaxf(m4[2], m4[3]));
      mx = fmaxf(mx, __shfl_xor(mx, 16));
      mx = fmaxf(mx, __shfl_xor(mx, 32));
      float mo = m_row[qf];
      if (!__all(mx <= mo + 8.f)) {     // T13 defer-max
        float mn = fmaxf(mo, mx);
        float al = __builtin_amdgcn_exp2f(mo - mn);
        m_row[qf] = mn;
        l_row[qf] *= al;
#pragma unroll
        for (int d = 0; d < 8; ++d) acc_o[qf][d] *= al;
      }
      float mn = m_row[qf];
#pragma unroll
      for (int g = 0; g < 4; ++g)
#pragma unroll
        for (int e = 0; e < 4; ++e)
          sacc[qf][g][e] = __builtin_amdgcn_exp2f(sacc[qf][g][e] - mn);
      f32x4 s4;
#pragma unroll
      for (int e = 0; e < 4; ++e)
        s4[e] = (sacc[qf][0][e] + sacc[qf][1][e]) + (sacc[qf][2][e] + sacc[qf][3][e]);
      float rs = (s4[0] + s4[1]) + (s4[2] + s4[3]);
      rs += __shfl_xor(rs, 16);
      rs += __shfl_xor(rs, 32);
      l_row[qf] += rs;

      int rowb = (qf * 16 + lr) * 128;
      int xw = lr7 << 4;
#pragma unroll
      for (int g = 0; g < 4; ++g) {
        uint2 pw;
        pw.x = cvtpk(sacc[qf][g][0], sacc[qf][g][1]);
        pw.y = cvtpk(sacc[qf][g][2], sacc[qf][g][3]);
        int cb = (g * 32 + lh * 8) ^ xw;
        *reinterpret_cast<uint2*>(reinterpret_cast<char*>(sPw) + rowb + cb) = pw;
      }
    }

    bf16x8 bp[2][2];
#pragma unroll
    for (int qf = 0; qf < 2; ++qf) {
      int rowb = (qf * 16 + lr) * 128;
      int xr = lr7 << 4;
#pragma unroll
      for (int c2 = 0; c2 < 2; ++c2) {
        int cb = (c2 * 64 + lh * 16) ^ xr;
        bp[qf][c2] = *reinterpret_cast<const bf16x8*>(
            reinterpret_cast<const char*>(sPw) + rowb + cb);
      }
    }
#pragma unroll
    for (int c2 = 0; c2 < 2; ++c2) {
#pragma unroll
      for (int d = 0; d < 8; ++d) {
        int row = d * 16 + lr;
        int cb = (c2 * 64 + lh * 16) ^ (lr7 << 4);
        bf16x8 bv = *reinterpret_cast<const bf16x8*>(sVc + row * 64 + (cb >> 1));
        acc_o[0][d] = __builtin_amdgcn_mfma_f32_16x16x32_bf16(bv, bp[0][c2], acc_o[0][d], 0, 0, 0);
        acc_o[1][d] = __builtin_amdgcn_mfma_f32_16x16x32_bf16(bv, bp[1][c2], acc_o[1][d], 0, 0, 0);
      }
    }

    __syncthreads();
    cur ^= 1;
  }

#pragma unroll
  for (int qf = 0; qf < 2; ++qf) {
    float inv = 1.f / l_row[qf];
    size_t qrow = (size_t)(b * 2048 + q0 + w * 32 + qf * 16 + lr) * 2048 + h * 128;
#pragma unroll
    for (int d = 0; d < 8; ++d) {
      ushort4 o;
      o.x = f2bf(acc_o[qf][d][0] * inv);
      o.y = f2bf(acc_o[qf][d][1] * inv);
      o.z = f2bf(acc_o[qf][d][2] * inv);
      o.w = f2bf(acc_o[qf][d][3] * inv);
      *reinterpret_cast<ushort4*>(Ob + qrow + d * 16 + lh * 4) = o;
    }
  }
}

extern "C" void kernel_launch(void* const* d_in, const int* in_sizes, int n_in,
                              void* d_out, int out_size, void* d_ws, size_t ws_size,
                              hipStream_t stream) {
  const float* x  = (const float*)d_in[0];
  const float* rc = (const float*)d_in[1];
  const float* rs = (const float*)d_in[2];
  const float* Wq = (const float*)d_in[3];
  const float* Wk = (const float*)d_in[4];
  const float* Wv = (const float*)d_in[5];
  const float* Wo = (const float*)d_in[6];
  float* out = (float*)d_out;
  char* ws = (char*)d_ws;
  const size_t MB = 1024 * 1024;
  u16* xb   = (u16*)(ws);            // 16 MB
  u16* Wqkb = (u16*)(ws + 16 * MB);  // 16 MB  [4096][2048] = [Wq;Wk]
  u16* Wvb  = (u16*)(ws + 32 * MB);  // 8 MB
  u16* Wob  = (u16*)(ws + 40 * MB);  // 8 MB
  u16* QKb  = (u16*)(ws + 48 * MB);  // 32 MB  [4096][4096]
  u16* VTb  = (u16*)(ws + 80 * MB);  // 16 MB  [2048][4096]
  u16* Ob   = (u16*)(ws + 16 * MB);  // 16 MB  (alias Wqkb, dead after QK GEMM)

  convert_all<<<24576, 256, 0, stream>>>(x, Wq, Wk, Wv, Wo, xb, Wqkb, Wvb, Wob);

  const float qscale = 0.08838834764831845f * 1.4426950408889634f;  // 1/sqrt(128)*log2(e)
  gemm_qkv256<<<512, 512, 0, stream>>>(xb, Wqkb, Wvb, QKb, VTb, rc, rs, qscale);

  attn_kernel<<<512, 256, 0, stream>>>(QKb, VTb, Ob);

  gemm_o<<<256, 512, 0, stream>>>(Ob, Wob, out);
}

// Round 11
// 244.631 us; speedup vs baseline: 1.3857x; 1.0191x over previous
//
#include <hip/hip_runtime.h>
#include <hip/hip_bf16.h>

typedef unsigned short u16;
typedef __bf16 bf16x8 __attribute__((ext_vector_type(8)));
typedef float f32x4 __attribute__((ext_vector_type(4)));

__device__ __forceinline__ float bf2f(u16 u) {
  union { unsigned int i; float f; } v; v.i = ((unsigned int)u) << 16; return v.f;
}
__device__ __forceinline__ u16 f2bf(float f) {
  union { float f; unsigned int i; } v; v.f = f;
  unsigned int r = v.i + 0x7fffu + ((v.i >> 16) & 1u);
  return (u16)(r >> 16);
}
__device__ __forceinline__ unsigned cvtpk(float lo, float hi) {
  unsigned r;
  asm("v_cvt_pk_bf16_f32 %0, %1, %2" : "=v"(r) : "v"(lo), "v"(hi));
  return r;
}

__device__ __forceinline__ void async_load16(void* lds, const void* g) {
  __builtin_amdgcn_global_load_lds((const __attribute__((address_space(1))) void*)g,
                                   (__attribute__((address_space(3))) void*)lds, 16, 0, 0);
}

#define BARRIER() do { asm volatile("" ::: "memory"); __builtin_amdgcn_s_barrier(); \
                       asm volatile("" ::: "memory"); } while (0)

// ---------------- fused fp32 -> bf16 convert (x, Wq|Wk -> Wqk, Wv, Wo) ----------------
__global__ void convert_all(const float* __restrict__ x, const float* __restrict__ Wq,
                            const float* __restrict__ Wk, const float* __restrict__ Wv,
                            const float* __restrict__ Wo, u16* __restrict__ xb,
                            u16* __restrict__ Wqkb, u16* __restrict__ Wvb,
                            u16* __restrict__ Wob) {
  int bid = blockIdx.x;
  const float* src;
  u16* dst;
  int off;
  if (bid < 8192)       { src = x;  dst = xb;              off = bid; }
  else if (bid < 12288) { src = Wq; dst = Wqkb;            off = bid - 8192; }
  else if (bid < 16384) { src = Wk; dst = Wqkb + 4194304;  off = bid - 12288; }
  else if (bid < 20480) { src = Wv; dst = Wvb;             off = bid - 16384; }
  else                  { src = Wo; dst = Wob;             off = bid - 20480; }
  int i = off * 1024 + threadIdx.x * 4;
  float4 v = *(const float4*)(src + i);
  ushort4 o;
  o.x = f2bf(v.x); o.y = f2bf(v.y); o.z = f2bf(v.z); o.w = f2bf(v.w);
  *(ushort4*)(dst + i) = o;
}

// ======== QK: 256x256 8-phase GEMM (m201 template), BK=64, rope-fused epilogue ========
// C[M,4096] = A[M,2048] * B[4096,2048]^T. 512 thr = 8 waves (wm row-half, wn col-quarter).
// LDS 128KB = 2 bufs x 4 halves{A0,A1,B0,B1} x 16KB (128 rows x 64 k x 2B).
// Swizzle: byte-in-row ^= (row&7)<<4, via inverse-swizzled global source (rule 21).
// Per K-tile T (buf T&1), 4 phases = C-quadrants of 16 MFMA:
//   q0: read A(mi0-3)x2ks (8) + B(nj0-1)x2ks (4); stage A1(T+1); bar; MFMA; bar
//   q1: read B(nj2-3) (4);                        stage B1(T+1); bar; MFMA; bar
//   q2: read A(mi4-7) (8);                        stage B0(T+2); bar; MFMA; bar
//   q3: (no reads)                                stage A0(T+2); vmcnt(4); bar; MFMA; bar
// Hazard ledger: each staged slot's readers drained >=1 trailing barrier earlier
// (A1(T+1): last read tile T-1 q2; B1(T+1): T-1 q1; B0(T+2): T q1; A0(T+2): T q2).
// q3's vmcnt(4)+barrier => tile T+1 landed for ALL waves before its q0 reads.
// Tail: vmcnt(0) at q3 of tile NK-2. Never drains vmcnt mid-loop otherwise.
// B-frag cols permuted: nj -> (wn>>1)*128 + (wn&1)*32 + (nj&1)*16 + (nj>>1)*64, so
// rope pairs (d,d+64) = acc[mi][ni]/acc[mi][ni+2] in-lane.
__device__ __forceinline__ void gemm_qk_8phase(const u16* __restrict__ A,
                                               const u16* __restrict__ Bm,
                                               u16* __restrict__ C, int K,
                                               int tm, int tn, u16* lds,
                                               const float* __restrict__ cosb,
                                               const float* __restrict__ sinb,
                                               float qscale) {
  const int NK = K >> 6;  // 32
  const int t = threadIdx.x;
  const int w = t >> 6, l = t & 63;
  const int wm = w >> 2, wn = w & 3;
  const int lr = l & 15, lh = l >> 4;
  const size_t row0 = (size_t)tm * 256, col0 = (size_t)tn * 256;
  const u16* Ag = A + row0 * K;
  const u16* Bg = Bm + col0 * K;

  auto stage_half = [&](int T, int h) {  // h: 0=A0 1=A1 2=B0 3=B1 (2 loads/thread)
    u16* dst = lds + (T & 1) * 32768 + h * 8192;
    const u16* src = (h < 2) ? (Ag + (size_t)(h * 128) * K)
                             : (Bg + (size_t)((h - 2) * 128) * K);
    const int kb = T * 64;
#pragma unroll
    for (int it = 0; it < 2; ++it) {
      int o = it * 8192 + t * 16;                      // byte offset in 16KB half
      int r = o >> 7;                                  // 128B rows
      int cbs = (o & 127) ^ ((r & 7) << 4);            // inverse-swizzled source col
      async_load16(dst + (o >> 1), src + (size_t)r * K + kb + (cbs >> 1));
    }
  };

  bf16x8 afq[4][2], bLo[2][2], bHi[2][2];
  f32x4 acc[8][4];
#pragma unroll
  for (int i = 0; i < 8; ++i)
#pragma unroll
    for (int j = 0; j < 4; ++j) acc[i][j] = (f32x4){0.f, 0.f, 0.f, 0.f};

  auto read_a = [&](int T, int mh) {
    const u16* sub = lds + (T & 1) * 32768 + wm * 8192;
#pragma unroll
    for (int mi = 0; mi < 4; ++mi) {
      int r = (mh * 4 + mi) * 16 + lr;
      int bb = r * 128, xr = (r & 7) << 4;
#pragma unroll
      for (int ks = 0; ks < 2; ++ks)
        afq[mi][ks] = *reinterpret_cast<const bf16x8*>(
            sub + ((bb + ((ks * 64 + lh * 16) ^ xr)) >> 1));
    }
  };
  auto read_b = [&](bf16x8 (*dst)[2], int T, int nh) {
    const u16* sub = lds + (T & 1) * 32768 + (2 + (wn >> 1)) * 8192;
#pragma unroll
    for (int nj2 = 0; nj2 < 2; ++nj2) {
      int nj = nh * 2 + nj2;
      int c = (wn & 1) * 32 + (nj & 1) * 16 + (nj >> 1) * 64 + lr;
      int bb = c * 128, xr = (c & 7) << 4;
#pragma unroll
      for (int ks = 0; ks < 2; ++ks)
        dst[nj2][ks] = *reinterpret_cast<const bf16x8*>(
            sub + ((bb + ((ks * 64 + lh * 16) ^ xr)) >> 1));
    }
  };
  auto mfma_q = [&](bf16x8 (*bq)[2], int mh, int nh) {
    __builtin_amdgcn_s_setprio(1);
#pragma unroll
    for (int ks = 0; ks < 2; ++ks)
#pragma unroll
      for (int mi = 0; mi < 4; ++mi)
#pragma unroll
        for (int nj2 = 0; nj2 < 2; ++nj2)
          acc[mh * 4 + mi][nh * 2 + nj2] = __builtin_amdgcn_mfma_f32_16x16x32_bf16(
              afq[mi][ks], bq[nj2][ks], acc[mh * 4 + mi][nh * 2 + nj2], 0, 0, 0);
    __builtin_amdgcn_s_setprio(0);
  };

  // prologue: tile0 fully + tile1's B0,A0 (12 loads); wait tile0 (leave 4)
  stage_half(0, 2); stage_half(0, 0); stage_half(0, 1); stage_half(0, 3);
  stage_half(1, 2); stage_half(1, 0);
  asm volatile("s_waitcnt vmcnt(4)" ::: "memory");
  BARRIER();

  for (int T = 0; T < NK; ++T) {
    // ---- q0 ----
    read_a(T, 0);
    read_b(bLo, T, 0);
    if (T + 1 < NK) stage_half(T + 1, 1);   // A1(T+1)
    BARRIER();
    mfma_q(bLo, 0, 0);
    BARRIER();
    // ---- q1 ----
    read_b(bHi, T, 1);
    if (T + 1 < NK) stage_half(T + 1, 3);   // B1(T+1)
    BARRIER();
    mfma_q(bHi, 0, 1);
    BARRIER();
    // ---- q2 ----
    read_a(T, 1);
    if (T + 2 < NK) stage_half(T + 2, 2);   // B0(T+2)
    BARRIER();
    mfma_q(bLo, 1, 0);
    BARRIER();
    // ---- q3 ----
    if (T + 2 < NK) stage_half(T + 2, 0);   // A0(T+2)
    if (T + 1 <= NK - 2)      asm volatile("s_waitcnt vmcnt(4)" ::: "memory");
    else if (T + 1 == NK - 1) asm volatile("s_waitcnt vmcnt(0)" ::: "memory");
    BARRIER();
    mfma_q(bHi, 1, 1);
    BARRIER();
  }

  // rope epilogue (fp32 acc): pairs (ni, ni+2) in-lane
  float scale = (2 * tn + (wn >> 1)) < 16 ? qscale : 1.0f;
  size_t colbase = col0 + (wn >> 1) * 128;
#pragma unroll
  for (int mi = 0; mi < 8; ++mi)
#pragma unroll
    for (int r = 0; r < 4; ++r) {
      size_t row = row0 + wm * 128 + mi * 16 + lh * 4 + r;
      int si = (int)(row & 2047);
      const float* cr = cosb + si * 128;
      const float* sr = sinb + si * 128;
#pragma unroll
      for (int ni = 0; ni < 2; ++ni) {
        int dlo = (wn & 1) * 32 + ni * 16 + lr;
        float v0 = acc[mi][ni][r];
        float v1 = acc[mi][ni + 2][r];
        float o0 = (v0 * cr[dlo] - v1 * sr[dlo]) * scale;
        float o1 = (v1 * cr[64 + dlo] + v0 * sr[64 + dlo]) * scale;
        C[row * 4096 + colbase + dlo]      = f2bf(o0);
        C[row * 4096 + colbase + 64 + dlo] = f2bf(o1);
      }
    }
}

// ======== old pipelined body (ring-4 BK=32) — kept for V^T and gemm_o ========
template <int BMHALF, int OUT_F32>
__device__ __forceinline__ void gemm_pipe_body(const u16* __restrict__ A,
                                               const u16* __restrict__ Bm,
                                               void* __restrict__ C, int M, int N, int K,
                                               int tm, int tn, u16* lds) {
  constexpr int MIc = BMHALF / 16;
  constexpr int SUBU16 = (BMHALF == 128) ? 16384 : 12288;
  constexpr int BOFF = (BMHALF == 128) ? 8192 : 4096;
  const int t = threadIdx.x;
  const int w = t >> 6, l = t & 63;
  const int wm = w >> 2, wn = w & 3;
  const int lr = l & 15, lh = l >> 4;
  const size_t row0 = (size_t)tm * (2 * BMHALF), col0 = (size_t)tn * 256;
  const u16* Ag = A + row0 * K;
  const u16* Bg = Bm + col0 * K;

  const int ra = t >> 2;
  const int kcs = ((t & 3) << 3) ^ ((ra & 6) << 2);
  auto stage = [&](int s) {
    u16* dst = lds + (s & 3) * SUBU16;
    const size_t koff = (size_t)s * 32 + kcs;
    if constexpr (BMHALF == 128) {
      async_load16(dst + t * 8,         Ag + (size_t)ra * K + koff);
      async_load16(dst + 4096 + t * 8,  Ag + (size_t)(ra + 128) * K + koff);
      async_load16(dst + 8192 + t * 8,  Bg + (size_t)ra * K + koff);
      async_load16(dst + 12288 + t * 8, Bg + (size_t)(ra + 128) * K + koff);
    } else {
      async_load16(dst + t * 8,         Ag + (size_t)ra * K + koff);
      async_load16(dst + 4096 + t * 8,  Bg + (size_t)ra * K + koff);
      async_load16(dst + 8192 + t * 8,  Bg + (size_t)(ra + 128) * K + koff);
    }
  };
  const int swl = (lh * 8) ^ ((lr & 6) << 2);
  auto read_af = [&](bf16x8* dst, int s) {
    const u16* sub = lds + (s & 3) * SUBU16;
#pragma unroll
    for (int mi = 0; mi < MIc; ++mi)
      dst[mi] = *reinterpret_cast<const bf16x8*>(sub + (wm * BMHALF + mi * 16 + lr) * 32 + swl);
  };
  auto read_bfv = [&](bf16x8* dst, int s) {
    const u16* sub = lds + (s & 3) * SUBU16 + BOFF;
#pragma unroll
    for (int ni = 0; ni < 4; ++ni)
      dst[ni] = *reinterpret_cast<const bf16x8*>(sub + (wn * 64 + ni * 16 + lr) * 32 + swl);
  };

  f32x4 acc[MIc][4];
#pragma unroll
  for (int i = 0; i < MIc; ++i)
#pragma unroll
    for (int j = 0; j < 4; ++j) acc[i][j] = (f32x4){0.f, 0.f, 0.f, 0.f};

  const int NK = K >> 5;
  bf16x8 afA[MIc], afB[MIc], bfvA[4], bfvB[4];

  stage(0); stage(1); stage(2);
  if constexpr (BMHALF == 128) asm volatile("s_waitcnt vmcnt(8)" ::: "memory");
  else                         asm volatile("s_waitcnt vmcnt(6)" ::: "memory");
  BARRIER();
  read_af(afA, 0);
  read_bfv(bfvA, 0);

  auto pipestep = [&](int s, bf16x8* curA, bf16x8* curB, bf16x8* nxtA, bf16x8* nxtB) {
    if (s + 2 < NK) {
      if constexpr (BMHALF == 128) asm volatile("s_waitcnt vmcnt(4)" ::: "memory");
      else                         asm volatile("s_waitcnt vmcnt(3)" ::: "memory");
    } else {
      asm volatile("s_waitcnt vmcnt(0)" ::: "memory");
    }
    BARRIER();
    if (s + 3 < NK) stage(s + 3);
    if (s + 1 < NK) {
      read_af(nxtA, s + 1);
      read_bfv(nxtB, s + 1);
    }
    __builtin_amdgcn_s_setprio(1);
#pragma unroll
    for (int mi = 0; mi < MIc; ++mi)
#pragma unroll
      for (int ni = 0; ni < 4; ++ni)
        acc[mi][ni] = __builtin_amdgcn_mfma_f32_16x16x32_bf16(curA[mi], curB[ni], acc[mi][ni], 0, 0, 0);
    __builtin_amdgcn_s_setprio(0);
  };

  for (int s = 0; s < NK; s += 2) {
    pipestep(s,     afA, bfvA, afB, bfvB);
    pipestep(s + 1, afB, bfvB, afA, bfvA);
  }

#pragma unroll
  for (int mi = 0; mi < MIc; ++mi)
#pragma unroll
    for (int ni = 0; ni < 4; ++ni)
#pragma unroll
      for (int r = 0; r < 4; ++r) {
        size_t row = row0 + wm * BMHALF + mi * 16 + lh * 4 + r;
        size_t col = col0 + wn * 64 + ni * 16 + lr;
        float v = acc[mi][ni][r];
        if (OUT_F32)
          ((float*)C)[row * N + col] = v;
        else
          ((u16*)C)[row * N + col] = f2bf(v);
      }
}

// QK (256 blocks, 8-phase 256x256, rope fused) + V^T (256 blocks, 128x256 old pipe)
__global__ __launch_bounds__(512, 2)
void gemm_qkv256(const u16* __restrict__ xb, const u16* __restrict__ Wqkb,
                 const u16* __restrict__ Wvb, u16* __restrict__ QKb, u16* __restrict__ VTb,
                 const float* __restrict__ cosb, const float* __restrict__ sinb,
                 float qscale) {
  __shared__ __align__(16) u16 lds[65536];  // 128 KB
  int bid = blockIdx.x;
  if (bid < 256) {
    int swz = (bid & 7) * 32 + (bid >> 3);
    gemm_qk_8phase(xb, Wqkb, QKb, 2048, swz >> 4, swz & 15, lds, cosb, sinb, qscale);
  } else {
    int b2 = bid - 256;
    int swz = (b2 & 7) * 32 + (b2 >> 3);
    gemm_pipe_body<64, 0>(Wvb, xb, VTb, 2048, 4096, 2048, swz >> 4, swz & 15, lds);
  }
}

// out = O @ Wo^T (fp32 out): 256 blocks of 128x256 = 1 exact round
__global__ __launch_bounds__(512, 2)
void gemm_o(const u16* __restrict__ Ob, const u16* __restrict__ Wob, float* __restrict__ out) {
  __shared__ __align__(16) u16 lds[4 * 12288];
  int bid = blockIdx.x;
  int swz = (bid & 7) * 32 + (bid >> 3);
  gemm_pipe_body<64, 1>(Ob, Wob, (void*)out, 4096, 2048, 2048, swz >> 3, swz & 7, lds);
}

// ---------------- Flash attention (proven structure; QKb strides) ----------------
__global__ __launch_bounds__(256, 2)
void attn_kernel(const u16* __restrict__ QKb, const u16* __restrict__ VT,
                 u16* __restrict__ Ob) {
  __shared__ __align__(16) u16 sK[2][64 * 128];   // 32 KB
  __shared__ __align__(16) u16 sV[2][128 * 64];   // 32 KB
  __shared__ __align__(16) u16 sP[4][32 * 64];    // 16 KB

  int id = blockIdx.x;
  int swz = (id & 7) * 64 + (id >> 3);
  int bh = swz >> 4;
  int qb = swz & 15;
  int b = bh >> 4, h = bh & 15;
  int t = threadIdx.x, w = t >> 6, l = t & 63;
  int lr = l & 15, lh = l >> 4;
  int lr7 = lr & 7;
  int q0 = qb * 128;

  const u16* Kbase = QKb + (size_t)(b * 2048) * 4096 + 2048 + h * 128;
  const u16* Vbase = VT + (size_t)(h * 128) * 4096 + b * 2048;
  u16* sPw = sP[w];

  bf16x8 aq[2][4];
#pragma unroll
  for (int qf = 0; qf < 2; ++qf) {
    size_t qrow = (size_t)(b * 2048 + q0 + w * 32 + qf * 16 + lr) * 4096 + h * 128;
#pragma unroll
    for (int c = 0; c < 4; ++c)
      aq[qf][c] = *reinterpret_cast<const bf16x8*>(QKb + qrow + c * 32 + lh * 8);
  }

  f32x4 zero = {0.f, 0.f, 0.f, 0.f};
  f32x4 acc_o[2][8];
#pragma unroll
  for (int qf = 0; qf < 2; ++qf)
#pragma unroll
    for (int d = 0; d < 8; ++d) acc_o[qf][d] = zero;
  float m_row[2] = {-1e30f, -1e30f};
  float l_row[2] = {0.f, 0.f};

  auto stage = [&](int buf, int kt2) {
    const u16* Kt = Kbase + (size_t)(kt2 * 64) * 4096;
    const u16* Vt = Vbase + kt2 * 64;
#pragma unroll
    for (int it = 0; it < 4; ++it) {
      int o = it * 4096 + t * 16;
      int rowK = o >> 8;
      int cbK = (o & 255) ^ ((rowK & 7) << 4);
      async_load16((u16*)sK[buf] + (o >> 1), Kt + (size_t)rowK * 4096 + (cbK >> 1));
      int rowV = o >> 7;
      int cbV = (o & 127) ^ ((rowV & 7) << 4);
      async_load16((u16*)sV[buf] + (o >> 1), Vt + (size_t)rowV * 4096 + (cbV >> 1));
    }
  };

  stage(0, 0);
  __syncthreads();
  int cur = 0;

  for (int kt = 0; kt < 32; ++kt) {
    if (kt < 31) stage(cur ^ 1, kt + 1);

    const u16* sKc = sK[cur];
    const u16* sVc = sV[cur];

    f32x4 sacc[2][4];
#pragma unroll
    for (int qf = 0; qf < 2; ++qf)
#pragma unroll
      for (int g = 0; g < 4; ++g) sacc[qf][g] = zero;
#pragma unroll
    for (int g = 0; g < 4; ++g) {
      int row = g * 16 + lr;
      int xr = lr7 << 4;
#pragma unroll
      for (int c = 0; c < 4; ++c) {
        int cb = (c * 64 + lh * 16) ^ xr;
        bf16x8 bk = *reinterpret_cast<const bf16x8*>(sKc + row * 128 + (cb >> 1));
        sacc[0][g] = __builtin_amdgcn_mfma_f32_16x16x32_bf16(bk, aq[0][c], sacc[0][g], 0, 0, 0);
        sacc[1][g] = __builtin_amdgcn_mfma_f32_16x16x32_bf16(bk, aq[1][c], sacc[1][g], 0, 0, 0);
      }
    }

#pragma unroll
    for (int qf = 0; qf < 2; ++qf) {
      f32x4 m4;
#pragma unroll
      for (int e = 0; e < 4; ++e)
        m4[e] = fmaxf(fmaxf(sacc[qf][0][e], sacc[qf][1][e]),
                      fmaxf(sacc[qf][2][e], sacc[qf][3][e]));
      float mx = fmaxf(fmaxf(m4[0], m4[1]), fmaxf(m4[2], m4[3]));
      mx = fmaxf(mx, __shfl_xor(mx, 16));
      mx = fmaxf(mx, __shfl_xor(mx, 32));
      float mo = m_row[qf];
      if (!__all(mx <= mo + 8.f)) {
        float mn = fmaxf(mo, mx);
        float al = __builtin_amdgcn_exp2f(mo - mn);
        m_row[qf] = mn;
        l_row[qf] *= al;
#pragma unroll
        for (int d = 0; d < 8; ++d) acc_o[qf][d] *= al;
      }
      float mn = m_row[qf];
#pragma unroll
      for (int g = 0; g < 4; ++g)
#pragma unroll
        for (int e = 0; e < 4; ++e)
          sacc[qf][g][e] = __builtin_amdgcn_exp2f(sacc[qf][g][e] - mn);
      f32x4 s4;
#pragma unroll
      for (int e = 0; e < 4; ++e)
        s4[e] = (sacc[qf][0][e] + sacc[qf][1][e]) + (sacc[qf][2][e] + sacc[qf][3][e]);
      float rs = (s4[0] + s4[1]) + (s4[2] + s4[3]);
      rs += __shfl_xor(rs, 16);
      rs += __shfl_xor(rs, 32);
      l_row[qf] += rs;

      int rowb = (qf * 16 + lr) * 128;
      int xw = lr7 << 4;
#pragma unroll
      for (int g = 0; g < 4; ++g) {
        uint2 pw;
        pw.x = cvtpk(sacc[qf][g][0], sacc[qf][g][1]);
        pw.y = cvtpk(sacc[qf][g][2], sacc[qf][g][3]);
        int cb = (g * 32 + lh * 8) ^ xw;
        *reinterpret_cast<uint2*>(reinterpret_cast<char*>(sPw) + rowb + cb) = pw;
      }
    }

    bf16x8 bp[2][2];
#pragma unroll
    for (int qf = 0; qf < 2; ++qf) {
      int rowb = (qf * 16 + lr) * 128;
      int xr = lr7 << 4;
#pragma unroll
      for (int c2 = 0; c2 < 2; ++c2) {
        int cb = (c2 * 64 + lh * 16) ^ xr;
        bp[qf][c2] = *reinterpret_cast<const bf16x8*>(
            reinterpret_cast<const char*>(sPw) + rowb + cb);
      }
    }
#pragma unroll
    for (int c2 = 0; c2 < 2; ++c2) {
#pragma unroll
      for (int d = 0; d < 8; ++d) {
        int row = d * 16 + lr;
        int cb = (c2 * 64 + lh * 16) ^ (lr7 << 4);
        bf16x8 bv = *reinterpret_cast<const bf16x8*>(sVc + row * 64 + (cb >> 1));
        acc_o[0][d] = __builtin_amdgcn_mfma_f32_16x16x32_bf16(bv, bp[0][c2], acc_o[0][d], 0, 0, 0);
        acc_o[1][d] = __builtin_amdgcn_mfma_f32_16x16x32_bf16(bv, bp[1][c2], acc_o[1][d], 0, 0, 0);
      }
    }

    __syncthreads();
    cur ^= 1;
  }

#pragma unroll
  for (int qf = 0; qf < 2; ++qf) {
    float inv = 1.f / l_row[qf];
    size_t qrow = (size_t)(b * 2048 + q0 + w * 32 + qf * 16 + lr) * 2048 + h * 128;
#pragma unroll
    for (int d = 0; d < 8; ++d) {
      ushort4 o;
      o.x = f2bf(acc_o[qf][d][0] * inv);
      o.y = f2bf(acc_o[qf][d][1] * inv);
      o.z = f2bf(acc_o[qf][d][2] * inv);
      o.w = f2bf(acc_o[qf][d][3] * inv);
      *reinterpret_cast<ushort4*>(Ob + qrow + d * 16 + lh * 4) = o;
    }
  }
}

extern "C" void kernel_launch(void* const* d_in, const int* in_sizes, int n_in,
                              void* d_out, int out_size, void* d_ws, size_t ws_size,
                              hipStream_t stream) {
  const float* x  = (const float*)d_in[0];
  const float* rc = (const float*)d_in[1];
  const float* rs = (const float*)d_in[2];
  const float* Wq = (const float*)d_in[3];
  const float* Wk = (const float*)d_in[4];
  const float* Wv = (const float*)d_in[5];
  const float* Wo = (const float*)d_in[6];
  float* out = (float*)d_out;
  char* ws = (char*)d_ws;
  const size_t MB = 1024 * 1024;
  u16* xb   = (u16*)(ws);            // 16 MB
  u16* Wqkb = (u16*)(ws + 16 * MB);  // 16 MB  [4096][2048] = [Wq;Wk]
  u16* Wvb  = (u16*)(ws + 32 * MB);  // 8 MB
  u16* Wob  = (u16*)(ws + 40 * MB);  // 8 MB
  u16* QKb  = (u16*)(ws + 48 * MB);  // 32 MB  [4096][4096]
  u16* VTb  = (u16*)(ws + 80 * MB);  // 16 MB  [2048][4096]
  u16* Ob   = (u16*)(ws + 16 * MB);  // 16 MB  (alias Wqkb, dead after QK GEMM)

  convert_all<<<24576, 256, 0, stream>>>(x, Wq, Wk, Wv, Wo, xb, Wqkb, Wvb, Wob);

  const float qscale = 0.08838834764831845f * 1.4426950408889634f;  // 1/sqrt(128)*log2(e)
  gemm_qkv256<<<512, 512, 0, stream>>>(xb, Wqkb, Wvb, QKb, VTb, rc, rs, qscale);

  attn_kernel<<<512, 256, 0, stream>>>(QKb, VTb, Ob);

  gemm_o<<<256, 512, 0, stream>>>(Ob, Wob, out);
}

// Round 12
// 241.961 us; speedup vs baseline: 1.4010x; 1.0110x over previous
//
#include <hip/hip_runtime.h>
#include <hip/hip_bf16.h>

typedef unsigned short u16;
typedef __bf16 bf16x8 __attribute__((ext_vector_type(8)));
typedef float f32x4 __attribute__((ext_vector_type(4)));

__device__ __forceinline__ float bf2f(u16 u) {
  union { unsigned int i; float f; } v; v.i = ((unsigned int)u) << 16; return v.f;
}
__device__ __forceinline__ u16 f2bf(float f) {
  union { float f; unsigned int i; } v; v.f = f;
  unsigned int r = v.i + 0x7fffu + ((v.i >> 16) & 1u);
  return (u16)(r >> 16);
}
__device__ __forceinline__ unsigned cvtpk(float lo, float hi) {
  unsigned r;
  asm("v_cvt_pk_bf16_f32 %0, %1, %2" : "=v"(r) : "v"(lo), "v"(hi));
  return r;
}

__device__ __forceinline__ void async_load16(void* lds, const void* g) {
  __builtin_amdgcn_global_load_lds((const __attribute__((address_space(1))) void*)g,
                                   (__attribute__((address_space(3))) void*)lds, 16, 0, 0);
}

#define BARRIER() do { asm volatile("" ::: "memory"); __builtin_amdgcn_s_barrier(); \
                       asm volatile("" ::: "memory"); } while (0)
// m201 wait discipline: after entry barrier, drain DS and pin the scheduler so the
// MFMA cluster stays clustered (rule 18: sched_barrier required after asm lgkmcnt).
#define LGKM0_PIN() do { asm volatile("s_waitcnt lgkmcnt(0)" ::: "memory"); \
                         __builtin_amdgcn_sched_barrier(0); } while (0)

// ---------------- fused fp32 -> bf16 convert (x, Wq|Wk -> Wqk, Wv, Wo) ----------------
__global__ void convert_all(const float* __restrict__ x, const float* __restrict__ Wq,
                            const float* __restrict__ Wk, const float* __restrict__ Wv,
                            const float* __restrict__ Wo, u16* __restrict__ xb,
                            u16* __restrict__ Wqkb, u16* __restrict__ Wvb,
                            u16* __restrict__ Wob) {
  int bid = blockIdx.x;
  const float* src;
  u16* dst;
  int off;
  if (bid < 8192)       { src = x;  dst = xb;              off = bid; }
  else if (bid < 12288) { src = Wq; dst = Wqkb;            off = bid - 8192; }
  else if (bid < 16384) { src = Wk; dst = Wqkb + 4194304;  off = bid - 12288; }
  else if (bid < 20480) { src = Wv; dst = Wvb;             off = bid - 16384; }
  else                  { src = Wo; dst = Wob;             off = bid - 20480; }
  int i = off * 1024 + threadIdx.x * 4;
  float4 v = *(const float4*)(src + i);
  ushort4 o;
  o.x = f2bf(v.x); o.y = f2bf(v.y); o.z = f2bf(v.z); o.w = f2bf(v.w);
  *(ushort4*)(dst + i) = o;
}

// ======== QK: 256x256 8-phase GEMM (m201 template), BK=64, rope-fused epilogue ========
// C[M,4096] = A[M,2048] * B[4096,2048]^T. 512 thr = 8 waves (wm row-half, wn col-quarter).
// LDS 128KB = 2 bufs x 4 halves{A0,A1,B0,B1} x 16KB (128 rows x 64 k x 2B).
// Swizzle: byte-in-row ^= (row&7)<<4, via inverse-swizzled global source (rule 21).
// Per K-tile T (buf T&1), 4 phases = C-quadrants of 16 MFMA:
//   q0: read A(mi0-3)x2ks (8) + B(nj0-1)x2ks (4); stage A1(T+1); lgkm(8); bar;
//       lgkm(0)+schedpin; MFMA; bar
//   q1: read B(nj2-3) (4); stage B1(T+1); bar; lgkm(0)+pin; MFMA; bar
//   q2: read A(mi4-7) (8); stage B0(T+2); bar; lgkm(0)+pin; MFMA; bar
//   q3: stage A0(T+2); vmcnt(4); bar; MFMA(no new reads); bar
// Hazard ledger (verified r11): each staged slot's readers drained >=1 trailing
// barrier earlier; q3's vmcnt(4)+barrier => tile T+1 landed for ALL waves.
// B-frag cols permuted: nj -> (wn&1)*32 + (nj&1)*16 + (nj>>1)*64 within (wn>>1)*128,
// so rope pairs (d,d+64) = acc[mi][ni]/acc[mi][ni+2] in-lane.
__device__ __forceinline__ void gemm_qk_8phase(const u16* __restrict__ A,
                                               const u16* __restrict__ Bm,
                                               u16* __restrict__ C, int K,
                                               int tm, int tn, u16* lds,
                                               const float* __restrict__ cosb,
                                               const float* __restrict__ sinb,
                                               float qscale) {
  const int NK = K >> 6;  // 32
  const int t = threadIdx.x;
  const int w = t >> 6, l = t & 63;
  const int wm = w >> 2, wn = w & 3;
  const int lr = l & 15, lh = l >> 4;
  const size_t row0 = (size_t)tm * 256, col0 = (size_t)tn * 256;
  const u16* Ag = A + row0 * K;
  const u16* Bg = Bm + col0 * K;

  auto stage_half = [&](int T, int h) {  // h: 0=A0 1=A1 2=B0 3=B1 (2 loads/thread)
    u16* dst = lds + (T & 1) * 32768 + h * 8192;
    const u16* src = (h < 2) ? (Ag + (size_t)(h * 128) * K)
                             : (Bg + (size_t)((h - 2) * 128) * K);
    const int kb = T * 64;
#pragma unroll
    for (int it = 0; it < 2; ++it) {
      int o = it * 8192 + t * 16;                      // byte offset in 16KB half
      int r = o >> 7;                                  // 128B rows
      int cbs = (o & 127) ^ ((r & 7) << 4);            // inverse-swizzled source col
      async_load16(dst + (o >> 1), src + (size_t)r * K + kb + (cbs >> 1));
    }
  };

  bf16x8 afq[4][2], bLo[2][2], bHi[2][2];
  f32x4 acc[8][4];
#pragma unroll
  for (int i = 0; i < 8; ++i)
#pragma unroll
    for (int j = 0; j < 4; ++j) acc[i][j] = (f32x4){0.f, 0.f, 0.f, 0.f};

  auto read_a = [&](int T, int mh) {
    const u16* sub = lds + (T & 1) * 32768 + wm * 8192;
#pragma unroll
    for (int mi = 0; mi < 4; ++mi) {
      int r = (mh * 4 + mi) * 16 + lr;
      int bb = r * 128, xr = (r & 7) << 4;
#pragma unroll
      for (int ks = 0; ks < 2; ++ks)
        afq[mi][ks] = *reinterpret_cast<const bf16x8*>(
            sub + ((bb + ((ks * 64 + lh * 16) ^ xr)) >> 1));
    }
  };
  auto read_b = [&](bf16x8 (*dst)[2], int T, int nh) {
    const u16* sub = lds + (T & 1) * 32768 + (2 + (wn >> 1)) * 8192;
#pragma unroll
    for (int nj2 = 0; nj2 < 2; ++nj2) {
      int nj = nh * 2 + nj2;
      int c = (wn & 1) * 32 + (nj & 1) * 16 + (nj >> 1) * 64 + lr;
      int bb = c * 128, xr = (c & 7) << 4;
#pragma unroll
      for (int ks = 0; ks < 2; ++ks)
        dst[nj2][ks] = *reinterpret_cast<const bf16x8*>(
            sub + ((bb + ((ks * 64 + lh * 16) ^ xr)) >> 1));
    }
  };
  auto mfma_q = [&](bf16x8 (*bq)[2], int mh, int nh) {
    __builtin_amdgcn_s_setprio(1);
#pragma unroll
    for (int ks = 0; ks < 2; ++ks)
#pragma unroll
      for (int mi = 0; mi < 4; ++mi)
#pragma unroll
        for (int nj2 = 0; nj2 < 2; ++nj2)
          acc[mh * 4 + mi][nh * 2 + nj2] = __builtin_amdgcn_mfma_f32_16x16x32_bf16(
              afq[mi][ks], bq[nj2][ks], acc[mh * 4 + mi][nh * 2 + nj2], 0, 0, 0);
    __builtin_amdgcn_s_setprio(0);
  };

  // prologue: tile0 fully + tile1's B0,A0 (12 loads); wait tile0 (leave 4)
  stage_half(0, 2); stage_half(0, 0); stage_half(0, 1); stage_half(0, 3);
  stage_half(1, 2); stage_half(1, 0);
  asm volatile("s_waitcnt vmcnt(4)" ::: "memory");
  BARRIER();

  for (int T = 0; T < NK; ++T) {
    // ---- q0 ----
    read_a(T, 0);
    read_b(bLo, T, 0);
    if (T + 1 < NK) stage_half(T + 1, 1);   // A1(T+1)
    asm volatile("s_waitcnt lgkmcnt(8)" ::: "memory");  // throttle (12-read phase)
    BARRIER();
    LGKM0_PIN();
    mfma_q(bLo, 0, 0);
    BARRIER();
    // ---- q1 ----
    read_b(bHi, T, 1);
    if (T + 1 < NK) stage_half(T + 1, 3);   // B1(T+1)
    BARRIER();
    LGKM0_PIN();
    mfma_q(bHi, 0, 1);
    BARRIER();
    // ---- q2 ----
    read_a(T, 1);
    if (T + 2 < NK) stage_half(T + 2, 2);   // B0(T+2)
    BARRIER();
    LGKM0_PIN();
    mfma_q(bLo, 1, 0);
    BARRIER();
    // ---- q3 ----
    if (T + 2 < NK) stage_half(T + 2, 0);   // A0(T+2)
    if (T + 1 <= NK - 2)      asm volatile("s_waitcnt vmcnt(4)" ::: "memory");
    else if (T + 1 == NK - 1) asm volatile("s_waitcnt vmcnt(0)" ::: "memory");
    BARRIER();
    mfma_q(bHi, 1, 1);
    BARRIER();
  }

  // rope epilogue (fp32 acc): pairs (ni, ni+2) in-lane
  float scale = (2 * tn + (wn >> 1)) < 16 ? qscale : 1.0f;
  size_t colbase = col0 + (wn >> 1) * 128;
#pragma unroll
  for (int mi = 0; mi < 8; ++mi)
#pragma unroll
    for (int r = 0; r < 4; ++r) {
      size_t row = row0 + wm * 128 + mi * 16 + lh * 4 + r;
      int si = (int)(row & 2047);
      const float* cr = cosb + si * 128;
      const float* sr = sinb + si * 128;
#pragma unroll
      for (int ni = 0; ni < 2; ++ni) {
        int dlo = (wn & 1) * 32 + ni * 16 + lr;
        float v0 = acc[mi][ni][r];
        float v1 = acc[mi][ni + 2][r];
        float o0 = (v0 * cr[dlo] - v1 * sr[dlo]) * scale;
        float o1 = (v1 * cr[64 + dlo] + v0 * sr[64 + dlo]) * scale;
        C[row * 4096 + colbase + dlo]      = f2bf(o0);
        C[row * 4096 + colbase + 64 + dlo] = f2bf(o1);
      }
    }
}

// ======== old pipelined body (ring-4 BK=32) — kept for V^T and gemm_o ========
template <int BMHALF, int OUT_F32>
__device__ __forceinline__ void gemm_pipe_body(const u16* __restrict__ A,
                                               const u16* __restrict__ Bm,
                                               void* __restrict__ C, int M, int N, int K,
                                               int tm, int tn, u16* lds) {
  constexpr int MIc = BMHALF / 16;
  constexpr int SUBU16 = (BMHALF == 128) ? 16384 : 12288;
  constexpr int BOFF = (BMHALF == 128) ? 8192 : 4096;
  const int t = threadIdx.x;
  const int w = t >> 6, l = t & 63;
  const int wm = w >> 2, wn = w & 3;
  const int lr = l & 15, lh = l >> 4;
  const size_t row0 = (size_t)tm * (2 * BMHALF), col0 = (size_t)tn * 256;
  const u16* Ag = A + row0 * K;
  const u16* Bg = Bm + col0 * K;

  const int ra = t >> 2;
  const int kcs = ((t & 3) << 3) ^ ((ra & 6) << 2);
  auto stage = [&](int s) {
    u16* dst = lds + (s & 3) * SUBU16;
    const size_t koff = (size_t)s * 32 + kcs;
    if constexpr (BMHALF == 128) {
      async_load16(dst + t * 8,         Ag + (size_t)ra * K + koff);
      async_load16(dst + 4096 + t * 8,  Ag + (size_t)(ra + 128) * K + koff);
      async_load16(dst + 8192 + t * 8,  Bg + (size_t)ra * K + koff);
      async_load16(dst + 12288 + t * 8, Bg + (size_t)(ra + 128) * K + koff);
    } else {
      async_load16(dst + t * 8,         Ag + (size_t)ra * K + koff);
      async_load16(dst + 4096 + t * 8,  Bg + (size_t)ra * K + koff);
      async_load16(dst + 8192 + t * 8,  Bg + (size_t)(ra + 128) * K + koff);
    }
  };
  const int swl = (lh * 8) ^ ((lr & 6) << 2);
  auto read_af = [&](bf16x8* dst, int s) {
    const u16* sub = lds + (s & 3) * SUBU16;
#pragma unroll
    for (int mi = 0; mi < MIc; ++mi)
      dst[mi] = *reinterpret_cast<const bf16x8*>(sub + (wm * BMHALF + mi * 16 + lr) * 32 + swl);
  };
  auto read_bfv = [&](bf16x8* dst, int s) {
    const u16* sub = lds + (s & 3) * SUBU16 + BOFF;
#pragma unroll
    for (int ni = 0; ni < 4; ++ni)
      dst[ni] = *reinterpret_cast<const bf16x8*>(sub + (wn * 64 + ni * 16 + lr) * 32 + swl);
  };

  f32x4 acc[MIc][4];
#pragma unroll
  for (int i = 0; i < MIc; ++i)
#pragma unroll
    for (int j = 0; j < 4; ++j) acc[i][j] = (f32x4){0.f, 0.f, 0.f, 0.f};

  const int NK = K >> 5;
  bf16x8 afA[MIc], afB[MIc], bfvA[4], bfvB[4];

  stage(0); stage(1); stage(2);
  if constexpr (BMHALF == 128) asm volatile("s_waitcnt vmcnt(8)" ::: "memory");
  else                         asm volatile("s_waitcnt vmcnt(6)" ::: "memory");
  BARRIER();
  read_af(afA, 0);
  read_bfv(bfvA, 0);

  auto pipestep = [&](int s, bf16x8* curA, bf16x8* curB, bf16x8* nxtA, bf16x8* nxtB) {
    if (s + 2 < NK) {
      if constexpr (BMHALF == 128) asm volatile("s_waitcnt vmcnt(4)" ::: "memory");
      else                         asm volatile("s_waitcnt vmcnt(3)" ::: "memory");
    } else {
      asm volatile("s_waitcnt vmcnt(0)" ::: "memory");
    }
    BARRIER();
    if (s + 3 < NK) stage(s + 3);
    if (s + 1 < NK) {
      read_af(nxtA, s + 1);
      read_bfv(nxtB, s + 1);
    }
    __builtin_amdgcn_s_setprio(1);
#pragma unroll
    for (int mi = 0; mi < MIc; ++mi)
#pragma unroll
      for (int ni = 0; ni < 4; ++ni)
        acc[mi][ni] = __builtin_amdgcn_mfma_f32_16x16x32_bf16(curA[mi], curB[ni], acc[mi][ni], 0, 0, 0);
    __builtin_amdgcn_s_setprio(0);
  };

  for (int s = 0; s < NK; s += 2) {
    pipestep(s,     afA, bfvA, afB, bfvB);
    pipestep(s + 1, afB, bfvB, afA, bfvA);
  }

#pragma unroll
  for (int mi = 0; mi < MIc; ++mi)
#pragma unroll
    for (int ni = 0; ni < 4; ++ni)
#pragma unroll
      for (int r = 0; r < 4; ++r) {
        size_t row = row0 + wm * BMHALF + mi * 16 + lh * 4 + r;
        size_t col = col0 + wn * 64 + ni * 16 + lr;
        float v = acc[mi][ni][r];
        if (OUT_F32)
          ((float*)C)[row * N + col] = v;
        else
          ((u16*)C)[row * N + col] = f2bf(v);
      }
}

// QK (256 blocks, 8-phase 256x256, rope fused) + V^T (256 blocks, 128x256 old pipe)
__global__ __launch_bounds__(512, 2)
void gemm_qkv256(const u16* __restrict__ xb, const u16* __restrict__ Wqkb,
                 const u16* __restrict__ Wvb, u16* __restrict__ QKb, u16* __restrict__ VTb,
                 const float* __restrict__ cosb, const float* __restrict__ sinb,
                 float qscale) {
  __shared__ __align__(16) u16 lds[65536];  // 128 KB
  int bid = blockIdx.x;
  if (bid < 256) {
    int swz = (bid & 7) * 32 + (bid >> 3);
    gemm_qk_8phase(xb, Wqkb, QKb, 2048, swz >> 4, swz & 15, lds, cosb, sinb, qscale);
  } else {
    int b2 = bid - 256;
    int swz = (b2 & 7) * 32 + (b2 >> 3);
    gemm_pipe_body<64, 0>(Wvb, xb, VTb, 2048, 4096, 2048, swz >> 4, swz & 15, lds);
  }
}

// out = O @ Wo^T (fp32 out): 256 blocks of 128x256 = 1 exact round
__global__ __launch_bounds__(512, 2)
void gemm_o(const u16* __restrict__ Ob, const u16* __restrict__ Wob, float* __restrict__ out) {
  __shared__ __align__(16) u16 lds[4 * 12288];
  int bid = blockIdx.x;
  int swz = (bid & 7) * 32 + (bid >> 3);
  gemm_pipe_body<64, 1>(Ob, Wob, (void*)out, 4096, 2048, 2048, swz >> 3, swz & 7, lds);
}

// ---------------- Flash attention (proven structure; QKb strides; +T5 setprio) --------
__global__ __launch_bounds__(256, 2)
void attn_kernel(const u16* __restrict__ QKb, const u16* __restrict__ VT,
                 u16* __restrict__ Ob) {
  __shared__ __align__(16) u16 sK[2][64 * 128];   // 32 KB
  __shared__ __align__(16) u16 sV[2][128 * 64];   // 32 KB
  __shared__ __align__(16) u16 sP[4][32 * 64];    // 16 KB

  int id = blockIdx.x;
  int swz = (id & 7) * 64 + (id >> 3);
  int bh = swz >> 4;
  int qb = swz & 15;
  int b = bh >> 4, h = bh & 15;
  int t = threadIdx.x, w = t >> 6, l = t & 63;
  int lr = l & 15, lh = l >> 4;
  int lr7 = lr & 7;
  int q0 = qb * 128;

  const u16* Kbase = QKb + (size_t)(b * 2048) * 4096 + 2048 + h * 128;
  const u16* Vbase = VT + (size_t)(h * 128) * 4096 + b * 2048;
  u16* sPw = sP[w];

  bf16x8 aq[2][4];
#pragma unroll
  for (int qf = 0; qf < 2; ++qf) {
    size_t qrow = (size_t)(b * 2048 + q0 + w * 32 + qf * 16 + lr) * 4096 + h * 128;
#pragma unroll
    for (int c = 0; c < 4; ++c)
      aq[qf][c] = *reinterpret_cast<const bf16x8*>(QKb + qrow + c * 32 + lh * 8);
  }

  f32x4 zero = {0.f, 0.f, 0.f, 0.f};
  f32x4 acc_o[2][8];
#pragma unroll
  for (int qf = 0; qf < 2; ++qf)
#pragma unroll
    for (int d = 0; d < 8; ++d) acc_o[qf][d] = zero;
  float m_row[2] = {-1e30f, -1e30f};
  float l_row[2] = {0.f, 0.f};

  auto stage = [&](int buf, int kt2) {
    const u16* Kt = Kbase + (size_t)(kt2 * 64) * 4096;
    const u16* Vt = Vbase + kt2 * 64;
#pragma unroll
    for (int it = 0; it < 4; ++it) {
      int o = it * 4096 + t * 16;
      int rowK = o >> 8;
      int cbK = (o & 255) ^ ((rowK & 7) << 4);
      async_load16((u16*)sK[buf] + (o >> 1), Kt + (size_t)rowK * 4096 + (cbK >> 1));
      int rowV = o >> 7;
      int cbV = (o & 127) ^ ((rowV & 7) << 4);
      async_load16((u16*)sV[buf] + (o >> 1), Vt + (size_t)rowV * 4096 + (cbV >> 1));
    }
  };

  stage(0, 0);
  __syncthreads();
  int cur = 0;

  for (int kt = 0; kt < 32; ++kt) {
    if (kt < 31) stage(cur ^ 1, kt + 1);

    const u16* sKc = sK[cur];
    const u16* sVc = sV[cur];

    f32x4 sacc[2][4];
#pragma unroll
    for (int qf = 0; qf < 2; ++qf)
#pragma unroll
      for (int g = 0; g < 4; ++g) sacc[qf][g] = zero;
    __builtin_amdgcn_s_setprio(1);
#pragma unroll
    for (int g = 0; g < 4; ++g) {
      int row = g * 16 + lr;
      int xr = lr7 << 4;
#pragma unroll
      for (int c = 0; c < 4; ++c) {
        int cb = (c * 64 + lh * 16) ^ xr;
        bf16x8 bk = *reinterpret_cast<const bf16x8*>(sKc + row * 128 + (cb >> 1));
        sacc[0][g] = __builtin_amdgcn_mfma_f32_16x16x32_bf16(bk, aq[0][c], sacc[0][g], 0, 0, 0);
        sacc[1][g] = __builtin_amdgcn_mfma_f32_16x16x32_bf16(bk, aq[1][c], sacc[1][g], 0, 0, 0);
      }
    }
    __builtin_amdgcn_s_setprio(0);

#pragma unroll
    for (int qf = 0; qf < 2; ++qf) {
      f32x4 m4;
#pragma unroll
      for (int e = 0; e < 4; ++e)
        m4[e] = fmaxf(fmaxf(sacc[qf][0][e], sacc[qf][1][e]),
                      fmaxf(sacc[qf][2][e], sacc[qf][3][e]));
      float mx = fmaxf(fmaxf(m4[0], m4[1]), fmaxf(m4[2], m4[3]));
      mx = fmaxf(mx, __shfl_xor(mx, 16));
      mx = fmaxf(mx, __shfl_xor(mx, 32));
      float mo = m_row[qf];
      if (!__all(mx <= mo + 8.f)) {
        float mn = fmaxf(mo, mx);
        float al = __builtin_amdgcn_exp2f(mo - mn);
        m_row[qf] = mn;
        l_row[qf] *= al;
#pragma unroll
        for (int d = 0; d < 8; ++d) acc_o[qf][d] *= al;
      }
      float mn = m_row[qf];
#pragma unroll
      for (int g = 0; g < 4; ++g)
#pragma unroll
        for (int e = 0; e < 4; ++e)
          sacc[qf][g][e] = __builtin_amdgcn_exp2f(sacc[qf][g][e] - mn);
      f32x4 s4;
#pragma unroll
      for (int e = 0; e < 4; ++e)
        s4[e] = (sacc[qf][0][e] + sacc[qf][1][e]) + (sacc[qf][2][e] + sacc[qf][3][e]);
      float rs = (s4[0] + s4[1]) + (s4[2] + s4[3]);
      rs += __shfl_xor(rs, 16);
      rs += __shfl_xor(rs, 32);
      l_row[qf] += rs;

      int rowb = (qf * 16 + lr) * 128;
      int xw = lr7 << 4;
#pragma unroll
      for (int g = 0; g < 4; ++g) {
        uint2 pw;
        pw.x = cvtpk(sacc[qf][g][0], sacc[qf][g][1]);
        pw.y = cvtpk(sacc[qf][g][2], sacc[qf][g][3]);
        int cb = (g * 32 + lh * 8) ^ xw;
        *reinterpret_cast<uint2*>(reinterpret_cast<char*>(sPw) + rowb + cb) = pw;
      }
    }

    bf16x8 bp[2][2];
#pragma unroll
    for (int qf = 0; qf < 2; ++qf) {
      int rowb = (qf * 16 + lr) * 128;
      int xr = lr7 << 4;
#pragma unroll
      for (int c2 = 0; c2 < 2; ++c2) {
        int cb = (c2 * 64 + lh * 16) ^ xr;
        bp[qf][c2] = *reinterpret_cast<const bf16x8*>(
            reinterpret_cast<const char*>(sPw) + rowb + cb);
      }
    }
    __builtin_amdgcn_s_setprio(1);
#pragma unroll
    for (int c2 = 0; c2 < 2; ++c2) {
#pragma unroll
      for (int d = 0; d < 8; ++d) {
        int row = d * 16 + lr;
        int cb = (c2 * 64 + lh * 16) ^ (lr7 << 4);
        bf16x8 bv = *reinterpret_cast<const bf16x8*>(sVc + row * 64 + (cb >> 1));
        acc_o[0][d] = __builtin_amdgcn_mfma_f32_16x16x32_bf16(bv, bp[0][c2], acc_o[0][d], 0, 0, 0);
        acc_o[1][d] = __builtin_amdgcn_mfma_f32_16x16x32_bf16(bv, bp[1][c2], acc_o[1][d], 0, 0, 0);
      }
    }
    __builtin_amdgcn_s_setprio(0);

    __syncthreads();
    cur ^= 1;
  }

#pragma unroll
  for (int qf = 0; qf < 2; ++qf) {
    float inv = 1.f / l_row[qf];
    size_t qrow = (size_t)(b * 2048 + q0 + w * 32 + qf * 16 + lr) * 2048 + h * 128;
#pragma unroll
    for (int d = 0; d < 8; ++d) {
      ushort4 o;
      o.x = f2bf(acc_o[qf][d][0] * inv);
      o.y = f2bf(acc_o[qf][d][1] * inv);
      o.z = f2bf(acc_o[qf][d][2] * inv);
      o.w = f2bf(acc_o[qf][d][3] * inv);
      *reinterpret_cast<ushort4*>(Ob + qrow + d * 16 + lh * 4) = o;
    }
  }
}

extern "C" void kernel_launch(void* const* d_in, const int* in_sizes, int n_in,
                              void* d_out, int out_size, void* d_ws, size_t ws_size,
                              hipStream_t stream) {
  const float* x  = (const float*)d_in[0];
  const float* rc = (const float*)d_in[1];
  const float* rs = (const float*)d_in[2];
  const float* Wq = (const float*)d_in[3];
  const float* Wk = (const float*)d_in[4];
  const float* Wv = (const float*)d_in[5];
  const float* Wo = (const float*)d_in[6];
  float* out = (float*)d_out;
  char* ws = (char*)d_ws;
  const size_t MB = 1024 * 1024;
  u16* xb   = (u16*)(ws);            // 16 MB
  u16* Wqkb = (u16*)(ws + 16 * MB);  // 16 MB  [4096][2048] = [Wq;Wk]
  u16* Wvb  = (u16*)(ws + 32 * MB);  // 8 MB
  u16* Wob  = (u16*)(ws + 40 * MB);  // 8 MB
  u16* QKb  = (u16*)(ws + 48 * MB);  // 32 MB  [4096][4096]
  u16* VTb  = (u16*)(ws + 80 * MB);  // 16 MB  [2048][4096]
  u16* Ob   = (u16*)(ws + 16 * MB);  // 16 MB  (alias Wqkb, dead after QK GEMM)

  convert_all<<<24576, 256, 0, stream>>>(x, Wq, Wk, Wv, Wo, xb, Wqkb, Wvb, Wob);

  const float qscale = 0.08838834764831845f * 1.4426950408889634f;  // 1/sqrt(128)*log2(e)
  gemm_qkv256<<<512, 512, 0, stream>>>(xb, Wqkb, Wvb, QKb, VTb, rc, rs, qscale);

  attn_kernel<<<512, 256, 0, stream>>>(QKb, VTb, Ob);

  gemm_o<<<256, 512, 0, stream>>>(Ob, Wob, out);
}